// Round 5
// baseline (504.312 us; speedup 1.0000x reference)
//
#include <hip/hip_runtime.h>
#include <hip/hip_bf16.h>
#include <cstdint>

#define D_DIM 128
#define N0_C 50000
#define N1_C 5000
#define E0_C 800000
#define E1_C 80000
#define BIN_SHIFT 9          // 512 dst nodes per bin (graph0 fill)

typedef __attribute__((ext_vector_type(8))) short bf16x8;
typedef __attribute__((ext_vector_type(4))) float f32x4;

__device__ __forceinline__ ushort f2bf_rne(float x) {
    unsigned int u = __float_as_uint(x);
    return (ushort)((u + 0x7FFFu + ((u >> 16) & 1u)) >> 16);
}
__device__ __forceinline__ float bf2f(ushort h) {
    return __uint_as_float(((unsigned int)h) << 16);
}

// ---------------------------------------------------------------------------
// CSR build: histogram -> 3-phase scan (single concatenated array) -> fill
// ---------------------------------------------------------------------------
__global__ __launch_bounds__(256) void hist_kernel(const int* __restrict__ dst,
                                                   int* __restrict__ cnt, int E) {
    int e = blockIdx.x * blockDim.x + threadIdx.x;
    if (e < E) atomicAdd(&cnt[dst[e]], 1);
}

__global__ __launch_bounds__(256) void scan_partial_kernel(
    const int* __restrict__ cnt, int* __restrict__ bsum, int n) {
    __shared__ int ws[4];
    int b = blockIdx.x, t = threadIdx.x, lane = t & 63, w = t >> 6;
    int base = b * 1024 + t * 4;
    int s = 0;
    if (base + 3 < n) { int4 q = *(const int4*)&cnt[base]; s = q.x + q.y + q.z + q.w; }
    else { for (int i = 0; i < 4; ++i) if (base + i < n) s += cnt[base + i]; }
    #pragma unroll
    for (int off = 32; off; off >>= 1) s += __shfl_down(s, off);
    if (lane == 0) ws[w] = s;
    __syncthreads();
    if (t == 0) bsum[b] = ws[0] + ws[1] + ws[2] + ws[3];
}

__global__ __launch_bounds__(1024) void exscan_kernel(const int* __restrict__ cnt,
                                                      int* __restrict__ rowptr, int n) {
    __shared__ int wsum[17];
    __shared__ int base_s;
    const int t = threadIdx.x;
    const int lane = t & 63;
    const int w = t >> 6;
    if (t == 0) { base_s = 0; rowptr[0] = 0; }
    __syncthreads();
    for (int i0 = 0; i0 < n; i0 += 1024) {
        int i = i0 + t;
        int v = (i < n) ? cnt[i] : 0;
        int x = v;
        #pragma unroll
        for (int off = 1; off < 64; off <<= 1) {
            int y = __shfl_up(x, off);
            if (lane >= off) x += y;
        }
        if (lane == 63) wsum[w] = x;
        __syncthreads();
        if (t == 0) {
            int run = base_s;
            #pragma unroll
            for (int j = 0; j < 16; ++j) { int c = wsum[j]; wsum[j] = run; run += c; }
            wsum[16] = run;
        }
        __syncthreads();
        if (i < n) rowptr[i + 1] = wsum[w] + x;
        __syncthreads();
        if (t == 0) base_s = wsum[16];
        __syncthreads();
    }
}

__global__ __launch_bounds__(256) void scan_final_kernel(
    const int* __restrict__ cnt, const int* __restrict__ boff,
    int* __restrict__ rowptr, int n) {
    __shared__ int wsum[4];
    int b = blockIdx.x, t = threadIdx.x, lane = t & 63, w = t >> 6;
    int base = b * 1024 + t * 4;
    int v0 = 0, v1 = 0, v2 = 0, v3 = 0;
    if (base + 3 < n) { int4 q = *(const int4*)&cnt[base]; v0 = q.x; v1 = q.y; v2 = q.z; v3 = q.w; }
    else {
        if (base + 0 < n) v0 = cnt[base + 0];
        if (base + 1 < n) v1 = cnt[base + 1];
        if (base + 2 < n) v2 = cnt[base + 2];
        if (base + 3 < n) v3 = cnt[base + 3];
    }
    int s = v0 + v1 + v2 + v3;
    int x = s;
    #pragma unroll
    for (int off = 1; off < 64; off <<= 1) {
        int y = __shfl_up(x, off);
        if (lane >= off) x += y;
    }
    if (lane == 63) wsum[w] = x;
    __syncthreads();
    if (t == 0) { int run = 0; for (int i = 0; i < 4; ++i) { int c = wsum[i]; wsum[i] = run; run += c; } }
    __syncthreads();
    int run = boff[b] + wsum[w] + x - s;
    if (base + 0 < n) { run += v0; rowptr[base + 1] = run; }
    if (base + 1 < n) { run += v1; rowptr[base + 2] = run; }
    if (base + 2 < n) { run += v2; rowptr[base + 3] = run; }
    if (base + 3 < n) { run += v3; rowptr[base + 4] = run; }
    if (b == 0 && t == 0) rowptr[0] = 0;
}

// small-graph fill (scatter window small -> L2-friendly)
__global__ __launch_bounds__(256) void fill_kernel(const int* __restrict__ src,
                                                   const int* __restrict__ dst,
                                                   const int* __restrict__ rowptr,
                                                   int rbase,
                                                   int* __restrict__ cursor,
                                                   int* __restrict__ colv, int E) {
    int e = blockIdx.x * blockDim.x + threadIdx.x;
    if (e < E) {
        int d = dst[e];
        int p = atomicAdd(&cursor[d], 1);
        colv[rowptr[d] - rbase + p] = src[e];
    }
}

// ---- graph0 binned fill: coalesced pair scatter, then windowed colv fill ----
__global__ __launch_bounds__(64) void initcur_kernel(const int* __restrict__ rowptr,
                                                     int* __restrict__ cursors,
                                                     int nbins, int N) {
    int b = blockIdx.x * 64 + threadIdx.x;
    if (b < nbins) {
        int idx = b << BIN_SHIFT; if (idx > N) idx = N;
        cursors[b] = rowptr[idx];
    }
}

__global__ __launch_bounds__(256) void binscatter_kernel(
    const int* __restrict__ src, const int* __restrict__ dstv,
    int* __restrict__ cursors, int2* __restrict__ pairs, int E, int nbins) {
    __shared__ int lcnt[128];
    __shared__ int sbase[128];
    int t = threadIdx.x;
    int e0 = blockIdx.x * 4096;
    if (t < 128) lcnt[t] = 0;
    __syncthreads();
    int lrank[16], dloc[16];
    #pragma unroll
    for (int i = 0; i < 16; ++i) {
        int e = e0 + t + i * 256;
        if (e < E) {
            int d = dstv[e];
            dloc[i] = d;
            lrank[i] = atomicAdd(&lcnt[d >> BIN_SHIFT], 1);
        } else dloc[i] = -1;
    }
    __syncthreads();
    if (t < nbins && lcnt[t] > 0) sbase[t] = atomicAdd(&cursors[t], lcnt[t]);
    __syncthreads();
    #pragma unroll
    for (int i = 0; i < 16; ++i) {
        int e = e0 + t + i * 256;
        if (e < E) {
            int d = dloc[i];
            pairs[sbase[d >> BIN_SHIFT] + lrank[i]] = make_int2(d, src[e]);
        }
    }
}

__global__ __launch_bounds__(256) void binfill_kernel(
    const int2* __restrict__ pairs, const int* __restrict__ rowptr,
    int* __restrict__ colv, int N) {
    __shared__ int rp[513];
    __shared__ int cur[512];
    int b = blockIdx.x, t = threadIdx.x;
    int binbase = b << BIN_SHIFT;
    for (int i = t; i < 513; i += 256) {
        int idx = binbase + i; if (idx > N) idx = N;
        rp[i] = rowptr[idx];
    }
    for (int i = t; i < 512; i += 256) cur[i] = 0;
    __syncthreads();
    int beg = rp[0], end = rp[512];
    for (int i = beg + t; i < end; i += 256) {
        int2 pr = pairs[i];
        int local = pr.x - binbase;
        int rank = atomicAdd(&cur[local], 1);
        colv[rp[local] + rank] = pr.y;
    }
}

// ---------------------------------------------------------------------------
// Weight prep: 8 logical 128x128 matrices -> W^T hi/lo bf16 planes [n][k]
// ---------------------------------------------------------------------------
__global__ __launch_bounds__(256) void wprep_kernel(
    const float* __restrict__ W0s, const float* __restrict__ W0n,
    const float* __restrict__ W1s, const float* __restrict__ W1n,
    const float* __restrict__ W2s, const float* __restrict__ W2n,
    ushort* __restrict__ wt_hi, ushort* __restrict__ wt_lo) {
    int gi = blockIdx.x * 256 + threadIdx.x;
    int mi = gi >> 14, idx = gi & 16383;
    int k = idx >> 7, n = idx & 127;
    const float* src; int row = k;
    switch (mi) {
        case 0: src = W0s; break;
        case 1: src = W0n; break;
        case 2: src = W1s; break;
        case 3: src = W1n; break;
        case 4: src = W2s; break;
        case 5: src = W2s; row = k + 128; break;
        case 6: src = W2n; break;
        default: src = W2n; row = k + 128; break;
    }
    float v = src[row * 128 + n];
    ushort h = f2bf_rne(v);
    ushort l = f2bf_rne(v - bf2f(h));
    wt_hi[(mi << 14) + n * 128 + k] = h;
    wt_lo[(mi << 14) + n * 128 + k] = l;
}

// ---------------------------------------------------------------------------
// Split-bf16 MFMA dual GEMM, fp32 A (in-register hi/lo split), NO LDS:
// B-fragments read straight from global (weights are 512KB -> L2-resident).
// No barriers, no bank conflicts; one wave per 16 rows.
// O1 = A@W1 (+bias1) (+C2[ddst[r]]),  O2 = A@W2 (+D2[ddst[r]])
// O2 emitted as bf16 if O2b non-null (consumed only by mean-aggregate).
// ---------------------------------------------------------------------------
__global__ __launch_bounds__(256, 3) void dualmm_mfma_kernel(
    const float* __restrict__ A,
    const ushort* __restrict__ w1hi, const ushort* __restrict__ w1lo,
    const ushort* __restrict__ w2hi, const ushort* __restrict__ w2lo,
    const float* __restrict__ bias1,
    const int* __restrict__ ddst,
    const float* __restrict__ C2g, const float* __restrict__ D2g,
    float* __restrict__ O1, float* __restrict__ O2,
    ushort* __restrict__ O2b, int N) {
    const int tid = threadIdx.x;
    const int lane = tid & 63;
    const int m = lane & 15, quad = lane >> 4;
    const int r0 = (blockIdx.x * 4 + (tid >> 6)) * 16;
    if (r0 >= N) return;
    const f32x4 zero = {0.f, 0.f, 0.f, 0.f};
    f32x4 acc1[8], acc2[8];
    #pragma unroll
    for (int ct = 0; ct < 8; ++ct) { acc1[ct] = zero; acc2[ct] = zero; }

    int ar = r0 + m; if (ar >= N) ar = N - 1;
    const int lofs = quad * 8;            // k-offset within slab for this lane

    #pragma unroll 1
    for (int c = 0; c < 4; ++c) {
        const int k0 = c * 32;
        const float* arow = A + (size_t)ar * 128 + k0 + lofs;
        float4 a0 = *(const float4*)arow;
        float4 a1 = *(const float4*)(arow + 4);
        float av[8] = {a0.x, a0.y, a0.z, a0.w, a1.x, a1.y, a1.z, a1.w};
        bf16x8 afh, afl;
        #pragma unroll
        for (int i = 0; i < 8; ++i) {
            ushort h = f2bf_rne(av[i]);
            ushort l = f2bf_rne(av[i] - bf2f(h));
            afh[i] = (short)h; afl[i] = (short)l;
        }
        #pragma unroll
        for (int ct = 0; ct < 8; ++ct) {
            const size_t bo = (size_t)(ct * 16 + m) * 128 + k0 + lofs;
            bf16x8 b1h = *(const bf16x8*)(w1hi + bo);
            bf16x8 b1l = *(const bf16x8*)(w1lo + bo);
            bf16x8 b2h = *(const bf16x8*)(w2hi + bo);
            bf16x8 b2l = *(const bf16x8*)(w2lo + bo);
            acc1[ct] = __builtin_amdgcn_mfma_f32_16x16x32_bf16(afh, b1h, acc1[ct], 0, 0, 0);
            acc1[ct] = __builtin_amdgcn_mfma_f32_16x16x32_bf16(afl, b1h, acc1[ct], 0, 0, 0);
            acc1[ct] = __builtin_amdgcn_mfma_f32_16x16x32_bf16(afh, b1l, acc1[ct], 0, 0, 0);
            acc2[ct] = __builtin_amdgcn_mfma_f32_16x16x32_bf16(afh, b2h, acc2[ct], 0, 0, 0);
            acc2[ct] = __builtin_amdgcn_mfma_f32_16x16x32_bf16(afl, b2h, acc2[ct], 0, 0, 0);
            acc2[ct] = __builtin_amdgcn_mfma_f32_16x16x32_bf16(afh, b2l, acc2[ct], 0, 0, 0);
        }
    }
    // epilogue: C/D layout col=lane&15, row=quad*4+reg
    int rr[4], cc[4];
    #pragma unroll
    for (int reg = 0; reg < 4; ++reg) {
        rr[reg] = r0 + quad * 4 + reg;
        cc[reg] = (ddst && rr[reg] < N) ? ddst[rr[reg]] : 0;
    }
    #pragma unroll
    for (int ct = 0; ct < 8; ++ct) {
        const int col = ct * 16 + m;
        float bv = bias1 ? bias1[col] : 0.f;
        #pragma unroll
        for (int reg = 0; reg < 4; ++reg) {
            int r = rr[reg];
            if (r < N) {
                float g1 = ddst ? C2g[(size_t)cc[reg] * D_DIM + col] : 0.f;
                float g2 = ddst ? D2g[(size_t)cc[reg] * D_DIM + col] : 0.f;
                O1[(size_t)r * D_DIM + col] = acc1[ct][reg] + bv + g1;
                float o2v = acc2[ct][reg] + g2;
                if (O2b) O2b[(size_t)r * D_DIM + col] = f2bf_rne(o2v);
                else     O2[(size_t)r * D_DIM + col] = o2v;
            }
        }
    }
}

// ---------------------------------------------------------------------------
// fp32 CSR gather-aggregate (small graphs): wave/node, float4/lane (2 rows/ld)
// ---------------------------------------------------------------------------
__global__ __launch_bounds__(256) void csr_agg2_kernel(
    const float* __restrict__ feat, const int* __restrict__ rowptr, int rbase,
    const int* __restrict__ colv, const float* __restrict__ addv,
    const float* __restrict__ bias, float* __restrict__ out,
    int Ndst, int do_relu) {
    int gt = blockIdx.x * blockDim.x + threadIdx.x;
    int wid = gt >> 6;
    if (wid >= Ndst) return;
    int lane = threadIdx.x & 63;
    int half = lane >> 5, li = lane & 31;
    const int f4 = li * 4;
    float4 acc = make_float4(0.f, 0.f, 0.f, 0.f);
    int beg = rowptr[wid] - rbase, end = rowptr[wid + 1] - rbase;
    int deg = end - beg;
    int j = beg + half;
    for (; j + 6 < end; j += 8) {
        int r0 = colv[j], r1 = colv[j + 2], r2 = colv[j + 4], r3 = colv[j + 6];
        float4 v0 = *(const float4*)&feat[(size_t)r0 * D_DIM + f4];
        float4 v1 = *(const float4*)&feat[(size_t)r1 * D_DIM + f4];
        float4 v2 = *(const float4*)&feat[(size_t)r2 * D_DIM + f4];
        float4 v3 = *(const float4*)&feat[(size_t)r3 * D_DIM + f4];
        acc.x += v0.x + v1.x + v2.x + v3.x;
        acc.y += v0.y + v1.y + v2.y + v3.y;
        acc.z += v0.z + v1.z + v2.z + v3.z;
        acc.w += v0.w + v1.w + v2.w + v3.w;
    }
    for (; j < end; j += 2) {
        int r = colv[j];
        float4 v = *(const float4*)&feat[(size_t)r * D_DIM + f4];
        acc.x += v.x; acc.y += v.y; acc.z += v.z; acc.w += v.w;
    }
    acc.x += __shfl_xor(acc.x, 32);
    acc.y += __shfl_xor(acc.y, 32);
    acc.z += __shfl_xor(acc.z, 32);
    acc.w += __shfl_xor(acc.w, 32);
    float invd = 1.f / fmaxf((float)deg, 1.f);
    acc.x *= invd; acc.y *= invd; acc.z *= invd; acc.w *= invd;
    if (addv) {
        float4 v = *(const float4*)&addv[(size_t)wid * D_DIM + f4];
        acc.x += v.x; acc.y += v.y; acc.z += v.z; acc.w += v.w;
    }
    if (bias) {
        float4 v = *(const float4*)&bias[f4];
        acc.x += v.x; acc.y += v.y; acc.z += v.z; acc.w += v.w;
    }
    if (do_relu) {
        acc.x = fmaxf(acc.x, 0.f); acc.y = fmaxf(acc.y, 0.f);
        acc.z = fmaxf(acc.z, 0.f); acc.w = fmaxf(acc.w, 0.f);
    }
    if (half == 0)
        *(float4*)&out[(size_t)wid * D_DIM + f4] = acc;
}

// ---------------------------------------------------------------------------
// bf16-input CSR gather-aggregate (big graphs): wave/node, uint4(8 bf16)/lane,
// 16 lanes/row -> 4 rows per load instr, 16 edges in flight. fp32 accumulate.
// Optional fused readout  z = relu(...)@Wm + bm.
// ---------------------------------------------------------------------------
__device__ __forceinline__ void acc8_add(float* acc, uint4 r) {
    acc[0] += __uint_as_float(r.x << 16);
    acc[1] += __uint_as_float(r.x & 0xFFFF0000u);
    acc[2] += __uint_as_float(r.y << 16);
    acc[3] += __uint_as_float(r.y & 0xFFFF0000u);
    acc[4] += __uint_as_float(r.z << 16);
    acc[5] += __uint_as_float(r.z & 0xFFFF0000u);
    acc[6] += __uint_as_float(r.w << 16);
    acc[7] += __uint_as_float(r.w & 0xFFFF0000u);
}

__global__ __launch_bounds__(256) void csr_aggb_kernel(
    const ushort* __restrict__ featb, const int* __restrict__ rowptr, int rbase,
    const int* __restrict__ colv, const float* __restrict__ addv,
    const float* __restrict__ bias, float* __restrict__ out,
    const float* __restrict__ Wm, const float* __restrict__ bm,
    float* __restrict__ z, int Ndst, int do_relu) {
    int gt = blockIdx.x * blockDim.x + threadIdx.x;
    int wid = gt >> 6;
    if (wid >= Ndst) return;
    int lane = threadIdx.x & 63;
    int q = lane >> 4, li = lane & 15;
    const int f8 = li * 8;
    float acc[8];
    #pragma unroll
    for (int i = 0; i < 8; ++i) acc[i] = 0.f;
    int beg = rowptr[wid] - rbase, end = rowptr[wid + 1] - rbase;
    int deg = end - beg;
    int j = beg + q;
    for (; j + 12 < end; j += 16) {
        int r0 = colv[j], r1 = colv[j + 4], r2 = colv[j + 8], r3 = colv[j + 12];
        uint4 v0 = *(const uint4*)&featb[(size_t)r0 * D_DIM + f8];
        uint4 v1 = *(const uint4*)&featb[(size_t)r1 * D_DIM + f8];
        uint4 v2 = *(const uint4*)&featb[(size_t)r2 * D_DIM + f8];
        uint4 v3 = *(const uint4*)&featb[(size_t)r3 * D_DIM + f8];
        acc8_add(acc, v0); acc8_add(acc, v1); acc8_add(acc, v2); acc8_add(acc, v3);
    }
    for (; j < end; j += 4) {
        int r = colv[j];
        uint4 v = *(const uint4*)&featb[(size_t)r * D_DIM + f8];
        acc8_add(acc, v);
    }
    #pragma unroll
    for (int i = 0; i < 8; ++i) {
        acc[i] += __shfl_xor(acc[i], 16);
        acc[i] += __shfl_xor(acc[i], 32);
    }
    float invd = 1.f / fmaxf((float)deg, 1.f);
    #pragma unroll
    for (int i = 0; i < 8; ++i) acc[i] *= invd;
    if (addv) {
        float4 a0 = *(const float4*)&addv[(size_t)wid * D_DIM + f8];
        float4 a1 = *(const float4*)&addv[(size_t)wid * D_DIM + f8 + 4];
        acc[0] += a0.x; acc[1] += a0.y; acc[2] += a0.z; acc[3] += a0.w;
        acc[4] += a1.x; acc[5] += a1.y; acc[6] += a1.z; acc[7] += a1.w;
    }
    if (bias) {
        float4 b0 = *(const float4*)&bias[f8];
        float4 b1 = *(const float4*)&bias[f8 + 4];
        acc[0] += b0.x; acc[1] += b0.y; acc[2] += b0.z; acc[3] += b0.w;
        acc[4] += b1.x; acc[5] += b1.y; acc[6] += b1.z; acc[7] += b1.w;
    }
    if (do_relu) {
        #pragma unroll
        for (int i = 0; i < 8; ++i) acc[i] = fmaxf(acc[i], 0.f);
    }
    if (out && q == 0) {
        *(float4*)&out[(size_t)wid * D_DIM + f8] =
            make_float4(acc[0], acc[1], acc[2], acc[3]);
        *(float4*)&out[(size_t)wid * D_DIM + f8 + 4] =
            make_float4(acc[4], acc[5], acc[6], acc[7]);
    }
    if (z) {
        float4 w0 = *(const float4*)&Wm[f8];
        float4 w1 = *(const float4*)&Wm[f8 + 4];
        float p = acc[0] * w0.x + acc[1] * w0.y + acc[2] * w0.z + acc[3] * w0.w
                + acc[4] * w1.x + acc[5] * w1.y + acc[6] * w1.z + acc[7] * w1.w;
        if (q != 0) p = 0.f;
        #pragma unroll
        for (int off = 32; off > 0; off >>= 1) p += __shfl_down(p, off);
        if (lane == 0) z[wid] = p + bm[0];
    }
}

// ---------------------------------------------------------------------------
// 2-phase online softmax over z[N0]
// ---------------------------------------------------------------------------
__global__ __launch_bounds__(256) void softmax_partial_kernel(
    const float* __restrict__ z, float* __restrict__ red, int N, int nblk) {
    __shared__ float sm[4], ss[4];
    int t = threadIdx.x, b = blockIdx.x;
    int lane = t & 63, w = t >> 6;
    float m = -1e30f, s = 0.f;
    for (int i = b * 256 + t; i < N; i += nblk * 256) {
        float v = z[i];
        if (v > m) { s = s * __expf(m - v) + 1.f; m = v; }
        else s += __expf(v - m);
    }
    #pragma unroll
    for (int off = 32; off > 0; off >>= 1) {
        float mo = __shfl_down(m, off), so = __shfl_down(s, off);
        if (mo > m) { s = s * __expf(m - mo) + so; m = mo; }
        else s += so * __expf(mo - m);
    }
    if (lane == 0) { sm[w] = m; ss[w] = s; }
    __syncthreads();
    if (t == 0) {
        for (int i = 1; i < 4; ++i) {
            float mo = sm[i], so = ss[i];
            if (mo > m) { s = s * __expf(m - mo) + so; m = mo; }
            else s += so * __expf(mo - m);
        }
        red[2 + 2 * b] = m; red[3 + 2 * b] = s;
    }
}

__global__ __launch_bounds__(64) void softmax_merge_kernel(float* __restrict__ red, int B) {
    int t = threadIdx.x;
    float m = -1e30f, s = 0.f;
    if (t < B) { m = red[2 + 2 * t]; s = red[3 + 2 * t]; }
    #pragma unroll
    for (int off = 32; off > 0; off >>= 1) {
        float mo = __shfl_down(m, off), so = __shfl_down(s, off);
        if (mo > m) { s = s * __expf(m - mo) + so; m = mo; }
        else s += so * __expf(mo - m);
    }
    if (t == 0) { red[0] = m; red[1] = s; }
}

__global__ __launch_bounds__(256) void softmax_final_kernel(
    const float* __restrict__ z, const float* __restrict__ red,
    float* __restrict__ out, int N) {
    int i = blockIdx.x * blockDim.x + threadIdx.x;
    if (i < N) out[i] = expf(z[i] - red[0]) / red[1];
}

// ---------------------------------------------------------------------------
// Host launcher
// ---------------------------------------------------------------------------
static inline char* align_up(char* p, size_t a) {
    return (char*)(((uintptr_t)p + a - 1) & ~(uintptr_t)(a - 1));
}

extern "C" void kernel_launch(void* const* d_in, const int* in_sizes, int n_in,
                              void* d_out, int out_size, void* d_ws, size_t ws_size,
                              hipStream_t stream) {
    const int N0 = N0_C, N1 = N1_C, E0 = E0_C, E1 = E1_C;
    const float* X   = (const float*)d_in[0];
    const float* W0s = (const float*)d_in[1];
    const float* W0n = (const float*)d_in[2];
    const float* b0  = (const float*)d_in[3];
    const float* W1s = (const float*)d_in[4];
    const float* W1n = (const float*)d_in[5];
    const float* b1  = (const float*)d_in[6];
    const float* W2s = (const float*)d_in[7];
    const float* W2n = (const float*)d_in[8];
    const float* b2  = (const float*)d_in[9];
    const float* Wm  = (const float*)d_in[10];
    const float* bm  = (const float*)d_in[11];
    const int* src0  = (const int*)d_in[12];
    const int* dst0  = (const int*)d_in[13];
    const int* src1  = (const int*)d_in[14];
    const int* dst1  = (const int*)d_in[15];
    const int* dsrc  = (const int*)d_in[16];
    const int* ddst  = (const int*)d_in[17];
    float* out = (float*)d_out;

    char* p = (char*)d_ws;
    const size_t FB = (size_t)N0 * D_DIM;
    const size_t SB = (size_t)N1 * D_DIM;
    auto grab_f = [&](size_t nf) { p = align_up(p, 256); float* r = (float*)p; p += nf * 4; return r; };
    auto grab_i = [&](size_t ni) { p = align_up(p, 256); int* r = (int*)p; p += ni * 4; return r; };
    auto grab_u = [&](size_t nu) { p = align_up(p, 256); ushort* r = (ushort*)p; p += nu * 2; return r; };

    float* bufA = grab_f(FB);   // y0s -> x0
    float* bufD = grab_f(FB);   // y2s
    float* x1b  = grab_f(SB);
    float* y1s  = grab_f(SB);   // -> x1f
    float* y1n  = grab_f(SB);
    float* C2   = grab_f(SB);
    float* D2   = grab_f(SB);
    float* zbuf = grab_f(N0);
    float* red  = grab_f(256);
    ushort* y0nb = grab_u(FB);  // bf16 neighbor-message planes
    ushort* y2nb = grab_u(FB);
    ushort* wt_hi = grab_u(8 * 16384);
    ushort* wt_lo = grab_u(8 * 16384);
    const int NC = N0 + 2 * N1;
    int* cntAll = grab_i(NC);
    int* rowptrAll = grab_i(NC + 1);
    int* bsum = grab_i(256);
    int* boff = grab_i(256);
    int* cursors = grab_i(128);
    int* col0 = grab_i(E0);
    int* col1 = grab_i(E1);
    int* colD = grab_i(N0);
    int2* pairbuf = (int2*)grab_i(2 * (size_t)E0);
    (void)ws_size; (void)n_in; (void)in_sizes; (void)out_size;

    const int BT = 256;
    auto cdiv = [](int a, int b) { return (a + b - 1) / b; };
    auto WT_HI = [&](int mi) { return wt_hi + ((size_t)mi << 14); };
    auto WT_LO = [&](int mi) { return wt_lo + ((size_t)mi << 14); };
    const int nbins0 = (N0 + (1 << BIN_SHIFT) - 1) >> BIN_SHIFT;   // 98

    // ---- CSR build ----
    hipMemsetAsync(cntAll, 0, (size_t)NC * 4, stream);
    hist_kernel<<<cdiv(E0, BT), BT, 0, stream>>>(dst0, cntAll, E0);
    hist_kernel<<<cdiv(E1, BT), BT, 0, stream>>>(dst1, cntAll + N0, E1);
    hist_kernel<<<cdiv(N0, BT), BT, 0, stream>>>(ddst, cntAll + N0 + N1, N0);
    const int NB = cdiv(NC, 1024);
    scan_partial_kernel<<<NB, BT, 0, stream>>>(cntAll, bsum, NC);
    exscan_kernel<<<1, 1024, 0, stream>>>(bsum, boff, NB);
    scan_final_kernel<<<NB, BT, 0, stream>>>(cntAll, boff, rowptrAll, NC);
    // graph0: binned two-pass fill (coalesced)
    initcur_kernel<<<2, 64, 0, stream>>>(rowptrAll, cursors, nbins0, N0);
    binscatter_kernel<<<cdiv(E0, 4096), BT, 0, stream>>>(src0, dst0, cursors, pairbuf, E0, nbins0);
    binfill_kernel<<<nbins0, BT, 0, stream>>>(pairbuf, rowptrAll, col0, N0);
    // small graphs: direct fill
    hipMemsetAsync(cntAll + N0, 0, (size_t)(2 * N1) * 4, stream);
    fill_kernel<<<cdiv(E1, BT), BT, 0, stream>>>(src1, dst1, rowptrAll + N0, E0, cntAll + N0, col1, E1);
    fill_kernel<<<cdiv(N0, BT), BT, 0, stream>>>(dsrc, ddst, rowptrAll + N0 + N1, E0 + E1,
                                                 cntAll + N0 + N1, colD, N0);

    // ---- weight prep ----
    wprep_kernel<<<512, BT, 0, stream>>>(W0s, W0n, W1s, W1n, W2s, W2n, wt_hi, wt_lo);

    // ---- layer 0 SAGE: x0 = X@W0s + b0 + mean_nbr(X@W0n) ----
    dualmm_mfma_kernel<<<cdiv(N0, 64), BT, 0, stream>>>(X,
        WT_HI(0), WT_LO(0), WT_HI(1), WT_LO(1), b0, nullptr, nullptr, nullptr,
        bufA, nullptr, y0nb, N0);
    csr_aggb_kernel<<<cdiv(N0, 4), BT, 0, stream>>>(y0nb, rowptrAll, 0, col0, bufA,
        nullptr, bufA, nullptr, nullptr, nullptr, N0, 0);

    // ---- down pool: x1 = relu(mean_cluster(x0)) ----
    csr_agg2_kernel<<<cdiv(N1, 4), BT, 0, stream>>>(bufA, rowptrAll + N0 + N1, E0 + E1,
        colD, nullptr, nullptr, x1b, N1, 1);

    // ---- layer 1 SAGE ----
    dualmm_mfma_kernel<<<cdiv(N1, 64), BT, 0, stream>>>(x1b,
        WT_HI(2), WT_LO(2), WT_HI(3), WT_LO(3), b1, nullptr, nullptr, nullptr,
        y1s, y1n, nullptr, N1);
    csr_agg2_kernel<<<cdiv(N1, 4), BT, 0, stream>>>(y1n, rowptrAll + N0, E0, col1, y1s,
        nullptr, y1s, N1, 1);

    // ---- layer 2: small dualmm (C2/D2 fp32), big dualmm w/ fused up-scatter ----
    dualmm_mfma_kernel<<<cdiv(N1, 64), BT, 0, stream>>>(y1s,
        WT_HI(4), WT_LO(4), WT_HI(6), WT_LO(6), nullptr, nullptr, nullptr, nullptr,
        C2, D2, nullptr, N1);
    dualmm_mfma_kernel<<<cdiv(N0, 64), BT, 0, stream>>>(bufA,
        WT_HI(5), WT_LO(5), WT_HI(7), WT_LO(7), nullptr, ddst, C2, D2,
        bufD, nullptr, y2nb, N0);

    // ---- layer 2 combine + fused readout ----
    csr_aggb_kernel<<<cdiv(N0, 4), BT, 0, stream>>>(y2nb, rowptrAll, 0, col0, bufD,
        b2, nullptr, Wm, bm, zbuf, N0, 1);

    // ---- softmax over nodes ----
    softmax_partial_kernel<<<64, BT, 0, stream>>>(zbuf, red, N0, 64);
    softmax_merge_kernel<<<1, 64, 0, stream>>>(red, 64);
    softmax_final_kernel<<<cdiv(N0, BT), BT, 0, stream>>>(zbuf, red, out, N0);
}

// Round 6
// 376.407 us; speedup vs baseline: 1.3398x; 1.3398x over previous
//
#include <hip/hip_runtime.h>
#include <hip/hip_bf16.h>
#include <cstdint>

#define D_DIM 128
#define N0_C 50000
#define N1_C 5000
#define E0_C 800000
#define E1_C 80000
#define BIN_SHIFT 9          // 512 dst nodes per bin (graph0 fill)

typedef __attribute__((ext_vector_type(8))) short bf16x8;
typedef __attribute__((ext_vector_type(4))) float f32x4;

__device__ __forceinline__ ushort f2bf_rne(float x) {
    unsigned int u = __float_as_uint(x);
    return (ushort)((u + 0x7FFFu + ((u >> 16) & 1u)) >> 16);
}
__device__ __forceinline__ float bf2f(ushort h) {
    return __uint_as_float(((unsigned int)h) << 16);
}

// ---------------------------------------------------------------------------
// CSR build: histogram -> 3-phase scan (single concatenated array) -> fill
// ---------------------------------------------------------------------------
__global__ __launch_bounds__(256) void hist_kernel(const int* __restrict__ dst,
                                                   int* __restrict__ cnt, int E) {
    int e = blockIdx.x * blockDim.x + threadIdx.x;
    if (e < E) atomicAdd(&cnt[dst[e]], 1);
}

__global__ __launch_bounds__(256) void scan_partial_kernel(
    const int* __restrict__ cnt, int* __restrict__ bsum, int n) {
    __shared__ int ws[4];
    int b = blockIdx.x, t = threadIdx.x, lane = t & 63, w = t >> 6;
    int base = b * 1024 + t * 4;
    int s = 0;
    if (base + 3 < n) { int4 q = *(const int4*)&cnt[base]; s = q.x + q.y + q.z + q.w; }
    else { for (int i = 0; i < 4; ++i) if (base + i < n) s += cnt[base + i]; }
    #pragma unroll
    for (int off = 32; off; off >>= 1) s += __shfl_down(s, off);
    if (lane == 0) ws[w] = s;
    __syncthreads();
    if (t == 0) bsum[b] = ws[0] + ws[1] + ws[2] + ws[3];
}

__global__ __launch_bounds__(1024) void exscan_kernel(const int* __restrict__ cnt,
                                                      int* __restrict__ rowptr, int n) {
    __shared__ int wsum[17];
    __shared__ int base_s;
    const int t = threadIdx.x;
    const int lane = t & 63;
    const int w = t >> 6;
    if (t == 0) { base_s = 0; rowptr[0] = 0; }
    __syncthreads();
    for (int i0 = 0; i0 < n; i0 += 1024) {
        int i = i0 + t;
        int v = (i < n) ? cnt[i] : 0;
        int x = v;
        #pragma unroll
        for (int off = 1; off < 64; off <<= 1) {
            int y = __shfl_up(x, off);
            if (lane >= off) x += y;
        }
        if (lane == 63) wsum[w] = x;
        __syncthreads();
        if (t == 0) {
            int run = base_s;
            #pragma unroll
            for (int j = 0; j < 16; ++j) { int c = wsum[j]; wsum[j] = run; run += c; }
            wsum[16] = run;
        }
        __syncthreads();
        if (i < n) rowptr[i + 1] = wsum[w] + x;
        __syncthreads();
        if (t == 0) base_s = wsum[16];
        __syncthreads();
    }
}

__global__ __launch_bounds__(256) void scan_final_kernel(
    const int* __restrict__ cnt, const int* __restrict__ boff,
    int* __restrict__ rowptr, int n) {
    __shared__ int wsum[4];
    int b = blockIdx.x, t = threadIdx.x, lane = t & 63, w = t >> 6;
    int base = b * 1024 + t * 4;
    int v0 = 0, v1 = 0, v2 = 0, v3 = 0;
    if (base + 3 < n) { int4 q = *(const int4*)&cnt[base]; v0 = q.x; v1 = q.y; v2 = q.z; v3 = q.w; }
    else {
        if (base + 0 < n) v0 = cnt[base + 0];
        if (base + 1 < n) v1 = cnt[base + 1];
        if (base + 2 < n) v2 = cnt[base + 2];
        if (base + 3 < n) v3 = cnt[base + 3];
    }
    int s = v0 + v1 + v2 + v3;
    int x = s;
    #pragma unroll
    for (int off = 1; off < 64; off <<= 1) {
        int y = __shfl_up(x, off);
        if (lane >= off) x += y;
    }
    if (lane == 63) wsum[w] = x;
    __syncthreads();
    if (t == 0) { int run = 0; for (int i = 0; i < 4; ++i) { int c = wsum[i]; wsum[i] = run; run += c; } }
    __syncthreads();
    int run = boff[b] + wsum[w] + x - s;
    if (base + 0 < n) { run += v0; rowptr[base + 1] = run; }
    if (base + 1 < n) { run += v1; rowptr[base + 2] = run; }
    if (base + 2 < n) { run += v2; rowptr[base + 3] = run; }
    if (base + 3 < n) { run += v3; rowptr[base + 4] = run; }
    if (b == 0 && t == 0) rowptr[0] = 0;
}

// small-graph fill (scatter window small -> L2-friendly)
__global__ __launch_bounds__(256) void fill_kernel(const int* __restrict__ src,
                                                   const int* __restrict__ dst,
                                                   const int* __restrict__ rowptr,
                                                   int rbase,
                                                   int* __restrict__ cursor,
                                                   int* __restrict__ colv, int E) {
    int e = blockIdx.x * blockDim.x + threadIdx.x;
    if (e < E) {
        int d = dst[e];
        int p = atomicAdd(&cursor[d], 1);
        colv[rowptr[d] - rbase + p] = src[e];
    }
}

// ---- graph0 binned fill: coalesced pair scatter, then windowed colv fill ----
__global__ __launch_bounds__(64) void initcur_kernel(const int* __restrict__ rowptr,
                                                     int* __restrict__ cursors,
                                                     int nbins, int N) {
    int b = blockIdx.x * 64 + threadIdx.x;
    if (b < nbins) {
        int idx = b << BIN_SHIFT; if (idx > N) idx = N;
        cursors[b] = rowptr[idx];
    }
}

__global__ __launch_bounds__(256) void binscatter_kernel(
    const int* __restrict__ src, const int* __restrict__ dstv,
    int* __restrict__ cursors, int2* __restrict__ pairs, int E, int nbins) {
    __shared__ int lcnt[128];
    __shared__ int sbase[128];
    int t = threadIdx.x;
    int e0 = blockIdx.x * 4096;
    if (t < 128) lcnt[t] = 0;
    __syncthreads();
    int lrank[16], dloc[16];
    #pragma unroll
    for (int i = 0; i < 16; ++i) {
        int e = e0 + t + i * 256;
        if (e < E) {
            int d = dstv[e];
            dloc[i] = d;
            lrank[i] = atomicAdd(&lcnt[d >> BIN_SHIFT], 1);
        } else dloc[i] = -1;
    }
    __syncthreads();
    if (t < nbins && lcnt[t] > 0) sbase[t] = atomicAdd(&cursors[t], lcnt[t]);
    __syncthreads();
    #pragma unroll
    for (int i = 0; i < 16; ++i) {
        int e = e0 + t + i * 256;
        if (e < E) {
            int d = dloc[i];
            pairs[sbase[d >> BIN_SHIFT] + lrank[i]] = make_int2(d, src[e]);
        }
    }
}

__global__ __launch_bounds__(256) void binfill_kernel(
    const int2* __restrict__ pairs, const int* __restrict__ rowptr,
    int* __restrict__ colv, int N) {
    __shared__ int rp[513];
    __shared__ int cur[512];
    int b = blockIdx.x, t = threadIdx.x;
    int binbase = b << BIN_SHIFT;
    for (int i = t; i < 513; i += 256) {
        int idx = binbase + i; if (idx > N) idx = N;
        rp[i] = rowptr[idx];
    }
    for (int i = t; i < 512; i += 256) cur[i] = 0;
    __syncthreads();
    int beg = rp[0], end = rp[512];
    for (int i = beg + t; i < end; i += 256) {
        int2 pr = pairs[i];
        int local = pr.x - binbase;
        int rank = atomicAdd(&cur[local], 1);
        colv[rp[local] + rank] = pr.y;
    }
}

// ---------------------------------------------------------------------------
// Weight prep: 8 logical 128x128 matrices -> W^T bf16 plane [n][k]
// mats: 0:W0s 1:W0n 2:W1s 3:W1n 4:W2s_top 5:W2s_bot 6:W2n_top 7:W2n_bot
// ---------------------------------------------------------------------------
__global__ __launch_bounds__(256) void wprep_kernel(
    const float* __restrict__ W0s, const float* __restrict__ W0n,
    const float* __restrict__ W1s, const float* __restrict__ W1n,
    const float* __restrict__ W2s, const float* __restrict__ W2n,
    ushort* __restrict__ wt) {
    int gi = blockIdx.x * 256 + threadIdx.x;
    int mi = gi >> 14, idx = gi & 16383;
    int k = idx >> 7, n = idx & 127;
    const float* src; int row = k;
    switch (mi) {
        case 0: src = W0s; break;
        case 1: src = W0n; break;
        case 2: src = W1s; break;
        case 3: src = W1n; break;
        case 4: src = W2s; break;
        case 5: src = W2s; row = k + 128; break;
        case 6: src = W2n; break;
        default: src = W2n; row = k + 128; break;
    }
    wt[(mi << 14) + n * 128 + k] = f2bf_rne(src[row * 128 + n]);
}

// ---------------------------------------------------------------------------
// Register-resident-B MFMA dual GEMM (no LDS, no barriers):
// each wave owns a 32-col slice; B-frags (2ct x 4slab x 2mat = 64 VGPR)
// loaded ONCE, then grid-stride over 16-row tiles streaming A.
// A fp32, split hi/lo bf16 in-register (W bf16-only; W-lo dropped).
// O1 = A@W1 (+bias1)(+C2[ddst[r]]),  O2 = A@W2 (+D2[ddst[r]])
// O2 -> bf16 plane if O2b non-null, else fp32 O2f.
// ---------------------------------------------------------------------------
__global__ __launch_bounds__(256, 4) void dualmm_reg_kernel(
    const float* __restrict__ A,
    const ushort* __restrict__ w1, const ushort* __restrict__ w2,
    const float* __restrict__ bias1,
    const int* __restrict__ ddst,
    const float* __restrict__ C2g, const float* __restrict__ D2g,
    float* __restrict__ O1, float* __restrict__ O2f,
    ushort* __restrict__ O2b, int N, int ntiles) {
    const int tid = threadIdx.x;
    const int wave = tid >> 6, lane = tid & 63;
    const int m = lane & 15, quad = lane >> 4;
    const int colbase = wave * 32;
    // persistent B fragments: [slab][ct][mat]
    bf16x8 bf[4][2][2];
    #pragma unroll
    for (int c = 0; c < 4; ++c)
        #pragma unroll
        for (int ct = 0; ct < 2; ++ct) {
            const size_t bo = (size_t)(colbase + ct * 16 + m) * 128 + c * 32 + quad * 8;
            bf[c][ct][0] = *(const bf16x8*)(w1 + bo);
            bf[c][ct][1] = *(const bf16x8*)(w2 + bo);
        }
    const f32x4 zero = {0.f, 0.f, 0.f, 0.f};

    for (int tile = blockIdx.x; tile < ntiles; tile += gridDim.x) {
        const int r0 = tile * 16;
        int ar = r0 + m; if (ar >= N) ar = N - 1;
        const float* arow = A + (size_t)ar * 128;
        f32x4 acc[2][2];
        acc[0][0] = zero; acc[0][1] = zero; acc[1][0] = zero; acc[1][1] = zero;
        #pragma unroll
        for (int c = 0; c < 4; ++c) {
            float4 a0 = *(const float4*)(arow + c * 32 + quad * 8);
            float4 a1 = *(const float4*)(arow + c * 32 + quad * 8 + 4);
            float av[8] = {a0.x, a0.y, a0.z, a0.w, a1.x, a1.y, a1.z, a1.w};
            bf16x8 afh, afl;
            #pragma unroll
            for (int i = 0; i < 8; ++i) {
                ushort h = f2bf_rne(av[i]);
                ushort l = f2bf_rne(av[i] - bf2f(h));
                afh[i] = (short)h; afl[i] = (short)l;
            }
            #pragma unroll
            for (int ct = 0; ct < 2; ++ct) {
                acc[ct][0] = __builtin_amdgcn_mfma_f32_16x16x32_bf16(afh, bf[c][ct][0], acc[ct][0], 0, 0, 0);
                acc[ct][0] = __builtin_amdgcn_mfma_f32_16x16x32_bf16(afl, bf[c][ct][0], acc[ct][0], 0, 0, 0);
                acc[ct][1] = __builtin_amdgcn_mfma_f32_16x16x32_bf16(afh, bf[c][ct][1], acc[ct][1], 0, 0, 0);
                acc[ct][1] = __builtin_amdgcn_mfma_f32_16x16x32_bf16(afl, bf[c][ct][1], acc[ct][1], 0, 0, 0);
            }
        }
        // epilogue: C/D layout col=lane&15, row=quad*4+reg
        int rr[4], cc[4];
        #pragma unroll
        for (int reg = 0; reg < 4; ++reg) {
            rr[reg] = r0 + quad * 4 + reg;
            cc[reg] = (ddst && rr[reg] < N) ? ddst[rr[reg]] : 0;
        }
        #pragma unroll
        for (int ct = 0; ct < 2; ++ct) {
            const int col = colbase + ct * 16 + m;
            float bv = bias1 ? bias1[col] : 0.f;
            #pragma unroll
            for (int reg = 0; reg < 4; ++reg) {
                int r = rr[reg];
                if (r < N) {
                    float g1 = ddst ? C2g[(size_t)cc[reg] * D_DIM + col] : 0.f;
                    float g2 = ddst ? D2g[(size_t)cc[reg] * D_DIM + col] : 0.f;
                    O1[(size_t)r * D_DIM + col] = acc[ct][0][reg] + bv + g1;
                    float o2v = acc[ct][1][reg] + g2;
                    if (O2b) O2b[(size_t)r * D_DIM + col] = f2bf_rne(o2v);
                    else     O2f[(size_t)r * D_DIM + col] = o2v;
                }
            }
        }
    }
}

// ---------------------------------------------------------------------------
// fp32 CSR gather-aggregate (small graphs): wave/node, float4/lane (2 rows/ld)
// ---------------------------------------------------------------------------
__global__ __launch_bounds__(256) void csr_agg2_kernel(
    const float* __restrict__ feat, const int* __restrict__ rowptr, int rbase,
    const int* __restrict__ colv, const float* __restrict__ addv,
    const float* __restrict__ bias, float* __restrict__ out,
    int Ndst, int do_relu) {
    int gt = blockIdx.x * blockDim.x + threadIdx.x;
    int wid = gt >> 6;
    if (wid >= Ndst) return;
    int lane = threadIdx.x & 63;
    int half = lane >> 5, li = lane & 31;
    const int f4 = li * 4;
    float4 acc = make_float4(0.f, 0.f, 0.f, 0.f);
    int beg = rowptr[wid] - rbase, end = rowptr[wid + 1] - rbase;
    int deg = end - beg;
    int j = beg + half;
    for (; j + 6 < end; j += 8) {
        int r0 = colv[j], r1 = colv[j + 2], r2 = colv[j + 4], r3 = colv[j + 6];
        float4 v0 = *(const float4*)&feat[(size_t)r0 * D_DIM + f4];
        float4 v1 = *(const float4*)&feat[(size_t)r1 * D_DIM + f4];
        float4 v2 = *(const float4*)&feat[(size_t)r2 * D_DIM + f4];
        float4 v3 = *(const float4*)&feat[(size_t)r3 * D_DIM + f4];
        acc.x += v0.x + v1.x + v2.x + v3.x;
        acc.y += v0.y + v1.y + v2.y + v3.y;
        acc.z += v0.z + v1.z + v2.z + v3.z;
        acc.w += v0.w + v1.w + v2.w + v3.w;
    }
    for (; j < end; j += 2) {
        int r = colv[j];
        float4 v = *(const float4*)&feat[(size_t)r * D_DIM + f4];
        acc.x += v.x; acc.y += v.y; acc.z += v.z; acc.w += v.w;
    }
    acc.x += __shfl_xor(acc.x, 32);
    acc.y += __shfl_xor(acc.y, 32);
    acc.z += __shfl_xor(acc.z, 32);
    acc.w += __shfl_xor(acc.w, 32);
    float invd = 1.f / fmaxf((float)deg, 1.f);
    acc.x *= invd; acc.y *= invd; acc.z *= invd; acc.w *= invd;
    if (addv) {
        float4 v = *(const float4*)&addv[(size_t)wid * D_DIM + f4];
        acc.x += v.x; acc.y += v.y; acc.z += v.z; acc.w += v.w;
    }
    if (bias) {
        float4 v = *(const float4*)&bias[f4];
        acc.x += v.x; acc.y += v.y; acc.z += v.z; acc.w += v.w;
    }
    if (do_relu) {
        acc.x = fmaxf(acc.x, 0.f); acc.y = fmaxf(acc.y, 0.f);
        acc.z = fmaxf(acc.z, 0.f); acc.w = fmaxf(acc.w, 0.f);
    }
    if (half == 0)
        *(float4*)&out[(size_t)wid * D_DIM + f4] = acc;
}

// ---------------------------------------------------------------------------
// bf16-input CSR gather-aggregate (big graphs): wave/node, uint4(8 bf16)/lane,
// 16 lanes/row -> 4 rows per load instr, 16 edges in flight. fp32 accumulate.
// Optional fused readout  z = relu(...)@Wm + bm.
// ---------------------------------------------------------------------------
__device__ __forceinline__ void acc8_add(float* acc, uint4 r) {
    acc[0] += __uint_as_float(r.x << 16);
    acc[1] += __uint_as_float(r.x & 0xFFFF0000u);
    acc[2] += __uint_as_float(r.y << 16);
    acc[3] += __uint_as_float(r.y & 0xFFFF0000u);
    acc[4] += __uint_as_float(r.z << 16);
    acc[5] += __uint_as_float(r.z & 0xFFFF0000u);
    acc[6] += __uint_as_float(r.w << 16);
    acc[7] += __uint_as_float(r.w & 0xFFFF0000u);
}

__global__ __launch_bounds__(256) void csr_aggb_kernel(
    const ushort* __restrict__ featb, const int* __restrict__ rowptr, int rbase,
    const int* __restrict__ colv, const float* __restrict__ addv,
    const float* __restrict__ bias, float* __restrict__ out,
    const float* __restrict__ Wm, const float* __restrict__ bm,
    float* __restrict__ z, int Ndst, int do_relu) {
    int gt = blockIdx.x * blockDim.x + threadIdx.x;
    int wid = gt >> 6;
    if (wid >= Ndst) return;
    int lane = threadIdx.x & 63;
    int q = lane >> 4, li = lane & 15;
    const int f8 = li * 8;
    float acc[8];
    #pragma unroll
    for (int i = 0; i < 8; ++i) acc[i] = 0.f;
    int beg = rowptr[wid] - rbase, end = rowptr[wid + 1] - rbase;
    int deg = end - beg;
    int j = beg + q;
    for (; j + 12 < end; j += 16) {
        int r0 = colv[j], r1 = colv[j + 4], r2 = colv[j + 8], r3 = colv[j + 12];
        uint4 v0 = *(const uint4*)&featb[(size_t)r0 * D_DIM + f8];
        uint4 v1 = *(const uint4*)&featb[(size_t)r1 * D_DIM + f8];
        uint4 v2 = *(const uint4*)&featb[(size_t)r2 * D_DIM + f8];
        uint4 v3 = *(const uint4*)&featb[(size_t)r3 * D_DIM + f8];
        acc8_add(acc, v0); acc8_add(acc, v1); acc8_add(acc, v2); acc8_add(acc, v3);
    }
    for (; j < end; j += 4) {
        int r = colv[j];
        uint4 v = *(const uint4*)&featb[(size_t)r * D_DIM + f8];
        acc8_add(acc, v);
    }
    #pragma unroll
    for (int i = 0; i < 8; ++i) {
        acc[i] += __shfl_xor(acc[i], 16);
        acc[i] += __shfl_xor(acc[i], 32);
    }
    float invd = 1.f / fmaxf((float)deg, 1.f);
    #pragma unroll
    for (int i = 0; i < 8; ++i) acc[i] *= invd;
    if (addv) {
        float4 a0 = *(const float4*)&addv[(size_t)wid * D_DIM + f8];
        float4 a1 = *(const float4*)&addv[(size_t)wid * D_DIM + f8 + 4];
        acc[0] += a0.x; acc[1] += a0.y; acc[2] += a0.z; acc[3] += a0.w;
        acc[4] += a1.x; acc[5] += a1.y; acc[6] += a1.z; acc[7] += a1.w;
    }
    if (bias) {
        float4 b0 = *(const float4*)&bias[f8];
        float4 b1 = *(const float4*)&bias[f8 + 4];
        acc[0] += b0.x; acc[1] += b0.y; acc[2] += b0.z; acc[3] += b0.w;
        acc[4] += b1.x; acc[5] += b1.y; acc[6] += b1.z; acc[7] += b1.w;
    }
    if (do_relu) {
        #pragma unroll
        for (int i = 0; i < 8; ++i) acc[i] = fmaxf(acc[i], 0.f);
    }
    if (out && q == 0) {
        *(float4*)&out[(size_t)wid * D_DIM + f8] =
            make_float4(acc[0], acc[1], acc[2], acc[3]);
        *(float4*)&out[(size_t)wid * D_DIM + f8 + 4] =
            make_float4(acc[4], acc[5], acc[6], acc[7]);
    }
    if (z) {
        float4 w0 = *(const float4*)&Wm[f8];
        float4 w1 = *(const float4*)&Wm[f8 + 4];
        float p = acc[0] * w0.x + acc[1] * w0.y + acc[2] * w0.z + acc[3] * w0.w
                + acc[4] * w1.x + acc[5] * w1.y + acc[6] * w1.z + acc[7] * w1.w;
        if (q != 0) p = 0.f;
        #pragma unroll
        for (int off = 32; off > 0; off >>= 1) p += __shfl_down(p, off);
        if (lane == 0) z[wid] = p + bm[0];
    }
}

// ---------------------------------------------------------------------------
// 2-phase online softmax over z[N0]
// ---------------------------------------------------------------------------
__global__ __launch_bounds__(256) void softmax_partial_kernel(
    const float* __restrict__ z, float* __restrict__ red, int N, int nblk) {
    __shared__ float sm[4], ss[4];
    int t = threadIdx.x, b = blockIdx.x;
    int lane = t & 63, w = t >> 6;
    float m = -1e30f, s = 0.f;
    for (int i = b * 256 + t; i < N; i += nblk * 256) {
        float v = z[i];
        if (v > m) { s = s * __expf(m - v) + 1.f; m = v; }
        else s += __expf(v - m);
    }
    #pragma unroll
    for (int off = 32; off > 0; off >>= 1) {
        float mo = __shfl_down(m, off), so = __shfl_down(s, off);
        if (mo > m) { s = s * __expf(m - mo) + so; m = mo; }
        else s += so * __expf(mo - m);
    }
    if (lane == 0) { sm[w] = m; ss[w] = s; }
    __syncthreads();
    if (t == 0) {
        for (int i = 1; i < 4; ++i) {
            float mo = sm[i], so = ss[i];
            if (mo > m) { s = s * __expf(m - mo) + so; m = mo; }
            else s += so * __expf(mo - m);
        }
        red[2 + 2 * b] = m; red[3 + 2 * b] = s;
    }
}

__global__ __launch_bounds__(64) void softmax_merge_kernel(float* __restrict__ red, int B) {
    int t = threadIdx.x;
    float m = -1e30f, s = 0.f;
    if (t < B) { m = red[2 + 2 * t]; s = red[3 + 2 * t]; }
    #pragma unroll
    for (int off = 32; off > 0; off >>= 1) {
        float mo = __shfl_down(m, off), so = __shfl_down(s, off);
        if (mo > m) { s = s * __expf(m - mo) + so; m = mo; }
        else s += so * __expf(mo - m);
    }
    if (t == 0) { red[0] = m; red[1] = s; }
}

__global__ __launch_bounds__(256) void softmax_final_kernel(
    const float* __restrict__ z, const float* __restrict__ red,
    float* __restrict__ out, int N) {
    int i = blockIdx.x * blockDim.x + threadIdx.x;
    if (i < N) out[i] = expf(z[i] - red[0]) / red[1];
}

// ---------------------------------------------------------------------------
// Host launcher
// ---------------------------------------------------------------------------
static inline char* align_up(char* p, size_t a) {
    return (char*)(((uintptr_t)p + a - 1) & ~(uintptr_t)(a - 1));
}

extern "C" void kernel_launch(void* const* d_in, const int* in_sizes, int n_in,
                              void* d_out, int out_size, void* d_ws, size_t ws_size,
                              hipStream_t stream) {
    const int N0 = N0_C, N1 = N1_C, E0 = E0_C, E1 = E1_C;
    const float* X   = (const float*)d_in[0];
    const float* W0s = (const float*)d_in[1];
    const float* W0n = (const float*)d_in[2];
    const float* b0  = (const float*)d_in[3];
    const float* W1s = (const float*)d_in[4];
    const float* W1n = (const float*)d_in[5];
    const float* b1  = (const float*)d_in[6];
    const float* W2s = (const float*)d_in[7];
    const float* W2n = (const float*)d_in[8];
    const float* b2  = (const float*)d_in[9];
    const float* Wm  = (const float*)d_in[10];
    const float* bm  = (const float*)d_in[11];
    const int* src0  = (const int*)d_in[12];
    const int* dst0  = (const int*)d_in[13];
    const int* src1  = (const int*)d_in[14];
    const int* dst1  = (const int*)d_in[15];
    const int* dsrc  = (const int*)d_in[16];
    const int* ddst  = (const int*)d_in[17];
    float* out = (float*)d_out;

    char* p = (char*)d_ws;
    const size_t FB = (size_t)N0 * D_DIM;
    const size_t SB = (size_t)N1 * D_DIM;
    auto grab_f = [&](size_t nf) { p = align_up(p, 256); float* r = (float*)p; p += nf * 4; return r; };
    auto grab_i = [&](size_t ni) { p = align_up(p, 256); int* r = (int*)p; p += ni * 4; return r; };
    auto grab_u = [&](size_t nu) { p = align_up(p, 256); ushort* r = (ushort*)p; p += nu * 2; return r; };

    float* bufA = grab_f(FB);   // y0s -> x0
    float* bufD = grab_f(FB);   // y2s
    float* x1b  = grab_f(SB);
    float* y1s  = grab_f(SB);   // -> x1f
    float* y1n  = grab_f(SB);
    float* C2   = grab_f(SB);
    float* D2   = grab_f(SB);
    float* zbuf = grab_f(N0);
    float* red  = grab_f(256);
    ushort* y0nb = grab_u(FB);  // bf16 neighbor-message planes
    ushort* y2nb = grab_u(FB);
    ushort* wt   = grab_u(8 * 16384);
    const int NC = N0 + 2 * N1;
    int* cntAll = grab_i(NC);
    int* rowptrAll = grab_i(NC + 1);
    int* bsum = grab_i(256);
    int* boff = grab_i(256);
    int* cursors = grab_i(128);
    int* col0 = grab_i(E0);
    int* col1 = grab_i(E1);
    int* colD = grab_i(N0);
    int2* pairbuf = (int2*)grab_i(2 * (size_t)E0);
    (void)ws_size; (void)n_in; (void)in_sizes; (void)out_size;

    const int BT = 256;
    auto cdiv = [](int a, int b) { return (a + b - 1) / b; };
    auto WT = [&](int mi) { return wt + ((size_t)mi << 14); };
    const int nbins0 = (N0 + (1 << BIN_SHIFT) - 1) >> BIN_SHIFT;   // 98
    const int nt0 = cdiv(N0, 16);          // 3125 row tiles
    const int nt1 = cdiv(N1, 16);          // 313
    const int G0 = 1024;                    // grid for big dualmm (16 waves/CU)

    // ---- CSR build ----
    hipMemsetAsync(cntAll, 0, (size_t)NC * 4, stream);
    hist_kernel<<<cdiv(E0, BT), BT, 0, stream>>>(dst0, cntAll, E0);
    hist_kernel<<<cdiv(E1, BT), BT, 0, stream>>>(dst1, cntAll + N0, E1);
    hist_kernel<<<cdiv(N0, BT), BT, 0, stream>>>(ddst, cntAll + N0 + N1, N0);
    const int NB = cdiv(NC, 1024);
    scan_partial_kernel<<<NB, BT, 0, stream>>>(cntAll, bsum, NC);
    exscan_kernel<<<1, 1024, 0, stream>>>(bsum, boff, NB);
    scan_final_kernel<<<NB, BT, 0, stream>>>(cntAll, boff, rowptrAll, NC);
    // graph0: binned two-pass fill (coalesced)
    initcur_kernel<<<2, 64, 0, stream>>>(rowptrAll, cursors, nbins0, N0);
    binscatter_kernel<<<cdiv(E0, 4096), BT, 0, stream>>>(src0, dst0, cursors, pairbuf, E0, nbins0);
    binfill_kernel<<<nbins0, BT, 0, stream>>>(pairbuf, rowptrAll, col0, N0);
    // small graphs: direct fill
    hipMemsetAsync(cntAll + N0, 0, (size_t)(2 * N1) * 4, stream);
    fill_kernel<<<cdiv(E1, BT), BT, 0, stream>>>(src1, dst1, rowptrAll + N0, E0, cntAll + N0, col1, E1);
    fill_kernel<<<cdiv(N0, BT), BT, 0, stream>>>(dsrc, ddst, rowptrAll + N0 + N1, E0 + E1,
                                                 cntAll + N0 + N1, colD, N0);

    // ---- weight prep ----
    wprep_kernel<<<512, BT, 0, stream>>>(W0s, W0n, W1s, W1n, W2s, W2n, wt);

    // ---- layer 0 SAGE: x0 = X@W0s + b0 + mean_nbr(X@W0n) ----
    dualmm_reg_kernel<<<G0, BT, 0, stream>>>(X, WT(0), WT(1), b0,
        nullptr, nullptr, nullptr, bufA, nullptr, y0nb, N0, nt0);
    csr_aggb_kernel<<<cdiv(N0, 4), BT, 0, stream>>>(y0nb, rowptrAll, 0, col0, bufA,
        nullptr, bufA, nullptr, nullptr, nullptr, N0, 0);

    // ---- down pool: x1 = relu(mean_cluster(x0)) ----
    csr_agg2_kernel<<<cdiv(N1, 4), BT, 0, stream>>>(bufA, rowptrAll + N0 + N1, E0 + E1,
        colD, nullptr, nullptr, x1b, N1, 1);

    // ---- layer 1 SAGE ----
    dualmm_reg_kernel<<<nt1, BT, 0, stream>>>(x1b, WT(2), WT(3), b1,
        nullptr, nullptr, nullptr, y1s, y1n, nullptr, N1, nt1);
    csr_agg2_kernel<<<cdiv(N1, 4), BT, 0, stream>>>(y1n, rowptrAll + N0, E0, col1, y1s,
        nullptr, y1s, N1, 1);

    // ---- layer 2: small dualmm (C2/D2 fp32), big dualmm w/ fused up-scatter ----
    dualmm_reg_kernel<<<nt1, BT, 0, stream>>>(y1s, WT(4), WT(6), nullptr,
        nullptr, nullptr, nullptr, C2, D2, nullptr, N1, nt1);
    dualmm_reg_kernel<<<G0, BT, 0, stream>>>(bufA, WT(5), WT(7), nullptr,
        ddst, C2, D2, bufD, nullptr, y2nb, N0, nt0);

    // ---- layer 2 combine + fused readout ----
    csr_aggb_kernel<<<cdiv(N0, 4), BT, 0, stream>>>(y2nb, rowptrAll, 0, col0, bufD,
        b2, nullptr, Wm, bm, zbuf, N0, 1);

    // ---- softmax over nodes ----
    softmax_partial_kernel<<<64, BT, 0, stream>>>(zbuf, red, N0, 64);
    softmax_merge_kernel<<<1, 64, 0, stream>>>(red, 64);
    softmax_final_kernel<<<cdiv(N0, BT), BT, 0, stream>>>(zbuf, red, out, N0);
}

// Round 7
// 375.099 us; speedup vs baseline: 1.3445x; 1.0035x over previous
//
#include <hip/hip_runtime.h>
#include <hip/hip_bf16.h>
#include <cstdint>

#define D_DIM 128
#define N0_C 50000
#define N1_C 5000
#define E0_C 800000
#define E1_C 80000
#define BIN_SHIFT 9          // 512 dst nodes per bin (graph0 fill)

typedef __attribute__((ext_vector_type(8))) short bf16x8;
typedef __attribute__((ext_vector_type(4))) float f32x4;

__device__ __forceinline__ ushort f2bf_rne(float x) {
    unsigned int u = __float_as_uint(x);
    return (ushort)((u + 0x7FFFu + ((u >> 16) & 1u)) >> 16);
}
__device__ __forceinline__ float bf2f(ushort h) {
    return __uint_as_float(((unsigned int)h) << 16);
}
__device__ __forceinline__ int imin(int a, int b) { return a < b ? a : b; }

// ---------------------------------------------------------------------------
// CSR build: one fused histogram over [dst0 | dst1 | ddst]
// ---------------------------------------------------------------------------
__global__ __launch_bounds__(256) void hist_all_kernel(
    const int* __restrict__ dst0, const int* __restrict__ dst1,
    const int* __restrict__ ddst, int* __restrict__ cnt) {
    int e = blockIdx.x * 256 + threadIdx.x;
    if (e < E0_C) atomicAdd(&cnt[dst0[e]], 1);
    else if (e < E0_C + E1_C) atomicAdd(&cnt[N0_C + dst1[e - E0_C]], 1);
    else if (e < E0_C + E1_C + N0_C) atomicAdd(&cnt[N0_C + N1_C + ddst[e - E0_C - E1_C]], 1);
}

__global__ __launch_bounds__(256) void scan_partial_kernel(
    const int* __restrict__ cnt, int* __restrict__ bsum, int n) {
    __shared__ int ws[4];
    int b = blockIdx.x, t = threadIdx.x, lane = t & 63, w = t >> 6;
    int base = b * 1024 + t * 4;
    int s = 0;
    if (base + 3 < n) { int4 q = *(const int4*)&cnt[base]; s = q.x + q.y + q.z + q.w; }
    else { for (int i = 0; i < 4; ++i) if (base + i < n) s += cnt[base + i]; }
    #pragma unroll
    for (int off = 32; off; off >>= 1) s += __shfl_down(s, off);
    if (lane == 0) ws[w] = s;
    __syncthreads();
    if (t == 0) bsum[b] = ws[0] + ws[1] + ws[2] + ws[3];
}

__global__ __launch_bounds__(1024) void exscan_kernel(const int* __restrict__ cnt,
                                                      int* __restrict__ rowptr, int n) {
    __shared__ int wsum[17];
    __shared__ int base_s;
    const int t = threadIdx.x;
    const int lane = t & 63;
    const int w = t >> 6;
    if (t == 0) { base_s = 0; rowptr[0] = 0; }
    __syncthreads();
    for (int i0 = 0; i0 < n; i0 += 1024) {
        int i = i0 + t;
        int v = (i < n) ? cnt[i] : 0;
        int x = v;
        #pragma unroll
        for (int off = 1; off < 64; off <<= 1) {
            int y = __shfl_up(x, off);
            if (lane >= off) x += y;
        }
        if (lane == 63) wsum[w] = x;
        __syncthreads();
        if (t == 0) {
            int run = base_s;
            #pragma unroll
            for (int j = 0; j < 16; ++j) { int c = wsum[j]; wsum[j] = run; run += c; }
            wsum[16] = run;
        }
        __syncthreads();
        if (i < n) rowptr[i + 1] = wsum[w] + x;
        __syncthreads();
        if (t == 0) base_s = wsum[16];
        __syncthreads();
    }
}

// phase 3: intra-block scan + block offset; also emits graph0 bin cursors
__global__ __launch_bounds__(256) void scan_final_kernel(
    const int* __restrict__ cnt, const int* __restrict__ boff,
    int* __restrict__ rowptr, int* __restrict__ cursors, int n) {
    __shared__ int wsum[4];
    int b = blockIdx.x, t = threadIdx.x, lane = t & 63, w = t >> 6;
    int base = b * 1024 + t * 4;
    int v0 = 0, v1 = 0, v2 = 0, v3 = 0;
    if (base + 3 < n) { int4 q = *(const int4*)&cnt[base]; v0 = q.x; v1 = q.y; v2 = q.z; v3 = q.w; }
    else {
        if (base + 0 < n) v0 = cnt[base + 0];
        if (base + 1 < n) v1 = cnt[base + 1];
        if (base + 2 < n) v2 = cnt[base + 2];
        if (base + 3 < n) v3 = cnt[base + 3];
    }
    int s = v0 + v1 + v2 + v3;
    int x = s;
    #pragma unroll
    for (int off = 1; off < 64; off <<= 1) {
        int y = __shfl_up(x, off);
        if (lane >= off) x += y;
    }
    if (lane == 63) wsum[w] = x;
    __syncthreads();
    if (t == 0) { int run = 0; for (int i = 0; i < 4; ++i) { int c = wsum[i]; wsum[i] = run; run += c; } }
    __syncthreads();
    int run = boff[b] + wsum[w] + x - s;
    #pragma unroll
    for (int k = 0; k < 4; ++k) {
        int v = (k == 0) ? v0 : (k == 1) ? v1 : (k == 2) ? v2 : v3;
        int pos = base + k + 1;
        if (pos <= n) {
            run += v;
            rowptr[pos] = run;
            if ((pos & 511) == 0 && pos < N0_C) cursors[pos >> BIN_SHIFT] = run;
        }
    }
    if (b == 0 && t == 0) { rowptr[0] = 0; cursors[0] = 0; }
}

// small-graph fill (scatter window small -> L2-friendly)
__global__ __launch_bounds__(256) void fill_kernel(const int* __restrict__ src,
                                                   const int* __restrict__ dst,
                                                   const int* __restrict__ rowptr,
                                                   int rbase,
                                                   int* __restrict__ cursor,
                                                   int* __restrict__ colv, int E) {
    int e = blockIdx.x * blockDim.x + threadIdx.x;
    if (e < E) {
        int d = dst[e];
        int p = atomicAdd(&cursor[d], 1);
        colv[rowptr[d] - rbase + p] = src[e];
    }
}

// ---- graph0 binned fill: coalesced pair scatter, then windowed colv fill ----
__global__ __launch_bounds__(256) void binscatter_kernel(
    const int* __restrict__ src, const int* __restrict__ dstv,
    int* __restrict__ cursors, int2* __restrict__ pairs, int E, int nbins) {
    __shared__ int lcnt[128];
    __shared__ int sbase[128];
    int t = threadIdx.x;
    int e0 = blockIdx.x * 4096;
    if (t < 128) lcnt[t] = 0;
    __syncthreads();
    int lrank[16], dloc[16];
    #pragma unroll
    for (int i = 0; i < 16; ++i) {
        int e = e0 + t + i * 256;
        if (e < E) {
            int d = dstv[e];
            dloc[i] = d;
            lrank[i] = atomicAdd(&lcnt[d >> BIN_SHIFT], 1);
        } else dloc[i] = -1;
    }
    __syncthreads();
    if (t < nbins && lcnt[t] > 0) sbase[t] = atomicAdd(&cursors[t], lcnt[t]);
    __syncthreads();
    #pragma unroll
    for (int i = 0; i < 16; ++i) {
        int e = e0 + t + i * 256;
        if (e < E) {
            int d = dloc[i];
            pairs[sbase[d >> BIN_SHIFT] + lrank[i]] = make_int2(d, src[e]);
        }
    }
}

__global__ __launch_bounds__(256) void binfill_kernel(
    const int2* __restrict__ pairs, const int* __restrict__ rowptr,
    int* __restrict__ colv, int N) {
    __shared__ int rp[513];
    __shared__ int cur[512];
    int b = blockIdx.x, t = threadIdx.x;
    int binbase = b << BIN_SHIFT;
    for (int i = t; i < 513; i += 256) {
        int idx = binbase + i; if (idx > N) idx = N;
        rp[i] = rowptr[idx];
    }
    for (int i = t; i < 512; i += 256) cur[i] = 0;
    __syncthreads();
    int beg = rp[0], end = rp[512];
    for (int i = beg + t; i < end; i += 256) {
        int2 pr = pairs[i];
        int local = pr.x - binbase;
        int rank = atomicAdd(&cur[local], 1);
        colv[rp[local] + rank] = pr.y;
    }
}

// ---------------------------------------------------------------------------
// Weight prep: 8 logical 128x128 matrices -> W^T bf16 plane [n][k]
// mats: 0:W0s 1:W0n 2:W1s 3:W1n 4:W2s_top 5:W2s_bot 6:W2n_top 7:W2n_bot
// ---------------------------------------------------------------------------
__global__ __launch_bounds__(256) void wprep_kernel(
    const float* __restrict__ W0s, const float* __restrict__ W0n,
    const float* __restrict__ W1s, const float* __restrict__ W1n,
    const float* __restrict__ W2s, const float* __restrict__ W2n,
    ushort* __restrict__ wt) {
    int gi = blockIdx.x * 256 + threadIdx.x;
    int mi = gi >> 14, idx = gi & 16383;
    int k = idx >> 7, n = idx & 127;
    const float* src; int row = k;
    switch (mi) {
        case 0: src = W0s; break;
        case 1: src = W0n; break;
        case 2: src = W1s; break;
        case 3: src = W1n; break;
        case 4: src = W2s; break;
        case 5: src = W2s; row = k + 128; break;
        case 6: src = W2n; break;
        default: src = W2n; row = k + 128; break;
    }
    wt[(mi << 14) + n * 128 + k] = f2bf_rne(src[row * 128 + n]);
}

// ---------------------------------------------------------------------------
// Register-resident-B MFMA dual GEMM, fp32 A (hi/lo split), no LDS/barriers.
// Optional per-row deg normalize+relu on A (rowdeg). Outputs fp32 or bf16.
// ---------------------------------------------------------------------------
__global__ __launch_bounds__(256, 4) void dualmm_reg_kernel(
    const float* __restrict__ A,
    const ushort* __restrict__ w1, const ushort* __restrict__ w2,
    const float* __restrict__ bias1, const int* __restrict__ rowdeg,
    float* __restrict__ O1f, ushort* __restrict__ O1b,
    float* __restrict__ O2f, ushort* __restrict__ O2b, int N, int ntiles) {
    const int tid = threadIdx.x;
    const int wave = tid >> 6, lane = tid & 63;
    const int m = lane & 15, quad = lane >> 4;
    const int colbase = wave * 32;
    bf16x8 bf[4][2][2];
    #pragma unroll
    for (int c = 0; c < 4; ++c)
        #pragma unroll
        for (int ct = 0; ct < 2; ++ct) {
            const size_t bo = (size_t)(colbase + ct * 16 + m) * 128 + c * 32 + quad * 8;
            bf[c][ct][0] = *(const bf16x8*)(w1 + bo);
            bf[c][ct][1] = *(const bf16x8*)(w2 + bo);
        }
    const f32x4 zero = {0.f, 0.f, 0.f, 0.f};

    for (int tile = blockIdx.x; tile < ntiles; tile += gridDim.x) {
        const int r0 = tile * 16;
        int ar = r0 + m; if (ar >= N) ar = N - 1;
        const float* arow = A + (size_t)ar * 128;
        float inv = 1.f;
        if (rowdeg) inv = 1.f / fmaxf((float)rowdeg[ar], 1.f);
        f32x4 acc[2][2];
        acc[0][0] = zero; acc[0][1] = zero; acc[1][0] = zero; acc[1][1] = zero;
        #pragma unroll
        for (int c = 0; c < 4; ++c) {
            float4 a0 = *(const float4*)(arow + c * 32 + quad * 8);
            float4 a1 = *(const float4*)(arow + c * 32 + quad * 8 + 4);
            float av[8] = {a0.x, a0.y, a0.z, a0.w, a1.x, a1.y, a1.z, a1.w};
            bf16x8 afh, afl;
            #pragma unroll
            for (int i = 0; i < 8; ++i) {
                float a = av[i];
                if (rowdeg) a = fmaxf(a * inv, 0.f);
                ushort h = f2bf_rne(a);
                ushort l = f2bf_rne(a - bf2f(h));
                afh[i] = (short)h; afl[i] = (short)l;
            }
            #pragma unroll
            for (int ct = 0; ct < 2; ++ct) {
                acc[ct][0] = __builtin_amdgcn_mfma_f32_16x16x32_bf16(afh, bf[c][ct][0], acc[ct][0], 0, 0, 0);
                acc[ct][0] = __builtin_amdgcn_mfma_f32_16x16x32_bf16(afl, bf[c][ct][0], acc[ct][0], 0, 0, 0);
                acc[ct][1] = __builtin_amdgcn_mfma_f32_16x16x32_bf16(afh, bf[c][ct][1], acc[ct][1], 0, 0, 0);
                acc[ct][1] = __builtin_amdgcn_mfma_f32_16x16x32_bf16(afl, bf[c][ct][1], acc[ct][1], 0, 0, 0);
            }
        }
        #pragma unroll
        for (int ct = 0; ct < 2; ++ct) {
            const int col = colbase + ct * 16 + m;
            float bv = bias1 ? bias1[col] : 0.f;
            #pragma unroll
            for (int reg = 0; reg < 4; ++reg) {
                int r = r0 + quad * 4 + reg;
                if (r < N) {
                    float o1 = acc[ct][0][reg] + bv;
                    float o2 = acc[ct][1][reg];
                    size_t o = (size_t)r * D_DIM + col;
                    if (O1b) O1b[o] = f2bf_rne(o1); else O1f[o] = o1;
                    if (O2b) O2b[o] = f2bf_rne(o2); else O2f[o] = o2;
                }
            }
        }
    }
}

// bf16-A variant (layer-2 big): no split, fused C2/D2 gather-add, bf16 outs.
__global__ __launch_bounds__(256, 4) void dualmm_regb_kernel(
    const ushort* __restrict__ Ab,
    const ushort* __restrict__ w1, const ushort* __restrict__ w2,
    const int* __restrict__ ddst,
    const float* __restrict__ C2g, const float* __restrict__ D2g,
    ushort* __restrict__ O1b, ushort* __restrict__ O2b, int N, int ntiles) {
    const int tid = threadIdx.x;
    const int wave = tid >> 6, lane = tid & 63;
    const int m = lane & 15, quad = lane >> 4;
    const int colbase = wave * 32;
    bf16x8 bf[4][2][2];
    #pragma unroll
    for (int c = 0; c < 4; ++c)
        #pragma unroll
        for (int ct = 0; ct < 2; ++ct) {
            const size_t bo = (size_t)(colbase + ct * 16 + m) * 128 + c * 32 + quad * 8;
            bf[c][ct][0] = *(const bf16x8*)(w1 + bo);
            bf[c][ct][1] = *(const bf16x8*)(w2 + bo);
        }
    const f32x4 zero = {0.f, 0.f, 0.f, 0.f};

    for (int tile = blockIdx.x; tile < ntiles; tile += gridDim.x) {
        const int r0 = tile * 16;
        int ar = r0 + m; if (ar >= N) ar = N - 1;
        const ushort* arow = Ab + (size_t)ar * 128;
        f32x4 acc[2][2];
        acc[0][0] = zero; acc[0][1] = zero; acc[1][0] = zero; acc[1][1] = zero;
        #pragma unroll
        for (int c = 0; c < 4; ++c) {
            bf16x8 af = *(const bf16x8*)(arow + c * 32 + quad * 8);
            #pragma unroll
            for (int ct = 0; ct < 2; ++ct) {
                acc[ct][0] = __builtin_amdgcn_mfma_f32_16x16x32_bf16(af, bf[c][ct][0], acc[ct][0], 0, 0, 0);
                acc[ct][1] = __builtin_amdgcn_mfma_f32_16x16x32_bf16(af, bf[c][ct][1], acc[ct][1], 0, 0, 0);
            }
        }
        int rr[4], cc[4];
        #pragma unroll
        for (int reg = 0; reg < 4; ++reg) {
            rr[reg] = r0 + quad * 4 + reg;
            cc[reg] = (rr[reg] < N) ? ddst[rr[reg]] : 0;
        }
        #pragma unroll
        for (int ct = 0; ct < 2; ++ct) {
            const int col = colbase + ct * 16 + m;
            #pragma unroll
            for (int reg = 0; reg < 4; ++reg) {
                int r = rr[reg];
                if (r < N) {
                    float g1 = C2g[(size_t)cc[reg] * D_DIM + col];
                    float g2 = D2g[(size_t)cc[reg] * D_DIM + col];
                    size_t o = (size_t)r * D_DIM + col;
                    O1b[o] = f2bf_rne(acc[ct][0][reg] + g1);
                    O2b[o] = f2bf_rne(acc[ct][1][reg] + g2);
                }
            }
        }
    }
}

// ---------------------------------------------------------------------------
// fp32 CSR gather-aggregate (small graph1): wave/node, float4/lane
// ---------------------------------------------------------------------------
__global__ __launch_bounds__(256) void csr_agg2_kernel(
    const float* __restrict__ feat, const int* __restrict__ rowptr, int rbase,
    const int* __restrict__ colv, const float* __restrict__ addv,
    float* __restrict__ out, int Ndst, int do_relu) {
    int gt = blockIdx.x * blockDim.x + threadIdx.x;
    int wid = gt >> 6;
    if (wid >= Ndst) return;
    int lane = threadIdx.x & 63;
    int half = lane >> 5, li = lane & 31;
    const int f4 = li * 4;
    float4 acc = make_float4(0.f, 0.f, 0.f, 0.f);
    int beg = rowptr[wid] - rbase, end = rowptr[wid + 1] - rbase;
    int deg = end - beg;
    for (int j = beg + half; j < end; j += 8) {
        int i1 = imin(j + 2, end - 1), i2 = imin(j + 4, end - 1), i3 = imin(j + 6, end - 1);
        int r0 = colv[j], r1 = colv[i1], r2 = colv[i2], r3 = colv[i3];
        float4 v0 = *(const float4*)&feat[(size_t)r0 * D_DIM + f4];
        float4 v1 = *(const float4*)&feat[(size_t)r1 * D_DIM + f4];
        float4 v2 = *(const float4*)&feat[(size_t)r2 * D_DIM + f4];
        float4 v3 = *(const float4*)&feat[(size_t)r3 * D_DIM + f4];
        acc.x += v0.x; acc.y += v0.y; acc.z += v0.z; acc.w += v0.w;
        if (j + 2 < end) { acc.x += v1.x; acc.y += v1.y; acc.z += v1.z; acc.w += v1.w; }
        if (j + 4 < end) { acc.x += v2.x; acc.y += v2.y; acc.z += v2.z; acc.w += v2.w; }
        if (j + 6 < end) { acc.x += v3.x; acc.y += v3.y; acc.z += v3.z; acc.w += v3.w; }
    }
    acc.x += __shfl_xor(acc.x, 32);
    acc.y += __shfl_xor(acc.y, 32);
    acc.z += __shfl_xor(acc.z, 32);
    acc.w += __shfl_xor(acc.w, 32);
    float invd = 1.f / fmaxf((float)deg, 1.f);
    acc.x *= invd; acc.y *= invd; acc.z *= invd; acc.w *= invd;
    if (addv) {
        float4 v = *(const float4*)&addv[(size_t)wid * D_DIM + f4];
        acc.x += v.x; acc.y += v.y; acc.z += v.z; acc.w += v.w;
    }
    if (do_relu) {
        acc.x = fmaxf(acc.x, 0.f); acc.y = fmaxf(acc.y, 0.f);
        acc.z = fmaxf(acc.z, 0.f); acc.w = fmaxf(acc.w, 0.f);
    }
    if (half == 0)
        *(float4*)&out[(size_t)wid * D_DIM + f4] = acc;
}

// ---------------------------------------------------------------------------
// bf16 CSR gather-aggregate (big graph0): wave/node, uint4(8 bf16)/lane,
// clamped-prefetch (4 row-loads always in flight). fp32 accumulate.
// Optional: bf16 addv, bf16 out, atomic pool-scatter, fused readout.
// ---------------------------------------------------------------------------
__device__ __forceinline__ void acc8_add(float* acc, uint4 r) {
    acc[0] += __uint_as_float(r.x << 16);
    acc[1] += __uint_as_float(r.x & 0xFFFF0000u);
    acc[2] += __uint_as_float(r.y << 16);
    acc[3] += __uint_as_float(r.y & 0xFFFF0000u);
    acc[4] += __uint_as_float(r.z << 16);
    acc[5] += __uint_as_float(r.z & 0xFFFF0000u);
    acc[6] += __uint_as_float(r.w << 16);
    acc[7] += __uint_as_float(r.w & 0xFFFF0000u);
}

__global__ __launch_bounds__(256) void csr_aggb_kernel(
    const ushort* __restrict__ featb, const int* __restrict__ rowptr, int rbase,
    const int* __restrict__ colv,
    const ushort* __restrict__ addvb, const float* __restrict__ bias,
    ushort* __restrict__ outb,
    const int* __restrict__ pooldst, float* __restrict__ poolbuf,
    const float* __restrict__ Wm, const float* __restrict__ bm,
    float* __restrict__ z, int Ndst, int do_relu) {
    int gt = blockIdx.x * blockDim.x + threadIdx.x;
    int wid = gt >> 6;
    if (wid >= Ndst) return;
    int lane = threadIdx.x & 63;
    int q = lane >> 4, li = lane & 15;
    const int f8 = li * 8;
    float acc[8];
    #pragma unroll
    for (int i = 0; i < 8; ++i) acc[i] = 0.f;
    int beg = rowptr[wid] - rbase, end = rowptr[wid + 1] - rbase;
    int deg = end - beg;
    for (int j = beg + q; j < end; j += 16) {
        int i1 = imin(j + 4, end - 1), i2 = imin(j + 8, end - 1), i3 = imin(j + 12, end - 1);
        int r0 = colv[j], r1 = colv[i1], r2 = colv[i2], r3 = colv[i3];
        uint4 v0 = *(const uint4*)&featb[(size_t)r0 * D_DIM + f8];
        uint4 v1 = *(const uint4*)&featb[(size_t)r1 * D_DIM + f8];
        uint4 v2 = *(const uint4*)&featb[(size_t)r2 * D_DIM + f8];
        uint4 v3 = *(const uint4*)&featb[(size_t)r3 * D_DIM + f8];
        acc8_add(acc, v0);
        if (j + 4 < end) acc8_add(acc, v1);
        if (j + 8 < end) acc8_add(acc, v2);
        if (j + 12 < end) acc8_add(acc, v3);
    }
    #pragma unroll
    for (int i = 0; i < 8; ++i) {
        acc[i] += __shfl_xor(acc[i], 16);
        acc[i] += __shfl_xor(acc[i], 32);
    }
    float invd = 1.f / fmaxf((float)deg, 1.f);
    #pragma unroll
    for (int i = 0; i < 8; ++i) acc[i] *= invd;
    if (addvb) {
        uint4 a = *(const uint4*)&addvb[(size_t)wid * D_DIM + f8];
        acc8_add(acc, a);
    }
    if (bias) {
        float4 b0 = *(const float4*)&bias[f8];
        float4 b1 = *(const float4*)&bias[f8 + 4];
        acc[0] += b0.x; acc[1] += b0.y; acc[2] += b0.z; acc[3] += b0.w;
        acc[4] += b1.x; acc[5] += b1.y; acc[6] += b1.z; acc[7] += b1.w;
    }
    if (do_relu) {
        #pragma unroll
        for (int i = 0; i < 8; ++i) acc[i] = fmaxf(acc[i], 0.f);
    }
    if (outb && q == 0) {
        uint4 o;
        o.x = (uint)f2bf_rne(acc[0]) | ((uint)f2bf_rne(acc[1]) << 16);
        o.y = (uint)f2bf_rne(acc[2]) | ((uint)f2bf_rne(acc[3]) << 16);
        o.z = (uint)f2bf_rne(acc[4]) | ((uint)f2bf_rne(acc[5]) << 16);
        o.w = (uint)f2bf_rne(acc[6]) | ((uint)f2bf_rne(acc[7]) << 16);
        *(uint4*)&outb[(size_t)wid * D_DIM + f8] = o;
    }
    if (pooldst) {       // cluster-sum scatter: each lane adds 2 feats (by quad)
        int c = pooldst[wid];
        float* pb = &poolbuf[(size_t)c * D_DIM + f8 + 2 * q];
        unsafeAtomicAdd(pb,     acc[2 * q]);
        unsafeAtomicAdd(pb + 1, acc[2 * q + 1]);
    }
    if (z) {
        float4 w0 = *(const float4*)&Wm[f8];
        float4 w1 = *(const float4*)&Wm[f8 + 4];
        float p = acc[0] * w0.x + acc[1] * w0.y + acc[2] * w0.z + acc[3] * w0.w
                + acc[4] * w1.x + acc[5] * w1.y + acc[6] * w1.z + acc[7] * w1.w;
        if (q != 0) p = 0.f;
        #pragma unroll
        for (int off = 32; off > 0; off >>= 1) p += __shfl_down(p, off);
        if (lane == 0) z[wid] = p + bm[0];
    }
}

// ---------------------------------------------------------------------------
// 2-phase online softmax over z[N0]
// ---------------------------------------------------------------------------
__global__ __launch_bounds__(256) void softmax_partial_kernel(
    const float* __restrict__ z, float* __restrict__ red, int N, int nblk) {
    __shared__ float sm[4], ss[4];
    int t = threadIdx.x, b = blockIdx.x;
    int lane = t & 63, w = t >> 6;
    float m = -1e30f, s = 0.f;
    for (int i = b * 256 + t; i < N; i += nblk * 256) {
        float v = z[i];
        if (v > m) { s = s * __expf(m - v) + 1.f; m = v; }
        else s += __expf(v - m);
    }
    #pragma unroll
    for (int off = 32; off > 0; off >>= 1) {
        float mo = __shfl_down(m, off), so = __shfl_down(s, off);
        if (mo > m) { s = s * __expf(m - mo) + so; m = mo; }
        else s += so * __expf(mo - m);
    }
    if (lane == 0) { sm[w] = m; ss[w] = s; }
    __syncthreads();
    if (t == 0) {
        for (int i = 1; i < 4; ++i) {
            float mo = sm[i], so = ss[i];
            if (mo > m) { s = s * __expf(m - mo) + so; m = mo; }
            else s += so * __expf(mo - m);
        }
        red[2 + 2 * b] = m; red[3 + 2 * b] = s;
    }
}

__global__ __launch_bounds__(64) void softmax_merge_kernel(float* __restrict__ red, int B) {
    int t = threadIdx.x;
    float m = -1e30f, s = 0.f;
    if (t < B) { m = red[2 + 2 * t]; s = red[3 + 2 * t]; }
    #pragma unroll
    for (int off = 32; off > 0; off >>= 1) {
        float mo = __shfl_down(m, off), so = __shfl_down(s, off);
        if (mo > m) { s = s * __expf(m - mo) + so; m = mo; }
        else s += so * __expf(mo - m);
    }
    if (t == 0) { red[0] = m; red[1] = s; }
}

__global__ __launch_bounds__(256) void softmax_final_kernel(
    const float* __restrict__ z, const float* __restrict__ red,
    float* __restrict__ out, int N) {
    int i = blockIdx.x * blockDim.x + threadIdx.x;
    if (i < N) out[i] = expf(z[i] - red[0]) / red[1];
}

// ---------------------------------------------------------------------------
// Host launcher
// ---------------------------------------------------------------------------
static inline char* align_up(char* p, size_t a) {
    return (char*)(((uintptr_t)p + a - 1) & ~(uintptr_t)(a - 1));
}

extern "C" void kernel_launch(void* const* d_in, const int* in_sizes, int n_in,
                              void* d_out, int out_size, void* d_ws, size_t ws_size,
                              hipStream_t stream) {
    const int N0 = N0_C, N1 = N1_C, E0 = E0_C, E1 = E1_C;
    const float* X   = (const float*)d_in[0];
    const float* W0s = (const float*)d_in[1];
    const float* W0n = (const float*)d_in[2];
    const float* b0  = (const float*)d_in[3];
    const float* W1s = (const float*)d_in[4];
    const float* W1n = (const float*)d_in[5];
    const float* b1  = (const float*)d_in[6];
    const float* W2s = (const float*)d_in[7];
    const float* W2n = (const float*)d_in[8];
    const float* b2  = (const float*)d_in[9];
    const float* Wm  = (const float*)d_in[10];
    const float* bm  = (const float*)d_in[11];
    const int* src0  = (const int*)d_in[12];
    const int* dst0  = (const int*)d_in[13];
    const int* src1  = (const int*)d_in[14];
    const int* dst1  = (const int*)d_in[15];
    const int* dsrc  = (const int*)d_in[16];
    const int* ddst  = (const int*)d_in[17];
    float* out = (float*)d_out;
    (void)dsrc;

    char* p = (char*)d_ws;
    const size_t FB = (size_t)N0 * D_DIM;
    const size_t SB = (size_t)N1 * D_DIM;
    auto grab_f = [&](size_t nf) { p = align_up(p, 256); float* r = (float*)p; p += nf * 4; return r; };
    auto grab_i = [&](size_t ni) { p = align_up(p, 256); int* r = (int*)p; p += ni * 4; return r; };
    auto grab_u = [&](size_t nu) { p = align_up(p, 256); ushort* r = (ushort*)p; p += nu * 2; return r; };

    const int NC = N0 + 2 * N1;
    // single zero-init region: [cntAll (NC) | cnt2 (N1) | x1accum (SB floats)]
    int* zeroRegion = grab_i((size_t)NC + N1 + SB);
    int* cntAll = zeroRegion;
    int* cnt2 = zeroRegion + NC;
    float* x1accum = (float*)(zeroRegion + NC + N1);
    const int* cntD = cntAll + N0 + N1;      // cluster degrees (from ddst hist)

    float* y1s  = grab_f(SB);   // -> x1f
    float* y1n  = grab_f(SB);
    float* C2   = grab_f(SB);
    float* D2   = grab_f(SB);
    float* zbuf = grab_f(N0);
    float* red  = grab_f(256);
    ushort* y0sb = grab_u(FB);
    ushort* y0nb = grab_u(FB);
    ushort* x0b  = grab_u(FB);
    ushort* y2sb = grab_u(FB);
    ushort* y2nb = grab_u(FB);
    ushort* wt   = grab_u(8 * 16384);
    int* rowptrAll = grab_i(NC + 1);
    int* bsum = grab_i(256);
    int* boff = grab_i(256);
    int* cursors = grab_i(128);
    int* col0 = grab_i(E0);
    int* col1 = grab_i(E1);
    int2* pairbuf = (int2*)grab_i(2 * (size_t)E0);
    (void)ws_size; (void)n_in; (void)in_sizes; (void)out_size;

    const int BT = 256;
    auto cdiv = [](int a, int b) { return (a + b - 1) / b; };
    auto WT = [&](int mi) { return wt + ((size_t)mi << 14); };
    const int nbins0 = (N0 + (1 << BIN_SHIFT) - 1) >> BIN_SHIFT;   // 98
    const int nt0 = cdiv(N0, 16);          // 3125 row tiles
    const int nt1 = cdiv(N1, 16);          // 313
    const int G0 = 1024;

    // ---- one memset: counts + small-fill cursors + x1 accumulator ----
    hipMemsetAsync(zeroRegion, 0, ((size_t)NC + N1 + SB) * 4, stream);

    // ---- CSR build ----
    hist_all_kernel<<<cdiv(E0 + E1 + N0, BT), BT, 0, stream>>>(dst0, dst1, ddst, cntAll);
    const int NB = cdiv(NC, 1024);
    scan_partial_kernel<<<NB, BT, 0, stream>>>(cntAll, bsum, NC);
    exscan_kernel<<<1, 1024, 0, stream>>>(bsum, boff, NB);
    scan_final_kernel<<<NB, BT, 0, stream>>>(cntAll, boff, rowptrAll, cursors, NC);
    binscatter_kernel<<<cdiv(E0, 4096), BT, 0, stream>>>(src0, dst0, cursors, pairbuf, E0, nbins0);
    binfill_kernel<<<nbins0, BT, 0, stream>>>(pairbuf, rowptrAll, col0, N0);
    fill_kernel<<<cdiv(E1, BT), BT, 0, stream>>>(src1, dst1, rowptrAll + N0, E0, cnt2, col1, E1);

    // ---- weight prep ----
    wprep_kernel<<<512, BT, 0, stream>>>(W0s, W0n, W1s, W1n, W2s, W2n, wt);

    // ---- layer 0 SAGE (bf16 outs): y0s = X@W0s + b0 ; y0n = X@W0n ----
    dualmm_reg_kernel<<<G0, BT, 0, stream>>>(X, WT(0), WT(1), b0, nullptr,
        nullptr, y0sb, nullptr, y0nb, N0, nt0);
    // x0 = y0s + mean_nbr(y0n); fused cluster-sum scatter into x1accum
    csr_aggb_kernel<<<cdiv(N0, 4), BT, 0, stream>>>(y0nb, rowptrAll, 0, col0,
        y0sb, nullptr, x0b, ddst, x1accum, nullptr, nullptr, nullptr, N0, 0);

    // ---- layer 1 SAGE (deg-normalize + relu fused into A-load) ----
    dualmm_reg_kernel<<<nt1, BT, 0, stream>>>(x1accum, WT(2), WT(3), b1, cntD,
        y1s, nullptr, y1n, nullptr, N1, nt1);
    csr_agg2_kernel<<<cdiv(N1, 4), BT, 0, stream>>>(y1n, rowptrAll + N0, E0, col1,
        y1s, y1s, N1, 1);

    // ---- layer 2: small dualmm (C2/D2 fp32), big bf16-A dualmm w/ up-scatter ----
    dualmm_reg_kernel<<<nt1, BT, 0, stream>>>(y1s, WT(4), WT(6), nullptr, nullptr,
        C2, nullptr, D2, nullptr, N1, nt1);
    dualmm_regb_kernel<<<G0, BT, 0, stream>>>(x0b, WT(5), WT(7), ddst, C2, D2,
        y2sb, y2nb, N0, nt0);

    // ---- layer 2 combine + fused readout ----
    csr_aggb_kernel<<<cdiv(N0, 4), BT, 0, stream>>>(y2nb, rowptrAll, 0, col0,
        y2sb, b2, nullptr, nullptr, nullptr, Wm, bm, zbuf, N0, 1);

    // ---- softmax over nodes ----
    softmax_partial_kernel<<<64, BT, 0, stream>>>(zbuf, red, N0, 64);
    softmax_merge_kernel<<<1, 64, 0, stream>>>(red, 64);
    softmax_final_kernel<<<cdiv(N0, BT), BT, 0, stream>>>(zbuf, red, out, N0);
}

// Round 8
// 354.266 us; speedup vs baseline: 1.4235x; 1.0588x over previous
//
#include <hip/hip_runtime.h>
#include <hip/hip_bf16.h>
#include <cstdint>

#define D_DIM 128
#define N0_C 50000
#define N1_C 5000
#define E0_C 800000
#define E1_C 80000
#define BIN_SHIFT 9          // 512 dst nodes per bin (graph0 fill)

typedef __attribute__((ext_vector_type(8))) short bf16x8;
typedef __attribute__((ext_vector_type(4))) float f32x4;

__device__ __forceinline__ ushort f2bf_rne(float x) {
    unsigned int u = __float_as_uint(x);
    return (ushort)((u + 0x7FFFu + ((u >> 16) & 1u)) >> 16);
}
__device__ __forceinline__ float bf2f(ushort h) {
    return __uint_as_float(((unsigned int)h) << 16);
}
__device__ __forceinline__ int imin(int a, int b) { return a < b ? a : b; }

// ---------------------------------------------------------------------------
// CSR build: one fused histogram over [dst0 | dst1 | ddst]
// ---------------------------------------------------------------------------
__global__ __launch_bounds__(256) void hist_all_kernel(
    const int* __restrict__ dst0, const int* __restrict__ dst1,
    const int* __restrict__ ddst, int* __restrict__ cnt) {
    int e = blockIdx.x * 256 + threadIdx.x;
    if (e < E0_C) atomicAdd(&cnt[dst0[e]], 1);
    else if (e < E0_C + E1_C) atomicAdd(&cnt[N0_C + dst1[e - E0_C]], 1);
    else if (e < E0_C + E1_C + N0_C) atomicAdd(&cnt[N0_C + N1_C + ddst[e - E0_C - E1_C]], 1);
}

__global__ __launch_bounds__(256) void scan_partial_kernel(
    const int* __restrict__ cnt, int* __restrict__ bsum, int n) {
    __shared__ int ws[4];
    int b = blockIdx.x, t = threadIdx.x, lane = t & 63, w = t >> 6;
    int base = b * 1024 + t * 4;
    int s = 0;
    if (base + 3 < n) { int4 q = *(const int4*)&cnt[base]; s = q.x + q.y + q.z + q.w; }
    else { for (int i = 0; i < 4; ++i) if (base + i < n) s += cnt[base + i]; }
    #pragma unroll
    for (int off = 32; off; off >>= 1) s += __shfl_down(s, off);
    if (lane == 0) ws[w] = s;
    __syncthreads();
    if (t == 0) bsum[b] = ws[0] + ws[1] + ws[2] + ws[3];
}

__global__ __launch_bounds__(1024) void exscan_kernel(const int* __restrict__ cnt,
                                                      int* __restrict__ rowptr, int n) {
    __shared__ int wsum[17];
    __shared__ int base_s;
    const int t = threadIdx.x;
    const int lane = t & 63;
    const int w = t >> 6;
    if (t == 0) { base_s = 0; rowptr[0] = 0; }
    __syncthreads();
    for (int i0 = 0; i0 < n; i0 += 1024) {
        int i = i0 + t;
        int v = (i < n) ? cnt[i] : 0;
        int x = v;
        #pragma unroll
        for (int off = 1; off < 64; off <<= 1) {
            int y = __shfl_up(x, off);
            if (lane >= off) x += y;
        }
        if (lane == 63) wsum[w] = x;
        __syncthreads();
        if (t == 0) {
            int run = base_s;
            #pragma unroll
            for (int j = 0; j < 16; ++j) { int c = wsum[j]; wsum[j] = run; run += c; }
            wsum[16] = run;
        }
        __syncthreads();
        if (i < n) rowptr[i + 1] = wsum[w] + x;
        __syncthreads();
        if (t == 0) base_s = wsum[16];
        __syncthreads();
    }
}

// phase 3: intra-block scan + block offset; also emits graph0 bin cursors
__global__ __launch_bounds__(256) void scan_final_kernel(
    const int* __restrict__ cnt, const int* __restrict__ boff,
    int* __restrict__ rowptr, int* __restrict__ cursors, int n) {
    __shared__ int wsum[4];
    int b = blockIdx.x, t = threadIdx.x, lane = t & 63, w = t >> 6;
    int base = b * 1024 + t * 4;
    int v0 = 0, v1 = 0, v2 = 0, v3 = 0;
    if (base + 3 < n) { int4 q = *(const int4*)&cnt[base]; v0 = q.x; v1 = q.y; v2 = q.z; v3 = q.w; }
    else {
        if (base + 0 < n) v0 = cnt[base + 0];
        if (base + 1 < n) v1 = cnt[base + 1];
        if (base + 2 < n) v2 = cnt[base + 2];
        if (base + 3 < n) v3 = cnt[base + 3];
    }
    int s = v0 + v1 + v2 + v3;
    int x = s;
    #pragma unroll
    for (int off = 1; off < 64; off <<= 1) {
        int y = __shfl_up(x, off);
        if (lane >= off) x += y;
    }
    if (lane == 63) wsum[w] = x;
    __syncthreads();
    if (t == 0) { int run = 0; for (int i = 0; i < 4; ++i) { int c = wsum[i]; wsum[i] = run; run += c; } }
    __syncthreads();
    int run = boff[b] + wsum[w] + x - s;
    #pragma unroll
    for (int k = 0; k < 4; ++k) {
        int v = (k == 0) ? v0 : (k == 1) ? v1 : (k == 2) ? v2 : v3;
        int pos = base + k + 1;
        if (pos <= n) {
            run += v;
            rowptr[pos] = run;
            if ((pos & 511) == 0 && pos < N0_C) cursors[pos >> BIN_SHIFT] = run;
        }
    }
    if (b == 0 && t == 0) { rowptr[0] = 0; cursors[0] = 0; }
}

// small-graph fill (scatter window small -> L2-friendly)
__global__ __launch_bounds__(256) void fill_kernel(const int* __restrict__ src,
                                                   const int* __restrict__ dst,
                                                   const int* __restrict__ rowptr,
                                                   int rbase,
                                                   int* __restrict__ cursor,
                                                   int* __restrict__ colv, int E) {
    int e = blockIdx.x * blockDim.x + threadIdx.x;
    if (e < E) {
        int d = dst[e];
        int p = atomicAdd(&cursor[d], 1);
        colv[rowptr[d] - rbase + p] = src[e];
    }
}

// ---- graph0 binned fill: coalesced pair scatter, then windowed colv fill ----
__global__ __launch_bounds__(256) void binscatter_kernel(
    const int* __restrict__ src, const int* __restrict__ dstv,
    int* __restrict__ cursors, int2* __restrict__ pairs, int E, int nbins) {
    __shared__ int lcnt[128];
    __shared__ int sbase[128];
    int t = threadIdx.x;
    int e0 = blockIdx.x * 4096;
    if (t < 128) lcnt[t] = 0;
    __syncthreads();
    int lrank[16], dloc[16];
    #pragma unroll
    for (int i = 0; i < 16; ++i) {
        int e = e0 + t + i * 256;
        if (e < E) {
            int d = dstv[e];
            dloc[i] = d;
            lrank[i] = atomicAdd(&lcnt[d >> BIN_SHIFT], 1);
        } else dloc[i] = -1;
    }
    __syncthreads();
    if (t < nbins && lcnt[t] > 0) sbase[t] = atomicAdd(&cursors[t], lcnt[t]);
    __syncthreads();
    #pragma unroll
    for (int i = 0; i < 16; ++i) {
        int e = e0 + t + i * 256;
        if (e < E) {
            int d = dloc[i];
            pairs[sbase[d >> BIN_SHIFT] + lrank[i]] = make_int2(d, src[e]);
        }
    }
}

__global__ __launch_bounds__(256) void binfill_kernel(
    const int2* __restrict__ pairs, const int* __restrict__ rowptr,
    int* __restrict__ colv, int N) {
    __shared__ int rp[513];
    __shared__ int cur[512];
    int b = blockIdx.x, t = threadIdx.x;
    int binbase = b << BIN_SHIFT;
    for (int i = t; i < 513; i += 256) {
        int idx = binbase + i; if (idx > N) idx = N;
        rp[i] = rowptr[idx];
    }
    for (int i = t; i < 512; i += 256) cur[i] = 0;
    __syncthreads();
    int beg = rp[0], end = rp[512];
    for (int i = beg + t; i < end; i += 256) {
        int2 pr = pairs[i];
        int local = pr.x - binbase;
        int rank = atomicAdd(&cur[local], 1);
        colv[rp[local] + rank] = pr.y;
    }
}

// ---------------------------------------------------------------------------
// Weight prep: 8 logical 128x128 matrices -> W^T bf16 plane [n][k]
// mats: 0:W0s 1:W0n 2:W1s 3:W1n 4:W2s_top 5:W2s_bot 6:W2n_top 7:W2n_bot
// ---------------------------------------------------------------------------
__global__ __launch_bounds__(256) void wprep_kernel(
    const float* __restrict__ W0s, const float* __restrict__ W0n,
    const float* __restrict__ W1s, const float* __restrict__ W1n,
    const float* __restrict__ W2s, const float* __restrict__ W2n,
    ushort* __restrict__ wt) {
    int gi = blockIdx.x * 256 + threadIdx.x;
    int mi = gi >> 14, idx = gi & 16383;
    int k = idx >> 7, n = idx & 127;
    const float* src; int row = k;
    switch (mi) {
        case 0: src = W0s; break;
        case 1: src = W0n; break;
        case 2: src = W1s; break;
        case 3: src = W1n; break;
        case 4: src = W2s; break;
        case 5: src = W2s; row = k + 128; break;
        case 6: src = W2n; break;
        default: src = W2n; row = k + 128; break;
    }
    wt[(mi << 14) + n * 128 + k] = f2bf_rne(src[row * 128 + n]);
}

// ---------------------------------------------------------------------------
// Register-resident-B MFMA dual GEMM, fp32 A (hi/lo split), no LDS/barriers.
// ---------------------------------------------------------------------------
__global__ __launch_bounds__(256, 4) void dualmm_reg_kernel(
    const float* __restrict__ A,
    const ushort* __restrict__ w1, const ushort* __restrict__ w2,
    const float* __restrict__ bias1,
    float* __restrict__ O1f, ushort* __restrict__ O1b,
    float* __restrict__ O2f, ushort* __restrict__ O2b, int N, int ntiles) {
    const int tid = threadIdx.x;
    const int wave = tid >> 6, lane = tid & 63;
    const int m = lane & 15, quad = lane >> 4;
    const int colbase = wave * 32;
    bf16x8 bf[4][2][2];
    #pragma unroll
    for (int c = 0; c < 4; ++c)
        #pragma unroll
        for (int ct = 0; ct < 2; ++ct) {
            const size_t bo = (size_t)(colbase + ct * 16 + m) * 128 + c * 32 + quad * 8;
            bf[c][ct][0] = *(const bf16x8*)(w1 + bo);
            bf[c][ct][1] = *(const bf16x8*)(w2 + bo);
        }
    const f32x4 zero = {0.f, 0.f, 0.f, 0.f};

    for (int tile = blockIdx.x; tile < ntiles; tile += gridDim.x) {
        const int r0 = tile * 16;
        int ar = r0 + m; if (ar >= N) ar = N - 1;
        const float* arow = A + (size_t)ar * 128;
        f32x4 acc[2][2];
        acc[0][0] = zero; acc[0][1] = zero; acc[1][0] = zero; acc[1][1] = zero;
        #pragma unroll
        for (int c = 0; c < 4; ++c) {
            float4 a0 = *(const float4*)(arow + c * 32 + quad * 8);
            float4 a1 = *(const float4*)(arow + c * 32 + quad * 8 + 4);
            float av[8] = {a0.x, a0.y, a0.z, a0.w, a1.x, a1.y, a1.z, a1.w};
            bf16x8 afh, afl;
            #pragma unroll
            for (int i = 0; i < 8; ++i) {
                ushort h = f2bf_rne(av[i]);
                ushort l = f2bf_rne(av[i] - bf2f(h));
                afh[i] = (short)h; afl[i] = (short)l;
            }
            #pragma unroll
            for (int ct = 0; ct < 2; ++ct) {
                acc[ct][0] = __builtin_amdgcn_mfma_f32_16x16x32_bf16(afh, bf[c][ct][0], acc[ct][0], 0, 0, 0);
                acc[ct][0] = __builtin_amdgcn_mfma_f32_16x16x32_bf16(afl, bf[c][ct][0], acc[ct][0], 0, 0, 0);
                acc[ct][1] = __builtin_amdgcn_mfma_f32_16x16x32_bf16(afh, bf[c][ct][1], acc[ct][1], 0, 0, 0);
                acc[ct][1] = __builtin_amdgcn_mfma_f32_16x16x32_bf16(afl, bf[c][ct][1], acc[ct][1], 0, 0, 0);
            }
        }
        #pragma unroll
        for (int ct = 0; ct < 2; ++ct) {
            const int col = colbase + ct * 16 + m;
            float bv = bias1 ? bias1[col] : 0.f;
            #pragma unroll
            for (int reg = 0; reg < 4; ++reg) {
                int r = r0 + quad * 4 + reg;
                if (r < N) {
                    float o1 = acc[ct][0][reg] + bv;
                    float o2 = acc[ct][1][reg];
                    size_t o = (size_t)r * D_DIM + col;
                    if (O1b) O1b[o] = f2bf_rne(o1); else O1f[o] = o1;
                    if (O2b) O2b[o] = f2bf_rne(o2); else O2f[o] = o2;
                }
            }
        }
    }
}

// bf16-A variant: no split; optional bias, optional C2/D2 gather-add,
// fp32-or-bf16 outputs.
__global__ __launch_bounds__(256, 4) void dualmm_regb_kernel(
    const ushort* __restrict__ Ab,
    const ushort* __restrict__ w1, const ushort* __restrict__ w2,
    const float* __restrict__ bias1,
    const int* __restrict__ ddst,
    const float* __restrict__ C2g, const float* __restrict__ D2g,
    float* __restrict__ O1f, ushort* __restrict__ O1b,
    float* __restrict__ O2f, ushort* __restrict__ O2b, int N, int ntiles) {
    const int tid = threadIdx.x;
    const int wave = tid >> 6, lane = tid & 63;
    const int m = lane & 15, quad = lane >> 4;
    const int colbase = wave * 32;
    bf16x8 bf[4][2][2];
    #pragma unroll
    for (int c = 0; c < 4; ++c)
        #pragma unroll
        for (int ct = 0; ct < 2; ++ct) {
            const size_t bo = (size_t)(colbase + ct * 16 + m) * 128 + c * 32 + quad * 8;
            bf[c][ct][0] = *(const bf16x8*)(w1 + bo);
            bf[c][ct][1] = *(const bf16x8*)(w2 + bo);
        }
    const f32x4 zero = {0.f, 0.f, 0.f, 0.f};

    for (int tile = blockIdx.x; tile < ntiles; tile += gridDim.x) {
        const int r0 = tile * 16;
        int ar = r0 + m; if (ar >= N) ar = N - 1;
        const ushort* arow = Ab + (size_t)ar * 128;
        f32x4 acc[2][2];
        acc[0][0] = zero; acc[0][1] = zero; acc[1][0] = zero; acc[1][1] = zero;
        #pragma unroll
        for (int c = 0; c < 4; ++c) {
            bf16x8 af = *(const bf16x8*)(arow + c * 32 + quad * 8);
            #pragma unroll
            for (int ct = 0; ct < 2; ++ct) {
                acc[ct][0] = __builtin_amdgcn_mfma_f32_16x16x32_bf16(af, bf[c][ct][0], acc[ct][0], 0, 0, 0);
                acc[ct][1] = __builtin_amdgcn_mfma_f32_16x16x32_bf16(af, bf[c][ct][1], acc[ct][1], 0, 0, 0);
            }
        }
        int rr[4], cc[4];
        #pragma unroll
        for (int reg = 0; reg < 4; ++reg) {
            rr[reg] = r0 + quad * 4 + reg;
            cc[reg] = (ddst && rr[reg] < N) ? ddst[rr[reg]] : 0;
        }
        #pragma unroll
        for (int ct = 0; ct < 2; ++ct) {
            const int col = colbase + ct * 16 + m;
            float bv = bias1 ? bias1[col] : 0.f;
            #pragma unroll
            for (int reg = 0; reg < 4; ++reg) {
                int r = rr[reg];
                if (r < N) {
                    float g1 = ddst ? C2g[(size_t)cc[reg] * D_DIM + col] : 0.f;
                    float g2 = ddst ? D2g[(size_t)cc[reg] * D_DIM + col] : 0.f;
                    float o1 = acc[ct][0][reg] + bv + g1;
                    float o2 = acc[ct][1][reg] + g2;
                    size_t o = (size_t)r * D_DIM + col;
                    if (O1b) O1b[o] = f2bf_rne(o1); else O1f[o] = o1;
                    if (O2b) O2b[o] = f2bf_rne(o2); else O2f[o] = o2;
                }
            }
        }
    }
}

// ---------------------------------------------------------------------------
// fp32 CSR gather-aggregate (small graph1): wave/node, float4/lane
// ---------------------------------------------------------------------------
__global__ __launch_bounds__(256) void csr_agg2_kernel(
    const float* __restrict__ feat, const int* __restrict__ rowptr, int rbase,
    const int* __restrict__ colv, const float* __restrict__ addv,
    float* __restrict__ out, int Ndst, int do_relu) {
    int gt = blockIdx.x * blockDim.x + threadIdx.x;
    int wid = gt >> 6;
    if (wid >= Ndst) return;
    int lane = threadIdx.x & 63;
    int half = lane >> 5, li = lane & 31;
    const int f4 = li * 4;
    float4 acc = make_float4(0.f, 0.f, 0.f, 0.f);
    int beg = rowptr[wid] - rbase, end = rowptr[wid + 1] - rbase;
    int deg = end - beg;
    for (int j = beg + half; j < end; j += 8) {
        int i1 = imin(j + 2, end - 1), i2 = imin(j + 4, end - 1), i3 = imin(j + 6, end - 1);
        int r0 = colv[j], r1 = colv[i1], r2 = colv[i2], r3 = colv[i3];
        float4 v0 = *(const float4*)&feat[(size_t)r0 * D_DIM + f4];
        float4 v1 = *(const float4*)&feat[(size_t)r1 * D_DIM + f4];
        float4 v2 = *(const float4*)&feat[(size_t)r2 * D_DIM + f4];
        float4 v3 = *(const float4*)&feat[(size_t)r3 * D_DIM + f4];
        acc.x += v0.x; acc.y += v0.y; acc.z += v0.z; acc.w += v0.w;
        if (j + 2 < end) { acc.x += v1.x; acc.y += v1.y; acc.z += v1.z; acc.w += v1.w; }
        if (j + 4 < end) { acc.x += v2.x; acc.y += v2.y; acc.z += v2.z; acc.w += v2.w; }
        if (j + 6 < end) { acc.x += v3.x; acc.y += v3.y; acc.z += v3.z; acc.w += v3.w; }
    }
    acc.x += __shfl_xor(acc.x, 32);
    acc.y += __shfl_xor(acc.y, 32);
    acc.z += __shfl_xor(acc.z, 32);
    acc.w += __shfl_xor(acc.w, 32);
    float invd = 1.f / fmaxf((float)deg, 1.f);
    acc.x *= invd; acc.y *= invd; acc.z *= invd; acc.w *= invd;
    if (addv) {
        float4 v = *(const float4*)&addv[(size_t)wid * D_DIM + f4];
        acc.x += v.x; acc.y += v.y; acc.z += v.z; acc.w += v.w;
    }
    if (do_relu) {
        acc.x = fmaxf(acc.x, 0.f); acc.y = fmaxf(acc.y, 0.f);
        acc.z = fmaxf(acc.z, 0.f); acc.w = fmaxf(acc.w, 0.f);
    }
    if (half == 0)
        *(float4*)&out[(size_t)wid * D_DIM + f4] = acc;
}

// ---------------------------------------------------------------------------
// bf16 CSR gather-aggregate: wave/node, uint4(8 bf16)/lane, 8 clamped
// row-loads in flight (latency-bound gather). fp32 accumulate.
// ---------------------------------------------------------------------------
__device__ __forceinline__ void acc8_add(float* acc, uint4 r) {
    acc[0] += __uint_as_float(r.x << 16);
    acc[1] += __uint_as_float(r.x & 0xFFFF0000u);
    acc[2] += __uint_as_float(r.y << 16);
    acc[3] += __uint_as_float(r.y & 0xFFFF0000u);
    acc[4] += __uint_as_float(r.z << 16);
    acc[5] += __uint_as_float(r.z & 0xFFFF0000u);
    acc[6] += __uint_as_float(r.w << 16);
    acc[7] += __uint_as_float(r.w & 0xFFFF0000u);
}

__global__ __launch_bounds__(256) void csr_aggb_kernel(
    const ushort* __restrict__ featb, const int* __restrict__ rowptr, int rbase,
    const int* __restrict__ colv,
    const ushort* __restrict__ addvb, const float* __restrict__ bias,
    ushort* __restrict__ outb,
    const float* __restrict__ Wm, const float* __restrict__ bm,
    float* __restrict__ z, int Ndst, int do_relu) {
    int gt = blockIdx.x * blockDim.x + threadIdx.x;
    int wid = gt >> 6;
    if (wid >= Ndst) return;
    int lane = threadIdx.x & 63;
    int q = lane >> 4, li = lane & 15;
    const int f8 = li * 8;
    float acc[8];
    #pragma unroll
    for (int i = 0; i < 8; ++i) acc[i] = 0.f;
    int beg = rowptr[wid] - rbase, end = rowptr[wid + 1] - rbase;
    int deg = end - beg;
    for (int j = beg + q; j < end; j += 32) {
        int idx[8]; uint4 v[8];
        #pragma unroll
        for (int k = 0; k < 8; ++k) idx[k] = imin(j + 4 * k, end - 1);
        #pragma unroll
        for (int k = 0; k < 8; ++k) {
            int r = colv[idx[k]];
            v[k] = *(const uint4*)&featb[(size_t)r * D_DIM + f8];
        }
        acc8_add(acc, v[0]);
        #pragma unroll
        for (int k = 1; k < 8; ++k)
            if (j + 4 * k < end) acc8_add(acc, v[k]);
    }
    #pragma unroll
    for (int i = 0; i < 8; ++i) {
        acc[i] += __shfl_xor(acc[i], 16);
        acc[i] += __shfl_xor(acc[i], 32);
    }
    float invd = 1.f / fmaxf((float)deg, 1.f);
    #pragma unroll
    for (int i = 0; i < 8; ++i) acc[i] *= invd;
    if (addvb) {
        uint4 a = *(const uint4*)&addvb[(size_t)wid * D_DIM + f8];
        acc8_add(acc, a);
    }
    if (bias) {
        float4 b0 = *(const float4*)&bias[f8];
        float4 b1 = *(const float4*)&bias[f8 + 4];
        acc[0] += b0.x; acc[1] += b0.y; acc[2] += b0.z; acc[3] += b0.w;
        acc[4] += b1.x; acc[5] += b1.y; acc[6] += b1.z; acc[7] += b1.w;
    }
    if (do_relu) {
        #pragma unroll
        for (int i = 0; i < 8; ++i) acc[i] = fmaxf(acc[i], 0.f);
    }
    if (outb && q == 0) {
        uint4 o;
        o.x = (uint)f2bf_rne(acc[0]) | ((uint)f2bf_rne(acc[1]) << 16);
        o.y = (uint)f2bf_rne(acc[2]) | ((uint)f2bf_rne(acc[3]) << 16);
        o.z = (uint)f2bf_rne(acc[4]) | ((uint)f2bf_rne(acc[5]) << 16);
        o.w = (uint)f2bf_rne(acc[6]) | ((uint)f2bf_rne(acc[7]) << 16);
        *(uint4*)&outb[(size_t)wid * D_DIM + f8] = o;
    }
    if (z) {
        float4 w0 = *(const float4*)&Wm[f8];
        float4 w1 = *(const float4*)&Wm[f8 + 4];
        float p = acc[0] * w0.x + acc[1] * w0.y + acc[2] * w0.z + acc[3] * w0.w
                + acc[4] * w1.x + acc[5] * w1.y + acc[6] * w1.z + acc[7] * w1.w;
        if (q != 0) p = 0.f;
        #pragma unroll
        for (int off = 32; off > 0; off >>= 1) p += __shfl_down(p, off);
        if (lane == 0) z[wid] = p + bm[0];
    }
}

// ---------------------------------------------------------------------------
// 2-phase online softmax over z[N0]
// ---------------------------------------------------------------------------
__global__ __launch_bounds__(256) void softmax_partial_kernel(
    const float* __restrict__ z, float* __restrict__ red, int N, int nblk) {
    __shared__ float sm[4], ss[4];
    int t = threadIdx.x, b = blockIdx.x;
    int lane = t & 63, w = t >> 6;
    float m = -1e30f, s = 0.f;
    for (int i = b * 256 + t; i < N; i += nblk * 256) {
        float v = z[i];
        if (v > m) { s = s * __expf(m - v) + 1.f; m = v; }
        else s += __expf(v - m);
    }
    #pragma unroll
    for (int off = 32; off > 0; off >>= 1) {
        float mo = __shfl_down(m, off), so = __shfl_down(s, off);
        if (mo > m) { s = s * __expf(m - mo) + so; m = mo; }
        else s += so * __expf(mo - m);
    }
    if (lane == 0) { sm[w] = m; ss[w] = s; }
    __syncthreads();
    if (t == 0) {
        for (int i = 1; i < 4; ++i) {
            float mo = sm[i], so = ss[i];
            if (mo > m) { s = s * __expf(m - mo) + so; m = mo; }
            else s += so * __expf(mo - m);
        }
        red[2 + 2 * b] = m; red[3 + 2 * b] = s;
    }
}

__global__ __launch_bounds__(64) void softmax_merge_kernel(float* __restrict__ red, int B) {
    int t = threadIdx.x;
    float m = -1e30f, s = 0.f;
    if (t < B) { m = red[2 + 2 * t]; s = red[3 + 2 * t]; }
    #pragma unroll
    for (int off = 32; off > 0; off >>= 1) {
        float mo = __shfl_down(m, off), so = __shfl_down(s, off);
        if (mo > m) { s = s * __expf(m - mo) + so; m = mo; }
        else s += so * __expf(mo - m);
    }
    if (t == 0) { red[0] = m; red[1] = s; }
}

__global__ __launch_bounds__(256) void softmax_final_kernel(
    const float* __restrict__ z, const float* __restrict__ red,
    float* __restrict__ out, int N) {
    int i = blockIdx.x * blockDim.x + threadIdx.x;
    if (i < N) out[i] = expf(z[i] - red[0]) / red[1];
}

// ---------------------------------------------------------------------------
// Host launcher
// ---------------------------------------------------------------------------
static inline char* align_up(char* p, size_t a) {
    return (char*)(((uintptr_t)p + a - 1) & ~(uintptr_t)(a - 1));
}

extern "C" void kernel_launch(void* const* d_in, const int* in_sizes, int n_in,
                              void* d_out, int out_size, void* d_ws, size_t ws_size,
                              hipStream_t stream) {
    const int N0 = N0_C, N1 = N1_C, E0 = E0_C, E1 = E1_C;
    const float* X   = (const float*)d_in[0];
    const float* W0s = (const float*)d_in[1];
    const float* W0n = (const float*)d_in[2];
    const float* b0  = (const float*)d_in[3];
    const float* W1s = (const float*)d_in[4];
    const float* W1n = (const float*)d_in[5];
    const float* b1  = (const float*)d_in[6];
    const float* W2s = (const float*)d_in[7];
    const float* W2n = (const float*)d_in[8];
    const float* b2  = (const float*)d_in[9];
    const float* Wm  = (const float*)d_in[10];
    const float* bm  = (const float*)d_in[11];
    const int* src0  = (const int*)d_in[12];
    const int* dst0  = (const int*)d_in[13];
    const int* src1  = (const int*)d_in[14];
    const int* dst1  = (const int*)d_in[15];
    const int* dsrc  = (const int*)d_in[16];
    const int* ddst  = (const int*)d_in[17];
    float* out = (float*)d_out;

    char* p = (char*)d_ws;
    const size_t FB = (size_t)N0 * D_DIM;
    const size_t SB = (size_t)N1 * D_DIM;
    auto grab_f = [&](size_t nf) { p = align_up(p, 256); float* r = (float*)p; p += nf * 4; return r; };
    auto grab_i = [&](size_t ni) { p = align_up(p, 256); int* r = (int*)p; p += ni * 4; return r; };
    auto grab_u = [&](size_t nu) { p = align_up(p, 256); ushort* r = (ushort*)p; p += nu * 2; return r; };

    const int NC = N0 + 2 * N1;
    // single zero-init region: [cntAll (NC) | cnt2 (N1) | cntD2 (N1)]
    int* zeroRegion = grab_i((size_t)NC + 2 * N1);
    int* cntAll = zeroRegion;
    int* cnt2 = zeroRegion + NC;            // graph1 fill cursors
    int* cntD2 = zeroRegion + NC + N1;      // down-edge fill cursors

    float* y1s  = grab_f(SB);   // -> x1f
    float* y1n  = grab_f(SB);
    float* C2   = grab_f(SB);
    float* D2   = grab_f(SB);
    float* zbuf = grab_f(N0);
    float* red  = grab_f(256);
    ushort* y0sb = grab_u(FB);
    ushort* y0nb = grab_u(FB);
    ushort* x0b  = grab_u(FB);
    ushort* y2sb = grab_u(FB);
    ushort* y2nb = grab_u(FB);
    ushort* x1bb = grab_u(SB);
    ushort* wt   = grab_u(8 * 16384);
    int* rowptrAll = grab_i(NC + 1);
    int* bsum = grab_i(256);
    int* boff = grab_i(256);
    int* cursors = grab_i(128);
    int* col0 = grab_i(E0);
    int* col1 = grab_i(E1);
    int* colD = grab_i(N0);
    int2* pairbuf = (int2*)grab_i(2 * (size_t)E0);
    (void)ws_size; (void)n_in; (void)in_sizes; (void)out_size;

    const int BT = 256;
    auto cdiv = [](int a, int b) { return (a + b - 1) / b; };
    auto WT = [&](int mi) { return wt + ((size_t)mi << 14); };
    const int nbins0 = (N0 + (1 << BIN_SHIFT) - 1) >> BIN_SHIFT;   // 98
    const int nt0 = cdiv(N0, 16);          // 3125 row tiles
    const int nt1 = cdiv(N1, 16);          // 313
    const int G0 = 1024;

    // ---- one memset for all cursors/counters ----
    hipMemsetAsync(zeroRegion, 0, ((size_t)NC + 2 * N1) * 4, stream);

    // ---- CSR build ----
    hist_all_kernel<<<cdiv(E0 + E1 + N0, BT), BT, 0, stream>>>(dst0, dst1, ddst, cntAll);
    const int NB = cdiv(NC, 1024);
    scan_partial_kernel<<<NB, BT, 0, stream>>>(cntAll, bsum, NC);
    exscan_kernel<<<1, 1024, 0, stream>>>(bsum, boff, NB);
    scan_final_kernel<<<NB, BT, 0, stream>>>(cntAll, boff, rowptrAll, cursors, NC);
    binscatter_kernel<<<cdiv(E0, 4096), BT, 0, stream>>>(src0, dst0, cursors, pairbuf, E0, nbins0);
    binfill_kernel<<<nbins0, BT, 0, stream>>>(pairbuf, rowptrAll, col0, N0);
    fill_kernel<<<cdiv(E1, BT), BT, 0, stream>>>(src1, dst1, rowptrAll + N0, E0, cnt2, col1, E1);
    fill_kernel<<<cdiv(N0, BT), BT, 0, stream>>>(dsrc, ddst, rowptrAll + N0 + N1, E0 + E1,
                                                 cntD2, colD, N0);

    // ---- weight prep ----
    wprep_kernel<<<512, BT, 0, stream>>>(W0s, W0n, W1s, W1n, W2s, W2n, wt);

    // ---- layer 0 SAGE (bf16 outs): y0s = X@W0s + b0 ; y0n = X@W0n ----
    dualmm_reg_kernel<<<G0, BT, 0, stream>>>(X, WT(0), WT(1), b0,
        nullptr, y0sb, nullptr, y0nb, N0, nt0);
    // x0 = y0s + mean_nbr(y0n)  (bf16 out)
    csr_aggb_kernel<<<cdiv(N0, 4), BT, 0, stream>>>(y0nb, rowptrAll, 0, col0,
        y0sb, nullptr, x0b, nullptr, nullptr, nullptr, N0, 0);

    // ---- down pool: x1 = relu(mean_cluster(x0))  (bf16 gather, no atomics) ----
    csr_aggb_kernel<<<cdiv(N1, 4), BT, 0, stream>>>(x0b, rowptrAll + N0 + N1, E0 + E1,
        colD, nullptr, nullptr, x1bb, nullptr, nullptr, nullptr, N1, 1);

    // ---- layer 1 SAGE (bf16 A) ----
    dualmm_regb_kernel<<<nt1, BT, 0, stream>>>(x1bb, WT(2), WT(3), b1,
        nullptr, nullptr, nullptr, y1s, nullptr, y1n, nullptr, N1, nt1);
    csr_agg2_kernel<<<cdiv(N1, 4), BT, 0, stream>>>(y1n, rowptrAll + N0, E0, col1,
        y1s, y1s, N1, 1);

    // ---- layer 2: small dualmm (fp32 A, C2/D2 fp32), big bf16-A w/ up-scatter ----
    dualmm_reg_kernel<<<nt1, BT, 0, stream>>>(y1s, WT(4), WT(6), nullptr,
        C2, nullptr, D2, nullptr, N1, nt1);
    dualmm_regb_kernel<<<G0, BT, 0, stream>>>(x0b, WT(5), WT(7), nullptr,
        ddst, C2, D2, nullptr, y2sb, nullptr, y2nb, N0, nt0);

    // ---- layer 2 combine + fused readout ----
    csr_aggb_kernel<<<cdiv(N0, 4), BT, 0, stream>>>(y2nb, rowptrAll, 0, col0,
        y2sb, b2, nullptr, Wm, bm, zbuf, N0, 1);

    // ---- softmax over nodes ----
    softmax_partial_kernel<<<64, BT, 0, stream>>>(zbuf, red, N0, 64);
    softmax_merge_kernel<<<1, 64, 0, stream>>>(red, 64);
    softmax_final_kernel<<<cdiv(N0, BT), BT, 0, stream>>>(zbuf, red, out, N0);
}

// Round 9
// 351.282 us; speedup vs baseline: 1.4356x; 1.0085x over previous
//
#include <hip/hip_runtime.h>
#include <hip/hip_bf16.h>
#include <cstdint>

#define D_DIM 128
#define N0_C 50000
#define N1_C 5000
#define E0_C 800000
#define E1_C 80000
#define BIN_SHIFT 9          // 512 dst nodes per bin (graph0 fill)

typedef __attribute__((ext_vector_type(8))) short bf16x8;
typedef __attribute__((ext_vector_type(4))) float f32x4;

__device__ __forceinline__ ushort f2bf_rne(float x) {
    unsigned int u = __float_as_uint(x);
    return (ushort)((u + 0x7FFFu + ((u >> 16) & 1u)) >> 16);
}
__device__ __forceinline__ float bf2f(ushort h) {
    return __uint_as_float(((unsigned int)h) << 16);
}
__device__ __forceinline__ int imin(int a, int b) { return a < b ? a : b; }
__device__ __forceinline__ int imax(int a, int b) { return a > b ? a : b; }

// ---------------------------------------------------------------------------
// CSR build: one fused histogram over [dst0 | dst1 | ddst]
// ---------------------------------------------------------------------------
__global__ __launch_bounds__(256) void hist_all_kernel(
    const int* __restrict__ dst0, const int* __restrict__ dst1,
    const int* __restrict__ ddst, int* __restrict__ cnt) {
    int e = blockIdx.x * 256 + threadIdx.x;
    if (e < E0_C) atomicAdd(&cnt[dst0[e]], 1);
    else if (e < E0_C + E1_C) atomicAdd(&cnt[N0_C + dst1[e - E0_C]], 1);
    else if (e < E0_C + E1_C + N0_C) atomicAdd(&cnt[N0_C + N1_C + ddst[e - E0_C - E1_C]], 1);
}

__global__ __launch_bounds__(256) void scan_partial_kernel(
    const int* __restrict__ cnt, int* __restrict__ bsum, int n) {
    __shared__ int ws[4];
    int b = blockIdx.x, t = threadIdx.x, lane = t & 63, w = t >> 6;
    int base = b * 1024 + t * 4;
    int s = 0;
    if (base + 3 < n) { int4 q = *(const int4*)&cnt[base]; s = q.x + q.y + q.z + q.w; }
    else { for (int i = 0; i < 4; ++i) if (base + i < n) s += cnt[base + i]; }
    #pragma unroll
    for (int off = 32; off; off >>= 1) s += __shfl_down(s, off);
    if (lane == 0) ws[w] = s;
    __syncthreads();
    if (t == 0) bsum[b] = ws[0] + ws[1] + ws[2] + ws[3];
}

__global__ __launch_bounds__(1024) void exscan_kernel(const int* __restrict__ cnt,
                                                      int* __restrict__ rowptr, int n) {
    __shared__ int wsum[17];
    __shared__ int base_s;
    const int t = threadIdx.x;
    const int lane = t & 63;
    const int w = t >> 6;
    if (t == 0) { base_s = 0; rowptr[0] = 0; }
    __syncthreads();
    for (int i0 = 0; i0 < n; i0 += 1024) {
        int i = i0 + t;
        int v = (i < n) ? cnt[i] : 0;
        int x = v;
        #pragma unroll
        for (int off = 1; off < 64; off <<= 1) {
            int y = __shfl_up(x, off);
            if (lane >= off) x += y;
        }
        if (lane == 63) wsum[w] = x;
        __syncthreads();
        if (t == 0) {
            int run = base_s;
            #pragma unroll
            for (int j = 0; j < 16; ++j) { int c = wsum[j]; wsum[j] = run; run += c; }
            wsum[16] = run;
        }
        __syncthreads();
        if (i < n) rowptr[i + 1] = wsum[w] + x;
        __syncthreads();
        if (t == 0) base_s = wsum[16];
        __syncthreads();
    }
}

// phase 3: intra-block scan + block offset; also emits graph0 bin cursors
__global__ __launch_bounds__(256) void scan_final_kernel(
    const int* __restrict__ cnt, const int* __restrict__ boff,
    int* __restrict__ rowptr, int* __restrict__ cursors, int n) {
    __shared__ int wsum[4];
    int b = blockIdx.x, t = threadIdx.x, lane = t & 63, w = t >> 6;
    int base = b * 1024 + t * 4;
    int v0 = 0, v1 = 0, v2 = 0, v3 = 0;
    if (base + 3 < n) { int4 q = *(const int4*)&cnt[base]; v0 = q.x; v1 = q.y; v2 = q.z; v3 = q.w; }
    else {
        if (base + 0 < n) v0 = cnt[base + 0];
        if (base + 1 < n) v1 = cnt[base + 1];
        if (base + 2 < n) v2 = cnt[base + 2];
        if (base + 3 < n) v3 = cnt[base + 3];
    }
    int s = v0 + v1 + v2 + v3;
    int x = s;
    #pragma unroll
    for (int off = 1; off < 64; off <<= 1) {
        int y = __shfl_up(x, off);
        if (lane >= off) x += y;
    }
    if (lane == 63) wsum[w] = x;
    __syncthreads();
    if (t == 0) { int run = 0; for (int i = 0; i < 4; ++i) { int c = wsum[i]; wsum[i] = run; run += c; } }
    __syncthreads();
    int run = boff[b] + wsum[w] + x - s;
    #pragma unroll
    for (int k = 0; k < 4; ++k) {
        int v = (k == 0) ? v0 : (k == 1) ? v1 : (k == 2) ? v2 : v3;
        int pos = base + k + 1;
        if (pos <= n) {
            run += v;
            rowptr[pos] = run;
            if ((pos & 511) == 0 && pos < N0_C) cursors[pos >> BIN_SHIFT] = run;
        }
    }
    if (b == 0 && t == 0) { rowptr[0] = 0; cursors[0] = 0; }
}

// merged small fill: graph1 edges then down edges (small windows, L2-friendly)
__global__ __launch_bounds__(256) void fill_small_kernel(
    const int* __restrict__ src1, const int* __restrict__ dst1,
    const int* __restrict__ dsrc, const int* __restrict__ ddst,
    const int* __restrict__ rowptrAll,
    int* __restrict__ cur1, int* __restrict__ curD,
    int* __restrict__ col1, int* __restrict__ colD) {
    int e = blockIdx.x * 256 + threadIdx.x;
    if (e < E1_C) {
        int d = dst1[e];
        int p = atomicAdd(&cur1[d], 1);
        col1[rowptrAll[N0_C + d] - E0_C + p] = src1[e];
    } else if (e < E1_C + N0_C) {
        int i = e - E1_C;
        int d = ddst[i];
        int p = atomicAdd(&curD[d], 1);
        colD[rowptrAll[N0_C + N1_C + d] - E0_C - E1_C + p] = dsrc[i];
    }
}

// ---- graph0 binned fill: packed (local<<17|src) scatter, then windowed fill
__global__ __launch_bounds__(256) void binscatter_kernel(
    const int* __restrict__ src, const int* __restrict__ dstv,
    int* __restrict__ cursors, int* __restrict__ pairs, int E, int nbins) {
    __shared__ int lcnt[128];
    __shared__ int sbase[128];
    int t = threadIdx.x;
    int e0 = blockIdx.x * 4096;
    if (t < 128) lcnt[t] = 0;
    __syncthreads();
    int lrank[16], dloc[16];
    #pragma unroll
    for (int i = 0; i < 16; ++i) {
        int e = e0 + t + i * 256;
        if (e < E) {
            int d = dstv[e];
            dloc[i] = d;
            lrank[i] = atomicAdd(&lcnt[d >> BIN_SHIFT], 1);
        } else dloc[i] = -1;
    }
    __syncthreads();
    if (t < nbins && lcnt[t] > 0) sbase[t] = atomicAdd(&cursors[t], lcnt[t]);
    __syncthreads();
    #pragma unroll
    for (int i = 0; i < 16; ++i) {
        int e = e0 + t + i * 256;
        if (e < E) {
            int d = dloc[i];
            int key = ((d & ((1 << BIN_SHIFT) - 1)) << 17) | src[e];
            pairs[sbase[d >> BIN_SHIFT] + lrank[i]] = key;
        }
    }
}

__global__ __launch_bounds__(256) void binfill_kernel(
    const int* __restrict__ pairs, const int* __restrict__ rowptr,
    int* __restrict__ colv, int N) {
    __shared__ int rp[513];
    __shared__ int cur[512];
    int b = blockIdx.x, t = threadIdx.x;
    int binbase = b << BIN_SHIFT;
    for (int i = t; i < 513; i += 256) {
        int idx = binbase + i; if (idx > N) idx = N;
        rp[i] = rowptr[idx];
    }
    for (int i = t; i < 512; i += 256) cur[i] = 0;
    __syncthreads();
    int beg = rp[0], end = rp[512];
    for (int i = beg + t; i < end; i += 256) {
        int key = pairs[i];
        int local = key >> 17;
        int rank = atomicAdd(&cur[local], 1);
        colv[rp[local] + rank] = key & 0x1FFFF;
    }
}

// ---------------------------------------------------------------------------
// Weight prep: 8 logical 128x128 matrices -> W^T bf16 plane [n][k]
// ---------------------------------------------------------------------------
__global__ __launch_bounds__(256) void wprep_kernel(
    const float* __restrict__ W0s, const float* __restrict__ W0n,
    const float* __restrict__ W1s, const float* __restrict__ W1n,
    const float* __restrict__ W2s, const float* __restrict__ W2n,
    ushort* __restrict__ wt) {
    int gi = blockIdx.x * 256 + threadIdx.x;
    int mi = gi >> 14, idx = gi & 16383;
    int k = idx >> 7, n = idx & 127;
    const float* src; int row = k;
    switch (mi) {
        case 0: src = W0s; break;
        case 1: src = W0n; break;
        case 2: src = W1s; break;
        case 3: src = W1n; break;
        case 4: src = W2s; break;
        case 5: src = W2s; row = k + 128; break;
        case 6: src = W2n; break;
        default: src = W2n; row = k + 128; break;
    }
    wt[(mi << 14) + n * 128 + k] = f2bf_rne(src[row * 128 + n]);
}

// ---------------------------------------------------------------------------
// Register-resident-B MFMA dual GEMM, fp32 A (hi/lo split), no LDS/barriers.
// bf16 outs use shfl-paired 4B packed stores.
// ---------------------------------------------------------------------------
__global__ __launch_bounds__(256, 4) void dualmm_reg_kernel(
    const float* __restrict__ A,
    const ushort* __restrict__ w1, const ushort* __restrict__ w2,
    const float* __restrict__ bias1,
    float* __restrict__ O1f, ushort* __restrict__ O1b,
    float* __restrict__ O2f, ushort* __restrict__ O2b, int N, int ntiles) {
    const int tid = threadIdx.x;
    const int wave = tid >> 6, lane = tid & 63;
    const int m = lane & 15, quad = lane >> 4;
    const int colbase = wave * 32;
    bf16x8 bf[4][2][2];
    #pragma unroll
    for (int c = 0; c < 4; ++c)
        #pragma unroll
        for (int ct = 0; ct < 2; ++ct) {
            const size_t bo = (size_t)(colbase + ct * 16 + m) * 128 + c * 32 + quad * 8;
            bf[c][ct][0] = *(const bf16x8*)(w1 + bo);
            bf[c][ct][1] = *(const bf16x8*)(w2 + bo);
        }
    const f32x4 zero = {0.f, 0.f, 0.f, 0.f};

    for (int tile = blockIdx.x; tile < ntiles; tile += gridDim.x) {
        const int r0 = tile * 16;
        int ar = r0 + m; if (ar >= N) ar = N - 1;
        const float* arow = A + (size_t)ar * 128;
        f32x4 acc[2][2];
        acc[0][0] = zero; acc[0][1] = zero; acc[1][0] = zero; acc[1][1] = zero;
        #pragma unroll
        for (int c = 0; c < 4; ++c) {
            float4 a0 = *(const float4*)(arow + c * 32 + quad * 8);
            float4 a1 = *(const float4*)(arow + c * 32 + quad * 8 + 4);
            float av[8] = {a0.x, a0.y, a0.z, a0.w, a1.x, a1.y, a1.z, a1.w};
            bf16x8 afh, afl;
            #pragma unroll
            for (int i = 0; i < 8; ++i) {
                ushort h = f2bf_rne(av[i]);
                ushort l = f2bf_rne(av[i] - bf2f(h));
                afh[i] = (short)h; afl[i] = (short)l;
            }
            #pragma unroll
            for (int ct = 0; ct < 2; ++ct) {
                acc[ct][0] = __builtin_amdgcn_mfma_f32_16x16x32_bf16(afh, bf[c][ct][0], acc[ct][0], 0, 0, 0);
                acc[ct][0] = __builtin_amdgcn_mfma_f32_16x16x32_bf16(afl, bf[c][ct][0], acc[ct][0], 0, 0, 0);
                acc[ct][1] = __builtin_amdgcn_mfma_f32_16x16x32_bf16(afh, bf[c][ct][1], acc[ct][1], 0, 0, 0);
                acc[ct][1] = __builtin_amdgcn_mfma_f32_16x16x32_bf16(afl, bf[c][ct][1], acc[ct][1], 0, 0, 0);
            }
        }
        #pragma unroll
        for (int ct = 0; ct < 2; ++ct) {
            const int col = colbase + ct * 16 + m;
            float bv = bias1 ? bias1[col] : 0.f;
            #pragma unroll
            for (int reg = 0; reg < 4; ++reg) {
                int r = r0 + quad * 4 + reg;
                float o1 = acc[ct][0][reg] + bv;
                float o2 = acc[ct][1][reg];
                if (O1b) {
                    uint u1 = f2bf_rne(o1), u2 = f2bf_rne(o2);
                    uint p1 = (uint)__shfl_xor((int)u1, 1);
                    uint p2 = (uint)__shfl_xor((int)u2, 1);
                    if (r < N && !(m & 1)) {
                        size_t o = (size_t)r * D_DIM + col;
                        *(uint*)&O1b[o] = u1 | (p1 << 16);
                        *(uint*)&O2b[o] = u2 | (p2 << 16);
                    }
                } else if (r < N) {
                    size_t o = (size_t)r * D_DIM + col;
                    O1f[o] = o1; O2f[o] = o2;
                }
            }
        }
    }
}

// bf16-A variant: no split; optional bias, optional C2/D2 gather-add,
// fp32-or-bf16 outputs (bf16 path uses packed stores).
__global__ __launch_bounds__(256, 4) void dualmm_regb_kernel(
    const ushort* __restrict__ Ab,
    const ushort* __restrict__ w1, const ushort* __restrict__ w2,
    const float* __restrict__ bias1,
    const int* __restrict__ ddst,
    const float* __restrict__ C2g, const float* __restrict__ D2g,
    float* __restrict__ O1f, ushort* __restrict__ O1b,
    float* __restrict__ O2f, ushort* __restrict__ O2b, int N, int ntiles) {
    const int tid = threadIdx.x;
    const int wave = tid >> 6, lane = tid & 63;
    const int m = lane & 15, quad = lane >> 4;
    const int colbase = wave * 32;
    bf16x8 bf[4][2][2];
    #pragma unroll
    for (int c = 0; c < 4; ++c)
        #pragma unroll
        for (int ct = 0; ct < 2; ++ct) {
            const size_t bo = (size_t)(colbase + ct * 16 + m) * 128 + c * 32 + quad * 8;
            bf[c][ct][0] = *(const bf16x8*)(w1 + bo);
            bf[c][ct][1] = *(const bf16x8*)(w2 + bo);
        }
    const f32x4 zero = {0.f, 0.f, 0.f, 0.f};

    for (int tile = blockIdx.x; tile < ntiles; tile += gridDim.x) {
        const int r0 = tile * 16;
        int ar = r0 + m; if (ar >= N) ar = N - 1;
        const ushort* arow = Ab + (size_t)ar * 128;
        f32x4 acc[2][2];
        acc[0][0] = zero; acc[0][1] = zero; acc[1][0] = zero; acc[1][1] = zero;
        #pragma unroll
        for (int c = 0; c < 4; ++c) {
            bf16x8 af = *(const bf16x8*)(arow + c * 32 + quad * 8);
            #pragma unroll
            for (int ct = 0; ct < 2; ++ct) {
                acc[ct][0] = __builtin_amdgcn_mfma_f32_16x16x32_bf16(af, bf[c][ct][0], acc[ct][0], 0, 0, 0);
                acc[ct][1] = __builtin_amdgcn_mfma_f32_16x16x32_bf16(af, bf[c][ct][1], acc[ct][1], 0, 0, 0);
            }
        }
        int rr[4], cc[4];
        #pragma unroll
        for (int reg = 0; reg < 4; ++reg) {
            rr[reg] = r0 + quad * 4 + reg;
            cc[reg] = (ddst && rr[reg] < N) ? ddst[rr[reg]] : 0;
        }
        #pragma unroll
        for (int ct = 0; ct < 2; ++ct) {
            const int col = colbase + ct * 16 + m;
            float bv = bias1 ? bias1[col] : 0.f;
            #pragma unroll
            for (int reg = 0; reg < 4; ++reg) {
                int r = rr[reg];
                float g1 = (ddst && r < N) ? C2g[(size_t)cc[reg] * D_DIM + col] : 0.f;
                float g2 = (ddst && r < N) ? D2g[(size_t)cc[reg] * D_DIM + col] : 0.f;
                float o1 = acc[ct][0][reg] + bv + g1;
                float o2 = acc[ct][1][reg] + g2;
                if (O1b) {
                    uint u1 = f2bf_rne(o1), u2 = f2bf_rne(o2);
                    uint p1 = (uint)__shfl_xor((int)u1, 1);
                    uint p2 = (uint)__shfl_xor((int)u2, 1);
                    if (r < N && !(m & 1)) {
                        size_t o = (size_t)r * D_DIM + col;
                        *(uint*)&O1b[o] = u1 | (p1 << 16);
                        *(uint*)&O2b[o] = u2 | (p2 << 16);
                    }
                } else if (r < N) {
                    size_t o = (size_t)r * D_DIM + col;
                    O1f[o] = o1; O2f[o] = o2;
                }
            }
        }
    }
}

// ---------------------------------------------------------------------------
// fp32 CSR gather-aggregate (small graph1): wave/node, float4/lane
// ---------------------------------------------------------------------------
__global__ __launch_bounds__(256) void csr_agg2_kernel(
    const float* __restrict__ feat, const int* __restrict__ rowptr, int rbase,
    const int* __restrict__ colv, const float* __restrict__ addv,
    float* __restrict__ out, int Ndst, int do_relu) {
    int gt = blockIdx.x * blockDim.x + threadIdx.x;
    int wid = gt >> 6;
    if (wid >= Ndst) return;
    int lane = threadIdx.x & 63;
    int half = lane >> 5, li = lane & 31;
    const int f4 = li * 4;
    float4 acc = make_float4(0.f, 0.f, 0.f, 0.f);
    int beg = rowptr[wid] - rbase, end = rowptr[wid + 1] - rbase;
    int deg = end - beg;
    for (int j = beg + half; j < end; j += 8) {
        int i1 = imin(j + 2, end - 1), i2 = imin(j + 4, end - 1), i3 = imin(j + 6, end - 1);
        int r0 = colv[j], r1 = colv[i1], r2 = colv[i2], r3 = colv[i3];
        float4 v0 = *(const float4*)&feat[(size_t)r0 * D_DIM + f4];
        float4 v1 = *(const float4*)&feat[(size_t)r1 * D_DIM + f4];
        float4 v2 = *(const float4*)&feat[(size_t)r2 * D_DIM + f4];
        float4 v3 = *(const float4*)&feat[(size_t)r3 * D_DIM + f4];
        acc.x += v0.x; acc.y += v0.y; acc.z += v0.z; acc.w += v0.w;
        if (j + 2 < end) { acc.x += v1.x; acc.y += v1.y; acc.z += v1.z; acc.w += v1.w; }
        if (j + 4 < end) { acc.x += v2.x; acc.y += v2.y; acc.z += v2.z; acc.w += v2.w; }
        if (j + 6 < end) { acc.x += v3.x; acc.y += v3.y; acc.z += v3.z; acc.w += v3.w; }
    }
    acc.x += __shfl_xor(acc.x, 32);
    acc.y += __shfl_xor(acc.y, 32);
    acc.z += __shfl_xor(acc.z, 32);
    acc.w += __shfl_xor(acc.w, 32);
    float invd = 1.f / fmaxf((float)deg, 1.f);
    acc.x *= invd; acc.y *= invd; acc.z *= invd; acc.w *= invd;
    if (addv) {
        float4 v = *(const float4*)&addv[(size_t)wid * D_DIM + f4];
        acc.x += v.x; acc.y += v.y; acc.z += v.z; acc.w += v.w;
    }
    if (do_relu) {
        acc.x = fmaxf(acc.x, 0.f); acc.y = fmaxf(acc.y, 0.f);
        acc.z = fmaxf(acc.z, 0.f); acc.w = fmaxf(acc.w, 0.f);
    }
    if (half == 0)
        *(float4*)&out[(size_t)wid * D_DIM + f4] = acc;
}

// ---------------------------------------------------------------------------
// bf16 CSR gather-aggregate, TWO nodes per wave: uint4(8 bf16)/lane,
// 8 distinct row-misses in flight per lane. fp32 accumulate.
// ---------------------------------------------------------------------------
__device__ __forceinline__ void acc8_add(float* acc, uint4 r) {
    acc[0] += __uint_as_float(r.x << 16);
    acc[1] += __uint_as_float(r.x & 0xFFFF0000u);
    acc[2] += __uint_as_float(r.y << 16);
    acc[3] += __uint_as_float(r.y & 0xFFFF0000u);
    acc[4] += __uint_as_float(r.z << 16);
    acc[5] += __uint_as_float(r.z & 0xFFFF0000u);
    acc[6] += __uint_as_float(r.w << 16);
    acc[7] += __uint_as_float(r.w & 0xFFFF0000u);
}

__global__ __launch_bounds__(256) void csr_aggb_kernel(
    const ushort* __restrict__ featb, const int* __restrict__ rowptr, int rbase,
    const int* __restrict__ colv,
    const ushort* __restrict__ addvb, const float* __restrict__ bias,
    ushort* __restrict__ outb,
    const float* __restrict__ Wm, const float* __restrict__ bm,
    float* __restrict__ z, int Ndst, int do_relu) {
    int gt = blockIdx.x * blockDim.x + threadIdx.x;
    int wp = gt >> 6;                 // wave id -> nodes 2wp, 2wp+1
    int nA = wp * 2;
    if (nA >= Ndst) return;
    int nB = nA + 1;
    bool hasB = (nB < Ndst);
    int lane = threadIdx.x & 63;
    int q = lane >> 4, li = lane & 15;
    const int f8 = li * 8;
    float accA[8], accB[8];
    #pragma unroll
    for (int i = 0; i < 8; ++i) { accA[i] = 0.f; accB[i] = 0.f; }
    int begA = rowptr[nA] - rbase, endA = rowptr[nA + 1] - rbase;
    int begB = 0, endB = 0;
    if (hasB) { begB = endA; endB = rowptr[nB + 1] - rbase; }
    int degA = endA - begA, degB = endB - begB;
    int lastA = (degA > 0) ? endA - 1 : 0;
    int lastB = (degB > 0) ? endB - 1 : 0;
    int jA = begA + q, jB = begB + q;
    while (jA < endA || jB < endB) {
        int ia[4], ib[4];
        #pragma unroll
        for (int k = 0; k < 4; ++k) {
            ia[k] = imin(jA + 4 * k, lastA);
            ib[k] = imin(jB + 4 * k, lastB);
        }
        uint4 va[4], vb[4];
        #pragma unroll
        for (int k = 0; k < 4; ++k) {
            int ra = colv[ia[k]];
            va[k] = *(const uint4*)&featb[(size_t)ra * D_DIM + f8];
        }
        #pragma unroll
        for (int k = 0; k < 4; ++k) {
            int rb = colv[ib[k]];
            vb[k] = *(const uint4*)&featb[(size_t)rb * D_DIM + f8];
        }
        #pragma unroll
        for (int k = 0; k < 4; ++k) {
            if (jA + 4 * k < endA) acc8_add(accA, va[k]);
            if (jB + 4 * k < endB) acc8_add(accB, vb[k]);
        }
        jA += 16; jB += 16;
    }
    #pragma unroll
    for (int i = 0; i < 8; ++i) {
        accA[i] += __shfl_xor(accA[i], 16);
        accA[i] += __shfl_xor(accA[i], 32);
        accB[i] += __shfl_xor(accB[i], 16);
        accB[i] += __shfl_xor(accB[i], 32);
    }
    float invA = 1.f / fmaxf((float)degA, 1.f);
    float invB = 1.f / fmaxf((float)degB, 1.f);
    #pragma unroll
    for (int i = 0; i < 8; ++i) { accA[i] *= invA; accB[i] *= invB; }
    if (addvb) {
        uint4 a = *(const uint4*)&addvb[(size_t)nA * D_DIM + f8];
        acc8_add(accA, a);
        if (hasB) {
            uint4 b = *(const uint4*)&addvb[(size_t)nB * D_DIM + f8];
            acc8_add(accB, b);
        }
    }
    if (bias) {
        float4 b0 = *(const float4*)&bias[f8];
        float4 b1 = *(const float4*)&bias[f8 + 4];
        accA[0] += b0.x; accA[1] += b0.y; accA[2] += b0.z; accA[3] += b0.w;
        accA[4] += b1.x; accA[5] += b1.y; accA[6] += b1.z; accA[7] += b1.w;
        accB[0] += b0.x; accB[1] += b0.y; accB[2] += b0.z; accB[3] += b0.w;
        accB[4] += b1.x; accB[5] += b1.y; accB[6] += b1.z; accB[7] += b1.w;
    }
    if (do_relu) {
        #pragma unroll
        for (int i = 0; i < 8; ++i) {
            accA[i] = fmaxf(accA[i], 0.f);
            accB[i] = fmaxf(accB[i], 0.f);
        }
    }
    if (outb) {
        if (q == 0) {
            uint4 o;
            o.x = (uint)f2bf_rne(accA[0]) | ((uint)f2bf_rne(accA[1]) << 16);
            o.y = (uint)f2bf_rne(accA[2]) | ((uint)f2bf_rne(accA[3]) << 16);
            o.z = (uint)f2bf_rne(accA[4]) | ((uint)f2bf_rne(accA[5]) << 16);
            o.w = (uint)f2bf_rne(accA[6]) | ((uint)f2bf_rne(accA[7]) << 16);
            *(uint4*)&outb[(size_t)nA * D_DIM + f8] = o;
        } else if (q == 1 && hasB) {
            uint4 o;
            o.x = (uint)f2bf_rne(accB[0]) | ((uint)f2bf_rne(accB[1]) << 16);
            o.y = (uint)f2bf_rne(accB[2]) | ((uint)f2bf_rne(accB[3]) << 16);
            o.z = (uint)f2bf_rne(accB[4]) | ((uint)f2bf_rne(accB[5]) << 16);
            o.w = (uint)f2bf_rne(accB[6]) | ((uint)f2bf_rne(accB[7]) << 16);
            *(uint4*)&outb[(size_t)nB * D_DIM + f8] = o;
        }
    }
    if (z) {
        float4 w0 = *(const float4*)&Wm[f8];
        float4 w1 = *(const float4*)&Wm[f8 + 4];
        float p = 0.f;
        if (q == 0)
            p = accA[0] * w0.x + accA[1] * w0.y + accA[2] * w0.z + accA[3] * w0.w
              + accA[4] * w1.x + accA[5] * w1.y + accA[6] * w1.z + accA[7] * w1.w;
        else if (q == 1)
            p = accB[0] * w0.x + accB[1] * w0.y + accB[2] * w0.z + accB[3] * w0.w
              + accB[4] * w1.x + accB[5] * w1.y + accB[6] * w1.z + accB[7] * w1.w;
        #pragma unroll
        for (int off = 8; off > 0; off >>= 1) p += __shfl_down(p, off);
        if (lane == 0) z[nA] = p + bm[0];
        if (lane == 16 && hasB) z[nB] = p + bm[0];
    }
}

// ---------------------------------------------------------------------------
// 2-phase online softmax over z[N0]
// ---------------------------------------------------------------------------
__global__ __launch_bounds__(256) void softmax_partial_kernel(
    const float* __restrict__ z, float* __restrict__ red, int N, int nblk) {
    __shared__ float sm[4], ss[4];
    int t = threadIdx.x, b = blockIdx.x;
    int lane = t & 63, w = t >> 6;
    float m = -1e30f, s = 0.f;
    for (int i = b * 256 + t; i < N; i += nblk * 256) {
        float v = z[i];
        if (v > m) { s = s * __expf(m - v) + 1.f; m = v; }
        else s += __expf(v - m);
    }
    #pragma unroll
    for (int off = 32; off > 0; off >>= 1) {
        float mo = __shfl_down(m, off), so = __shfl_down(s, off);
        if (mo > m) { s = s * __expf(m - mo) + so; m = mo; }
        else s += so * __expf(mo - m);
    }
    if (lane == 0) { sm[w] = m; ss[w] = s; }
    __syncthreads();
    if (t == 0) {
        for (int i = 1; i < 4; ++i) {
            float mo = sm[i], so = ss[i];
            if (mo > m) { s = s * __expf(m - mo) + so; m = mo; }
            else s += so * __expf(mo - m);
        }
        red[2 + 2 * b] = m; red[3 + 2 * b] = s;
    }
}

__global__ __launch_bounds__(64) void softmax_merge_kernel(float* __restrict__ red, int B) {
    int t = threadIdx.x;
    float m = -1e30f, s = 0.f;
    if (t < B) { m = red[2 + 2 * t]; s = red[3 + 2 * t]; }
    #pragma unroll
    for (int off = 32; off > 0; off >>= 1) {
        float mo = __shfl_down(m, off), so = __shfl_down(s, off);
        if (mo > m) { s = s * __expf(m - mo) + so; m = mo; }
        else s += so * __expf(mo - m);
    }
    if (t == 0) { red[0] = m; red[1] = s; }
}

__global__ __launch_bounds__(256) void softmax_final_kernel(
    const float* __restrict__ z, const float* __restrict__ red,
    float* __restrict__ out, int N) {
    int i = blockIdx.x * blockDim.x + threadIdx.x;
    if (i < N) out[i] = expf(z[i] - red[0]) / red[1];
}

// ---------------------------------------------------------------------------
// Host launcher
// ---------------------------------------------------------------------------
static inline char* align_up(char* p, size_t a) {
    return (char*)(((uintptr_t)p + a - 1) & ~(uintptr_t)(a - 1));
}

extern "C" void kernel_launch(void* const* d_in, const int* in_sizes, int n_in,
                              void* d_out, int out_size, void* d_ws, size_t ws_size,
                              hipStream_t stream) {
    const int N0 = N0_C, N1 = N1_C, E0 = E0_C, E1 = E1_C;
    const float* X   = (const float*)d_in[0];
    const float* W0s = (const float*)d_in[1];
    const float* W0n = (const float*)d_in[2];
    const float* b0  = (const float*)d_in[3];
    const float* W1s = (const float*)d_in[4];
    const float* W1n = (const float*)d_in[5];
    const float* b1  = (const float*)d_in[6];
    const float* W2s = (const float*)d_in[7];
    const float* W2n = (const float*)d_in[8];
    const float* b2  = (const float*)d_in[9];
    const float* Wm  = (const float*)d_in[10];
    const float* bm  = (const float*)d_in[11];
    const int* src0  = (const int*)d_in[12];
    const int* dst0  = (const int*)d_in[13];
    const int* src1  = (const int*)d_in[14];
    const int* dst1  = (const int*)d_in[15];
    const int* dsrc  = (const int*)d_in[16];
    const int* ddst  = (const int*)d_in[17];
    float* out = (float*)d_out;

    char* p = (char*)d_ws;
    const size_t FB = (size_t)N0 * D_DIM;
    const size_t SB = (size_t)N1 * D_DIM;
    auto grab_f = [&](size_t nf) { p = align_up(p, 256); float* r = (float*)p; p += nf * 4; return r; };
    auto grab_i = [&](size_t ni) { p = align_up(p, 256); int* r = (int*)p; p += ni * 4; return r; };
    auto grab_u = [&](size_t nu) { p = align_up(p, 256); ushort* r = (ushort*)p; p += nu * 2; return r; };

    const int NC = N0 + 2 * N1;
    // single zero-init region: [cntAll (NC) | cnt2 (N1) | cntD2 (N1)]
    int* zeroRegion = grab_i((size_t)NC + 2 * N1);
    int* cntAll = zeroRegion;
    int* cnt2 = zeroRegion + NC;
    int* cntD2 = zeroRegion + NC + N1;

    float* y1s  = grab_f(SB);   // -> x1f
    float* y1n  = grab_f(SB);
    float* C2   = grab_f(SB);
    float* D2   = grab_f(SB);
    float* zbuf = grab_f(N0);
    float* red  = grab_f(256);
    ushort* y0sb = grab_u(FB);
    ushort* y0nb = grab_u(FB);
    ushort* x0b  = grab_u(FB);
    ushort* y2sb = grab_u(FB);
    ushort* y2nb = grab_u(FB);
    ushort* x1bb = grab_u(SB);
    ushort* wt   = grab_u(8 * 16384);
    int* rowptrAll = grab_i(NC + 1);
    int* bsum = grab_i(256);
    int* boff = grab_i(256);
    int* cursors = grab_i(128);
    int* col0 = grab_i(E0);
    int* col1 = grab_i(E1);
    int* colD = grab_i(N0);
    int* pairbuf = grab_i((size_t)E0);
    (void)ws_size; (void)n_in; (void)in_sizes; (void)out_size;

    const int BT = 256;
    auto cdiv = [](int a, int b) { return (a + b - 1) / b; };
    auto WT = [&](int mi) { return wt + ((size_t)mi << 14); };
    const int nbins0 = (N0 + (1 << BIN_SHIFT) - 1) >> BIN_SHIFT;   // 98
    const int nt0 = cdiv(N0, 16);
    const int nt1 = cdiv(N1, 16);
    const int G0 = 1024;

    // ---- one memset for all cursors/counters ----
    hipMemsetAsync(zeroRegion, 0, ((size_t)NC + 2 * N1) * 4, stream);

    // ---- CSR build ----
    hist_all_kernel<<<cdiv(E0 + E1 + N0, BT), BT, 0, stream>>>(dst0, dst1, ddst, cntAll);
    const int NB = cdiv(NC, 1024);
    scan_partial_kernel<<<NB, BT, 0, stream>>>(cntAll, bsum, NC);
    exscan_kernel<<<1, 1024, 0, stream>>>(bsum, boff, NB);
    scan_final_kernel<<<NB, BT, 0, stream>>>(cntAll, boff, rowptrAll, cursors, NC);
    binscatter_kernel<<<cdiv(E0, 4096), BT, 0, stream>>>(src0, dst0, cursors, pairbuf, E0, nbins0);
    binfill_kernel<<<nbins0, BT, 0, stream>>>(pairbuf, rowptrAll, col0, N0);
    fill_small_kernel<<<cdiv(E1 + N0, BT), BT, 0, stream>>>(src1, dst1, dsrc, ddst,
        rowptrAll, cnt2, cntD2, col1, colD);

    // ---- weight prep ----
    wprep_kernel<<<512, BT, 0, stream>>>(W0s, W0n, W1s, W1n, W2s, W2n, wt);

    // ---- layer 0 SAGE (bf16 outs): y0s = X@W0s + b0 ; y0n = X@W0n ----
    dualmm_reg_kernel<<<G0, BT, 0, stream>>>(X, WT(0), WT(1), b0,
        nullptr, y0sb, nullptr, y0nb, N0, nt0);
    // x0 = y0s + mean_nbr(y0n)  (bf16 out)
    csr_aggb_kernel<<<cdiv(N0, 8), BT, 0, stream>>>(y0nb, rowptrAll, 0, col0,
        y0sb, nullptr, x0b, nullptr, nullptr, nullptr, N0, 0);

    // ---- down pool: x1 = relu(mean_cluster(x0)) ----
    csr_aggb_kernel<<<cdiv(N1, 8), BT, 0, stream>>>(x0b, rowptrAll + N0 + N1, E0 + E1,
        colD, nullptr, nullptr, x1bb, nullptr, nullptr, nullptr, N1, 1);

    // ---- layer 1 SAGE (bf16 A) ----
    dualmm_regb_kernel<<<nt1, BT, 0, stream>>>(x1bb, WT(2), WT(3), b1,
        nullptr, nullptr, nullptr, y1s, nullptr, y1n, nullptr, N1, nt1);
    csr_agg2_kernel<<<cdiv(N1, 4), BT, 0, stream>>>(y1n, rowptrAll + N0, E0, col1,
        y1s, y1s, N1, 1);

    // ---- layer 2: small dualmm (fp32 A, C2/D2 fp32), big bf16-A w/ up-scatter ----
    dualmm_reg_kernel<<<nt1, BT, 0, stream>>>(y1s, WT(4), WT(6), nullptr,
        C2, nullptr, D2, nullptr, N1, nt1);
    dualmm_regb_kernel<<<G0, BT, 0, stream>>>(x0b, WT(5), WT(7), nullptr,
        ddst, C2, D2, nullptr, y2sb, nullptr, y2nb, N0, nt0);

    // ---- layer 2 combine + fused readout ----
    csr_aggb_kernel<<<cdiv(N0, 8), BT, 0, stream>>>(y2nb, rowptrAll, 0, col0,
        y2sb, b2, nullptr, Wm, bm, zbuf, N0, 1);

    // ---- softmax over nodes ----
    softmax_partial_kernel<<<64, BT, 0, stream>>>(zbuf, red, N0, 64);
    softmax_merge_kernel<<<1, 64, 0, stream>>>(red, 64);
    softmax_final_kernel<<<cdiv(N0, BT), BT, 0, stream>>>(zbuf, red, out, N0);
}

// Round 10
// 331.676 us; speedup vs baseline: 1.5205x; 1.0591x over previous
//
#include <hip/hip_runtime.h>
#include <hip/hip_bf16.h>
#include <cstdint>

#define D_DIM 128
#define N0_C 50000
#define N1_C 5000
#define E0_C 800000
#define E1_C 80000
#define BIN_SHIFT 9          // 512 dst nodes per bin (graph0 fill)

typedef __attribute__((ext_vector_type(8))) short bf16x8;
typedef __attribute__((ext_vector_type(4))) float f32x4;
typedef __attribute__((ext_vector_type(2))) float f32x2;

__device__ __forceinline__ ushort f2bf_rne(float x) {
    unsigned int u = __float_as_uint(x);
    return (ushort)((u + 0x7FFFu + ((u >> 16) & 1u)) >> 16);
}
__device__ __forceinline__ float bf2f(ushort h) {
    return __uint_as_float(((unsigned int)h) << 16);
}
__device__ __forceinline__ int imin(int a, int b) { return a < b ? a : b; }

// ---------------------------------------------------------------------------
// prep: fused histogram over [dst0|dst1|ddst]  +  weight prep (independent)
// wt mats: 0:W0s 1:W0n 2:W1s 3:W1n 4:W2s_top 5:W2s_bot 6:W2n_top 7:W2n_bot
// ---------------------------------------------------------------------------
__global__ __launch_bounds__(256) void prep_kernel(
    const int* __restrict__ dst0, const int* __restrict__ dst1,
    const int* __restrict__ ddst, int* __restrict__ cnt,
    const float* __restrict__ W0s, const float* __restrict__ W0n,
    const float* __restrict__ W1s, const float* __restrict__ W1n,
    const float* __restrict__ W2s, const float* __restrict__ W2n,
    ushort* __restrict__ wt, int nbh) {
    int b = blockIdx.x, t = threadIdx.x;
    if (b < nbh) {
        int e = b * 256 + t;
        if (e < E0_C) atomicAdd(&cnt[dst0[e]], 1);
        else if (e < E0_C + E1_C) atomicAdd(&cnt[N0_C + dst1[e - E0_C]], 1);
        else if (e < E0_C + E1_C + N0_C) atomicAdd(&cnt[N0_C + N1_C + ddst[e - E0_C - E1_C]], 1);
    } else {
        int gi = (b - nbh) * 256 + t;
        int mi = gi >> 14, idx = gi & 16383;
        int k = idx >> 7, n = idx & 127;
        const float* src; int row = k;
        switch (mi) {
            case 0: src = W0s; break;
            case 1: src = W0n; break;
            case 2: src = W1s; break;
            case 3: src = W1n; break;
            case 4: src = W2s; break;
            case 5: src = W2s; row = k + 128; break;
            case 6: src = W2n; break;
            default: src = W2n; row = k + 128; break;
        }
        wt[(mi << 14) + n * 128 + k] = f2bf_rne(src[row * 128 + n]);
    }
}

__global__ __launch_bounds__(256) void scan_partial_kernel(
    const int* __restrict__ cnt, int* __restrict__ bsum, int n) {
    __shared__ int ws[4];
    int b = blockIdx.x, t = threadIdx.x, lane = t & 63, w = t >> 6;
    int base = b * 1024 + t * 4;
    int s = 0;
    if (base + 3 < n) { int4 q = *(const int4*)&cnt[base]; s = q.x + q.y + q.z + q.w; }
    else { for (int i = 0; i < 4; ++i) if (base + i < n) s += cnt[base + i]; }
    #pragma unroll
    for (int off = 32; off; off >>= 1) s += __shfl_down(s, off);
    if (lane == 0) ws[w] = s;
    __syncthreads();
    if (t == 0) bsum[b] = ws[0] + ws[1] + ws[2] + ws[3];
}

__global__ __launch_bounds__(1024) void exscan_kernel(const int* __restrict__ cnt,
                                                      int* __restrict__ rowptr, int n) {
    __shared__ int wsum[17];
    __shared__ int base_s;
    const int t = threadIdx.x;
    const int lane = t & 63;
    const int w = t >> 6;
    if (t == 0) { base_s = 0; rowptr[0] = 0; }
    __syncthreads();
    for (int i0 = 0; i0 < n; i0 += 1024) {
        int i = i0 + t;
        int v = (i < n) ? cnt[i] : 0;
        int x = v;
        #pragma unroll
        for (int off = 1; off < 64; off <<= 1) {
            int y = __shfl_up(x, off);
            if (lane >= off) x += y;
        }
        if (lane == 63) wsum[w] = x;
        __syncthreads();
        if (t == 0) {
            int run = base_s;
            #pragma unroll
            for (int j = 0; j < 16; ++j) { int c = wsum[j]; wsum[j] = run; run += c; }
            wsum[16] = run;
        }
        __syncthreads();
        if (i < n) rowptr[i + 1] = wsum[w] + x;
        __syncthreads();
        if (t == 0) base_s = wsum[16];
        __syncthreads();
    }
}

// phase 3: intra-block scan + block offset; also emits graph0 bin cursors
__global__ __launch_bounds__(256) void scan_final_kernel(
    const int* __restrict__ cnt, const int* __restrict__ boff,
    int* __restrict__ rowptr, int* __restrict__ cursors, int n) {
    __shared__ int wsum[4];
    int b = blockIdx.x, t = threadIdx.x, lane = t & 63, w = t >> 6;
    int base = b * 1024 + t * 4;
    int v0 = 0, v1 = 0, v2 = 0, v3 = 0;
    if (base + 3 < n) { int4 q = *(const int4*)&cnt[base]; v0 = q.x; v1 = q.y; v2 = q.z; v3 = q.w; }
    else {
        if (base + 0 < n) v0 = cnt[base + 0];
        if (base + 1 < n) v1 = cnt[base + 1];
        if (base + 2 < n) v2 = cnt[base + 2];
        if (base + 3 < n) v3 = cnt[base + 3];
    }
    int s = v0 + v1 + v2 + v3;
    int x = s;
    #pragma unroll
    for (int off = 1; off < 64; off <<= 1) {
        int y = __shfl_up(x, off);
        if (lane >= off) x += y;
    }
    if (lane == 63) wsum[w] = x;
    __syncthreads();
    if (t == 0) { int run = 0; for (int i = 0; i < 4; ++i) { int c = wsum[i]; wsum[i] = run; run += c; } }
    __syncthreads();
    int run = boff[b] + wsum[w] + x - s;
    #pragma unroll
    for (int k = 0; k < 4; ++k) {
        int v = (k == 0) ? v0 : (k == 1) ? v1 : (k == 2) ? v2 : v3;
        int pos = base + k + 1;
        if (pos <= n) {
            run += v;
            rowptr[pos] = run;
            if ((pos & 511) == 0 && pos < N0_C) cursors[pos >> BIN_SHIFT] = run;
        }
    }
    if (b == 0 && t == 0) { rowptr[0] = 0; cursors[0] = 0; }
}

// ---------------------------------------------------------------------------
// scatfill: graph0 binned pair-scatter (blocks < nbscat) + small fills
// (graph1 edges, down edges) in remaining blocks — both depend only on scan.
// ---------------------------------------------------------------------------
__global__ __launch_bounds__(256) void scatfill_kernel(
    const int* __restrict__ src0, const int* __restrict__ dst0,
    const int* __restrict__ src1, const int* __restrict__ dst1,
    const int* __restrict__ dsrc, const int* __restrict__ ddst,
    const int* __restrict__ rowptrAll,
    int* __restrict__ cursors, int* __restrict__ pairs,
    int* __restrict__ cur1, int* __restrict__ curD,
    int* __restrict__ col1, int* __restrict__ colD,
    int nbscat, int nbins) {
    __shared__ int lcnt[128];
    __shared__ int sbase[128];
    int t = threadIdx.x;
    if (blockIdx.x < nbscat) {
        int e0 = blockIdx.x * 4096;
        if (t < 128) lcnt[t] = 0;
        __syncthreads();
        int lrank[16], dloc[16];
        #pragma unroll
        for (int i = 0; i < 16; ++i) {
            int e = e0 + t + i * 256;
            if (e < E0_C) {
                int d = dst0[e];
                dloc[i] = d;
                lrank[i] = atomicAdd(&lcnt[d >> BIN_SHIFT], 1);
            } else dloc[i] = -1;
        }
        __syncthreads();
        if (t < nbins && lcnt[t] > 0) sbase[t] = atomicAdd(&cursors[t], lcnt[t]);
        __syncthreads();
        #pragma unroll
        for (int i = 0; i < 16; ++i) {
            int e = e0 + t + i * 256;
            if (e < E0_C) {
                int d = dloc[i];
                int key = ((d & ((1 << BIN_SHIFT) - 1)) << 17) | src0[e];
                pairs[sbase[d >> BIN_SHIFT] + lrank[i]] = key;
            }
        }
    } else {
        int e = (blockIdx.x - nbscat) * 256 + t;
        if (e < E1_C) {
            int d = dst1[e];
            int p = atomicAdd(&cur1[d], 1);
            col1[rowptrAll[N0_C + d] - E0_C + p] = src1[e];
        } else if (e < E1_C + N0_C) {
            int i = e - E1_C;
            int d = ddst[i];
            int p = atomicAdd(&curD[d], 1);
            colD[rowptrAll[N0_C + N1_C + d] - E0_C - E1_C + p] = dsrc[i];
        }
    }
}

__global__ __launch_bounds__(256) void binfill_kernel(
    const int* __restrict__ pairs, const int* __restrict__ rowptr,
    int* __restrict__ colv, int N) {
    __shared__ int rp[513];
    __shared__ int cur[512];
    int b = blockIdx.x, t = threadIdx.x;
    int binbase = b << BIN_SHIFT;
    for (int i = t; i < 513; i += 256) {
        int idx = binbase + i; if (idx > N) idx = N;
        rp[i] = rowptr[idx];
    }
    for (int i = t; i < 512; i += 256) cur[i] = 0;
    __syncthreads();
    int beg = rp[0], end = rp[512];
    for (int i = beg + t; i < end; i += 256) {
        int key = pairs[i];
        int local = key >> 17;
        int rank = atomicAdd(&cur[local], 1);
        colv[rp[local] + rank] = key & 0x1FFFF;
    }
}

// ---------------------------------------------------------------------------
// Register-resident-B MFMA dual GEMM, fp32 A (hi/lo split), no LDS/barriers.
// O1 -> bf16 (packed pair stores) or fp32; O2 -> fp8 (packed quad) or fp32.
// ---------------------------------------------------------------------------
__global__ __launch_bounds__(256, 4) void dualmm_reg_kernel(
    const float* __restrict__ A,
    const ushort* __restrict__ w1, const ushort* __restrict__ w2,
    const float* __restrict__ bias1,
    float* __restrict__ O1f, ushort* __restrict__ O1b,
    float* __restrict__ O2f, unsigned char* __restrict__ O2f8,
    int N, int ntiles) {
    const int tid = threadIdx.x;
    const int wave = tid >> 6, lane = tid & 63;
    const int m = lane & 15, quad = lane >> 4;
    const int colbase = wave * 32;
    bf16x8 bf[4][2][2];
    #pragma unroll
    for (int c = 0; c < 4; ++c)
        #pragma unroll
        for (int ct = 0; ct < 2; ++ct) {
            const size_t bo = (size_t)(colbase + ct * 16 + m) * 128 + c * 32 + quad * 8;
            bf[c][ct][0] = *(const bf16x8*)(w1 + bo);
            bf[c][ct][1] = *(const bf16x8*)(w2 + bo);
        }
    const f32x4 zero = {0.f, 0.f, 0.f, 0.f};

    for (int tile = blockIdx.x; tile < ntiles; tile += gridDim.x) {
        const int r0 = tile * 16;
        int ar = r0 + m; if (ar >= N) ar = N - 1;
        const float* arow = A + (size_t)ar * 128;
        f32x4 acc[2][2];
        acc[0][0] = zero; acc[0][1] = zero; acc[1][0] = zero; acc[1][1] = zero;
        #pragma unroll
        for (int c = 0; c < 4; ++c) {
            float4 a0 = *(const float4*)(arow + c * 32 + quad * 8);
            float4 a1 = *(const float4*)(arow + c * 32 + quad * 8 + 4);
            float av[8] = {a0.x, a0.y, a0.z, a0.w, a1.x, a1.y, a1.z, a1.w};
            bf16x8 afh, afl;
            #pragma unroll
            for (int i = 0; i < 8; ++i) {
                ushort h = f2bf_rne(av[i]);
                ushort l = f2bf_rne(av[i] - bf2f(h));
                afh[i] = (short)h; afl[i] = (short)l;
            }
            #pragma unroll
            for (int ct = 0; ct < 2; ++ct) {
                acc[ct][0] = __builtin_amdgcn_mfma_f32_16x16x32_bf16(afh, bf[c][ct][0], acc[ct][0], 0, 0, 0);
                acc[ct][0] = __builtin_amdgcn_mfma_f32_16x16x32_bf16(afl, bf[c][ct][0], acc[ct][0], 0, 0, 0);
                acc[ct][1] = __builtin_amdgcn_mfma_f32_16x16x32_bf16(afh, bf[c][ct][1], acc[ct][1], 0, 0, 0);
                acc[ct][1] = __builtin_amdgcn_mfma_f32_16x16x32_bf16(afl, bf[c][ct][1], acc[ct][1], 0, 0, 0);
            }
        }
        #pragma unroll
        for (int ct = 0; ct < 2; ++ct) {
            const int col = colbase + ct * 16 + m;
            float bv = bias1 ? bias1[col] : 0.f;
            #pragma unroll
            for (int reg = 0; reg < 4; ++reg) {
                int r = r0 + quad * 4 + reg;
                float o1 = acc[ct][0][reg] + bv;
                float o2 = acc[ct][1][reg];
                if (O1b) {
                    uint u1 = f2bf_rne(o1);
                    uint p1 = (uint)__shfl_xor((int)u1, 1);
                    float o2n = __shfl_xor(o2, 1);
                    int pk = __builtin_amdgcn_cvt_pk_fp8_f32(o2, o2n, 0, false);
                    int pk2 = __shfl_xor(pk, 2);
                    if (r < N) {
                        if (!(m & 1)) *(uint*)&O1b[(size_t)r * D_DIM + col] = u1 | (p1 << 16);
                        if (!(m & 3)) *(uint*)&O2f8[(size_t)r * D_DIM + col] =
                            ((uint)pk & 0xFFFFu) | ((uint)pk2 << 16);
                    }
                } else if (r < N) {
                    size_t o = (size_t)r * D_DIM + col;
                    O1f[o] = o1; O2f[o] = o2;
                }
            }
        }
    }
}

// bf16-A variant: optional C2/D2 gather-add; O1 bf16, O2 fp8 (or fp32 pair).
__global__ __launch_bounds__(256, 4) void dualmm_regb_kernel(
    const ushort* __restrict__ Ab,
    const ushort* __restrict__ w1, const ushort* __restrict__ w2,
    const float* __restrict__ bias1,
    const int* __restrict__ ddst,
    const float* __restrict__ C2g, const float* __restrict__ D2g,
    float* __restrict__ O1f, ushort* __restrict__ O1b,
    float* __restrict__ O2f, unsigned char* __restrict__ O2f8,
    int N, int ntiles) {
    const int tid = threadIdx.x;
    const int wave = tid >> 6, lane = tid & 63;
    const int m = lane & 15, quad = lane >> 4;
    const int colbase = wave * 32;
    bf16x8 bf[4][2][2];
    #pragma unroll
    for (int c = 0; c < 4; ++c)
        #pragma unroll
        for (int ct = 0; ct < 2; ++ct) {
            const size_t bo = (size_t)(colbase + ct * 16 + m) * 128 + c * 32 + quad * 8;
            bf[c][ct][0] = *(const bf16x8*)(w1 + bo);
            bf[c][ct][1] = *(const bf16x8*)(w2 + bo);
        }
    const f32x4 zero = {0.f, 0.f, 0.f, 0.f};

    for (int tile = blockIdx.x; tile < ntiles; tile += gridDim.x) {
        const int r0 = tile * 16;
        int ar = r0 + m; if (ar >= N) ar = N - 1;
        const ushort* arow = Ab + (size_t)ar * 128;
        f32x4 acc[2][2];
        acc[0][0] = zero; acc[0][1] = zero; acc[1][0] = zero; acc[1][1] = zero;
        #pragma unroll
        for (int c = 0; c < 4; ++c) {
            bf16x8 af = *(const bf16x8*)(arow + c * 32 + quad * 8);
            #pragma unroll
            for (int ct = 0; ct < 2; ++ct) {
                acc[ct][0] = __builtin_amdgcn_mfma_f32_16x16x32_bf16(af, bf[c][ct][0], acc[ct][0], 0, 0, 0);
                acc[ct][1] = __builtin_amdgcn_mfma_f32_16x16x32_bf16(af, bf[c][ct][1], acc[ct][1], 0, 0, 0);
            }
        }
        int rr[4], cc[4];
        #pragma unroll
        for (int reg = 0; reg < 4; ++reg) {
            rr[reg] = r0 + quad * 4 + reg;
            cc[reg] = (ddst && rr[reg] < N) ? ddst[rr[reg]] : 0;
        }
        #pragma unroll
        for (int ct = 0; ct < 2; ++ct) {
            const int col = colbase + ct * 16 + m;
            float bv = bias1 ? bias1[col] : 0.f;
            #pragma unroll
            for (int reg = 0; reg < 4; ++reg) {
                int r = rr[reg];
                float g1 = (ddst && r < N) ? C2g[(size_t)cc[reg] * D_DIM + col] : 0.f;
                float g2 = (ddst && r < N) ? D2g[(size_t)cc[reg] * D_DIM + col] : 0.f;
                float o1 = acc[ct][0][reg] + bv + g1;
                float o2 = acc[ct][1][reg] + g2;
                if (O1b) {
                    uint u1 = f2bf_rne(o1);
                    uint p1 = (uint)__shfl_xor((int)u1, 1);
                    float o2n = __shfl_xor(o2, 1);
                    int pk = __builtin_amdgcn_cvt_pk_fp8_f32(o2, o2n, 0, false);
                    int pk2 = __shfl_xor(pk, 2);
                    if (r < N) {
                        if (!(m & 1)) *(uint*)&O1b[(size_t)r * D_DIM + col] = u1 | (p1 << 16);
                        if (!(m & 3)) *(uint*)&O2f8[(size_t)r * D_DIM + col] =
                            ((uint)pk & 0xFFFFu) | ((uint)pk2 << 16);
                    }
                } else if (r < N) {
                    size_t o = (size_t)r * D_DIM + col;
                    O1f[o] = o1; O2f[o] = o2;
                }
            }
        }
    }
}

// ---------------------------------------------------------------------------
// fp32 CSR gather-aggregate (small graph1): wave/node, float4/lane
// ---------------------------------------------------------------------------
__global__ __launch_bounds__(256) void csr_agg2_kernel(
    const float* __restrict__ feat, const int* __restrict__ rowptr, int rbase,
    const int* __restrict__ colv, const float* __restrict__ addv,
    float* __restrict__ out, int Ndst, int do_relu) {
    int gt = blockIdx.x * blockDim.x + threadIdx.x;
    int wid = gt >> 6;
    if (wid >= Ndst) return;
    int lane = threadIdx.x & 63;
    int half = lane >> 5, li = lane & 31;
    const int f4 = li * 4;
    float4 acc = make_float4(0.f, 0.f, 0.f, 0.f);
    int beg = rowptr[wid] - rbase, end = rowptr[wid + 1] - rbase;
    int deg = end - beg;
    for (int j = beg + half; j < end; j += 8) {
        int i1 = imin(j + 2, end - 1), i2 = imin(j + 4, end - 1), i3 = imin(j + 6, end - 1);
        int r0 = colv[j], r1 = colv[i1], r2 = colv[i2], r3 = colv[i3];
        float4 v0 = *(const float4*)&feat[(size_t)r0 * D_DIM + f4];
        float4 v1 = *(const float4*)&feat[(size_t)r1 * D_DIM + f4];
        float4 v2 = *(const float4*)&feat[(size_t)r2 * D_DIM + f4];
        float4 v3 = *(const float4*)&feat[(size_t)r3 * D_DIM + f4];
        acc.x += v0.x; acc.y += v0.y; acc.z += v0.z; acc.w += v0.w;
        if (j + 2 < end) { acc.x += v1.x; acc.y += v1.y; acc.z += v1.z; acc.w += v1.w; }
        if (j + 4 < end) { acc.x += v2.x; acc.y += v2.y; acc.z += v2.z; acc.w += v2.w; }
        if (j + 6 < end) { acc.x += v3.x; acc.y += v3.y; acc.z += v3.z; acc.w += v3.w; }
    }
    acc.x += __shfl_xor(acc.x, 32);
    acc.y += __shfl_xor(acc.y, 32);
    acc.z += __shfl_xor(acc.z, 32);
    acc.w += __shfl_xor(acc.w, 32);
    float invd = 1.f / fmaxf((float)deg, 1.f);
    acc.x *= invd; acc.y *= invd; acc.z *= invd; acc.w *= invd;
    if (addv) {
        float4 v = *(const float4*)&addv[(size_t)wid * D_DIM + f4];
        acc.x += v.x; acc.y += v.y; acc.z += v.z; acc.w += v.w;
    }
    if (do_relu) {
        acc.x = fmaxf(acc.x, 0.f); acc.y = fmaxf(acc.y, 0.f);
        acc.z = fmaxf(acc.z, 0.f); acc.w = fmaxf(acc.w, 0.f);
    }
    if (half == 0)
        *(float4*)&out[(size_t)wid * D_DIM + f4] = acc;
}

// ---------------------------------------------------------------------------
// big CSR gather-aggregate, 2 nodes/wave; FP8=1 -> fp8 feature plane (128B
// rows, HW cvt decode), FP8=0 -> bf16 plane (256B rows). fp32 accumulate.
// ---------------------------------------------------------------------------
__device__ __forceinline__ void acc8_add_bf(float* acc, uint4 r) {
    acc[0] += __uint_as_float(r.x << 16);
    acc[1] += __uint_as_float(r.x & 0xFFFF0000u);
    acc[2] += __uint_as_float(r.y << 16);
    acc[3] += __uint_as_float(r.y & 0xFFFF0000u);
    acc[4] += __uint_as_float(r.z << 16);
    acc[5] += __uint_as_float(r.z & 0xFFFF0000u);
    acc[6] += __uint_as_float(r.w << 16);
    acc[7] += __uint_as_float(r.w & 0xFFFF0000u);
}
__device__ __forceinline__ void acc8_add_f8(float* acc, uint2 r) {
    f32x2 a = __builtin_amdgcn_cvt_pk_f32_fp8((int)r.x, false);
    f32x2 b = __builtin_amdgcn_cvt_pk_f32_fp8((int)r.x, true);
    f32x2 c = __builtin_amdgcn_cvt_pk_f32_fp8((int)r.y, false);
    f32x2 d = __builtin_amdgcn_cvt_pk_f32_fp8((int)r.y, true);
    acc[0] += a[0]; acc[1] += a[1]; acc[2] += b[0]; acc[3] += b[1];
    acc[4] += c[0]; acc[5] += c[1]; acc[6] += d[0]; acc[7] += d[1];
}

template <int FP8>
__global__ __launch_bounds__(256) void csr_agg_big(
    const void* __restrict__ featv, const int* __restrict__ rowptr, int rbase,
    const int* __restrict__ colv,
    const ushort* __restrict__ addvb, const float* __restrict__ bias,
    ushort* __restrict__ outb,
    const float* __restrict__ Wm, const float* __restrict__ bm,
    float* __restrict__ z, int Ndst, int do_relu) {
    const char* feat = (const char*)featv;
    int gt = blockIdx.x * blockDim.x + threadIdx.x;
    int wp = gt >> 6;                 // wave id -> nodes 2wp, 2wp+1
    int nA = wp * 2;
    if (nA >= Ndst) return;
    int nB = nA + 1;
    bool hasB = (nB < Ndst);
    int lane = threadIdx.x & 63;
    int q = lane >> 4, li = lane & 15;
    float accA[8], accB[8];
    #pragma unroll
    for (int i = 0; i < 8; ++i) { accA[i] = 0.f; accB[i] = 0.f; }
    int begA = rowptr[nA] - rbase, endA = rowptr[nA + 1] - rbase;
    int begB = 0, endB = 0;
    if (hasB) { begB = endA; endB = rowptr[nB + 1] - rbase; }
    int degA = endA - begA, degB = endB - begB;
    int lastA = (degA > 0) ? endA - 1 : 0;
    int lastB = (degB > 0) ? endB - 1 : 0;
    int jA = begA + q, jB = begB + q;
    while (jA < endA || jB < endB) {
        int ia[4], ib[4];
        #pragma unroll
        for (int k = 0; k < 4; ++k) {
            ia[k] = imin(jA + 4 * k, lastA);
            ib[k] = imin(jB + 4 * k, lastB);
        }
        if (FP8) {
            uint2 va[4], vb[4];
            #pragma unroll
            for (int k = 0; k < 4; ++k) {
                int ra = colv[ia[k]];
                va[k] = *(const uint2*)(feat + (size_t)ra * 128 + li * 8);
            }
            #pragma unroll
            for (int k = 0; k < 4; ++k) {
                int rb = colv[ib[k]];
                vb[k] = *(const uint2*)(feat + (size_t)rb * 128 + li * 8);
            }
            #pragma unroll
            for (int k = 0; k < 4; ++k) {
                if (jA + 4 * k < endA) acc8_add_f8(accA, va[k]);
                if (jB + 4 * k < endB) acc8_add_f8(accB, vb[k]);
            }
        } else {
            uint4 va[4], vb[4];
            #pragma unroll
            for (int k = 0; k < 4; ++k) {
                int ra = colv[ia[k]];
                va[k] = *(const uint4*)(feat + (size_t)ra * 256 + li * 16);
            }
            #pragma unroll
            for (int k = 0; k < 4; ++k) {
                int rb = colv[ib[k]];
                vb[k] = *(const uint4*)(feat + (size_t)rb * 256 + li * 16);
            }
            #pragma unroll
            for (int k = 0; k < 4; ++k) {
                if (jA + 4 * k < endA) acc8_add_bf(accA, va[k]);
                if (jB + 4 * k < endB) acc8_add_bf(accB, vb[k]);
            }
        }
        jA += 16; jB += 16;
    }
    const int f8 = li * 8;
    #pragma unroll
    for (int i = 0; i < 8; ++i) {
        accA[i] += __shfl_xor(accA[i], 16);
        accA[i] += __shfl_xor(accA[i], 32);
        accB[i] += __shfl_xor(accB[i], 16);
        accB[i] += __shfl_xor(accB[i], 32);
    }
    float invA = 1.f / fmaxf((float)degA, 1.f);
    float invB = 1.f / fmaxf((float)degB, 1.f);
    #pragma unroll
    for (int i = 0; i < 8; ++i) { accA[i] *= invA; accB[i] *= invB; }
    if (addvb) {
        uint4 a = *(const uint4*)&addvb[(size_t)nA * D_DIM + f8];
        acc8_add_bf(accA, a);
        if (hasB) {
            uint4 b = *(const uint4*)&addvb[(size_t)nB * D_DIM + f8];
            acc8_add_bf(accB, b);
        }
    }
    if (bias) {
        float4 b0 = *(const float4*)&bias[f8];
        float4 b1 = *(const float4*)&bias[f8 + 4];
        accA[0] += b0.x; accA[1] += b0.y; accA[2] += b0.z; accA[3] += b0.w;
        accA[4] += b1.x; accA[5] += b1.y; accA[6] += b1.z; accA[7] += b1.w;
        accB[0] += b0.x; accB[1] += b0.y; accB[2] += b0.z; accB[3] += b0.w;
        accB[4] += b1.x; accB[5] += b1.y; accB[6] += b1.z; accB[7] += b1.w;
    }
    if (do_relu) {
        #pragma unroll
        for (int i = 0; i < 8; ++i) {
            accA[i] = fmaxf(accA[i], 0.f);
            accB[i] = fmaxf(accB[i], 0.f);
        }
    }
    if (outb) {
        if (q == 0) {
            uint4 o;
            o.x = (uint)f2bf_rne(accA[0]) | ((uint)f2bf_rne(accA[1]) << 16);
            o.y = (uint)f2bf_rne(accA[2]) | ((uint)f2bf_rne(accA[3]) << 16);
            o.z = (uint)f2bf_rne(accA[4]) | ((uint)f2bf_rne(accA[5]) << 16);
            o.w = (uint)f2bf_rne(accA[6]) | ((uint)f2bf_rne(accA[7]) << 16);
            *(uint4*)&outb[(size_t)nA * D_DIM + f8] = o;
        } else if (q == 1 && hasB) {
            uint4 o;
            o.x = (uint)f2bf_rne(accB[0]) | ((uint)f2bf_rne(accB[1]) << 16);
            o.y = (uint)f2bf_rne(accB[2]) | ((uint)f2bf_rne(accB[3]) << 16);
            o.z = (uint)f2bf_rne(accB[4]) | ((uint)f2bf_rne(accB[5]) << 16);
            o.w = (uint)f2bf_rne(accB[6]) | ((uint)f2bf_rne(accB[7]) << 16);
            *(uint4*)&outb[(size_t)nB * D_DIM + f8] = o;
        }
    }
    if (z) {
        float4 w0 = *(const float4*)&Wm[f8];
        float4 w1 = *(const float4*)&Wm[f8 + 4];
        float p = 0.f;
        if (q == 0)
            p = accA[0] * w0.x + accA[1] * w0.y + accA[2] * w0.z + accA[3] * w0.w
              + accA[4] * w1.x + accA[5] * w1.y + accA[6] * w1.z + accA[7] * w1.w;
        else if (q == 1)
            p = accB[0] * w0.x + accB[1] * w0.y + accB[2] * w0.z + accB[3] * w0.w
              + accB[4] * w1.x + accB[5] * w1.y + accB[6] * w1.z + accB[7] * w1.w;
        #pragma unroll
        for (int off = 8; off > 0; off >>= 1) p += __shfl_down(p, off);
        if (lane == 0) z[nA] = p + bm[0];
        if (lane == 16 && hasB) z[nB] = p + bm[0];
    }
}

// ---------------------------------------------------------------------------
// softmax: partial (64 blocks) then final (re-merges partials per block)
// ---------------------------------------------------------------------------
__global__ __launch_bounds__(256) void softmax_partial_kernel(
    const float* __restrict__ z, float* __restrict__ red, int N, int nblk) {
    __shared__ float sm[4], ss[4];
    int t = threadIdx.x, b = blockIdx.x;
    int lane = t & 63, w = t >> 6;
    float m = -1e30f, s = 0.f;
    for (int i = b * 256 + t; i < N; i += nblk * 256) {
        float v = z[i];
        if (v > m) { s = s * __expf(m - v) + 1.f; m = v; }
        else s += __expf(v - m);
    }
    #pragma unroll
    for (int off = 32; off > 0; off >>= 1) {
        float mo = __shfl_down(m, off), so = __shfl_down(s, off);
        if (mo > m) { s = s * __expf(m - mo) + so; m = mo; }
        else s += so * __expf(mo - m);
    }
    if (lane == 0) { sm[w] = m; ss[w] = s; }
    __syncthreads();
    if (t == 0) {
        for (int i = 1; i < 4; ++i) {
            float mo = sm[i], so = ss[i];
            if (mo > m) { s = s * __expf(m - mo) + so; m = mo; }
            else s += so * __expf(mo - m);
        }
        red[2 + 2 * b] = m; red[3 + 2 * b] = s;
    }
}

__global__ __launch_bounds__(256) void softmax_final_kernel(
    const float* __restrict__ z, const float* __restrict__ red,
    float* __restrict__ out, int N, int B) {
    __shared__ float sm_s, ss_s;
    int t = threadIdx.x;
    if (t < 64) {
        float m = -1e30f, s = 0.f;
        if (t < B) { m = red[2 + 2 * t]; s = red[3 + 2 * t]; }
        #pragma unroll
        for (int off = 32; off > 0; off >>= 1) {
            float mo = __shfl_down(m, off), so = __shfl_down(s, off);
            if (mo > m) { s = s * __expf(m - mo) + so; m = mo; }
            else s += so * __expf(mo - m);
        }
        if (t == 0) { sm_s = m; ss_s = s; }
    }
    __syncthreads();
    float mx = sm_s, sum = ss_s;
    for (int i = blockIdx.x * 256 + t; i < N; i += gridDim.x * 256)
        out[i] = expf(z[i] - mx) / sum;
}

// ---------------------------------------------------------------------------
// Host launcher
// ---------------------------------------------------------------------------
static inline char* align_up(char* p, size_t a) {
    return (char*)(((uintptr_t)p + a - 1) & ~(uintptr_t)(a - 1));
}

extern "C" void kernel_launch(void* const* d_in, const int* in_sizes, int n_in,
                              void* d_out, int out_size, void* d_ws, size_t ws_size,
                              hipStream_t stream) {
    const int N0 = N0_C, N1 = N1_C, E0 = E0_C, E1 = E1_C;
    const float* X   = (const float*)d_in[0];
    const float* W0s = (const float*)d_in[1];
    const float* W0n = (const float*)d_in[2];
    const float* b0  = (const float*)d_in[3];
    const float* W1s = (const float*)d_in[4];
    const float* W1n = (const float*)d_in[5];
    const float* b1  = (const float*)d_in[6];
    const float* W2s = (const float*)d_in[7];
    const float* W2n = (const float*)d_in[8];
    const float* b2  = (const float*)d_in[9];
    const float* Wm  = (const float*)d_in[10];
    const float* bm  = (const float*)d_in[11];
    const int* src0  = (const int*)d_in[12];
    const int* dst0  = (const int*)d_in[13];
    const int* src1  = (const int*)d_in[14];
    const int* dst1  = (const int*)d_in[15];
    const int* dsrc  = (const int*)d_in[16];
    const int* ddst  = (const int*)d_in[17];
    float* out = (float*)d_out;

    char* p = (char*)d_ws;
    const size_t FB = (size_t)N0 * D_DIM;
    const size_t SB = (size_t)N1 * D_DIM;
    auto grab_f = [&](size_t nf) { p = align_up(p, 256); float* r = (float*)p; p += nf * 4; return r; };
    auto grab_i = [&](size_t ni) { p = align_up(p, 256); int* r = (int*)p; p += ni * 4; return r; };
    auto grab_u = [&](size_t nu) { p = align_up(p, 256); ushort* r = (ushort*)p; p += nu * 2; return r; };
    auto grab_b = [&](size_t nb) { p = align_up(p, 256); unsigned char* r = (unsigned char*)p; p += nb; return r; };

    const int NC = N0 + 2 * N1;
    // single zero-init region: [cntAll (NC) | cnt2 (N1) | cntD2 (N1)]
    int* zeroRegion = grab_i((size_t)NC + 2 * N1);
    int* cntAll = zeroRegion;
    int* cnt2 = zeroRegion + NC;
    int* cntD2 = zeroRegion + NC + N1;

    float* y1s  = grab_f(SB);   // -> x1f
    float* y1n  = grab_f(SB);
    float* C2   = grab_f(SB);
    float* D2   = grab_f(SB);
    float* zbuf = grab_f(N0);
    float* red  = grab_f(256);
    ushort* y0sb = grab_u(FB);
    ushort* x0b  = grab_u(FB);
    ushort* y2sb = grab_u(FB);
    ushort* x1bb = grab_u(SB);
    unsigned char* y0nf8 = grab_b(FB);
    unsigned char* y2nf8 = grab_b(FB);
    ushort* wt   = grab_u(8 * 16384);
    int* rowptrAll = grab_i(NC + 1);
    int* bsum = grab_i(256);
    int* boff = grab_i(256);
    int* cursors = grab_i(128);
    int* col0 = grab_i(E0);
    int* col1 = grab_i(E1);
    int* colD = grab_i(N0);
    int* pairbuf = grab_i((size_t)E0);
    (void)ws_size; (void)n_in; (void)in_sizes; (void)out_size;

    const int BT = 256;
    auto cdiv = [](int a, int b) { return (a + b - 1) / b; };
    auto WT = [&](int mi) { return wt + ((size_t)mi << 14); };
    const int nbins0 = (N0 + (1 << BIN_SHIFT) - 1) >> BIN_SHIFT;   // 98
    const int nt0 = cdiv(N0, 16);
    const int nt1 = cdiv(N1, 16);
    const int G0 = 1024;

    // ---- one memset for all cursors/counters ----
    hipMemsetAsync(zeroRegion, 0, ((size_t)NC + 2 * N1) * 4, stream);

    // ---- CSR build + weight prep ----
    const int nbh = cdiv(E0 + E1 + N0, BT);
    prep_kernel<<<nbh + 512, BT, 0, stream>>>(dst0, dst1, ddst, cntAll,
        W0s, W0n, W1s, W1n, W2s, W2n, wt, nbh);
    const int NB = cdiv(NC, 1024);
    scan_partial_kernel<<<NB, BT, 0, stream>>>(cntAll, bsum, NC);
    exscan_kernel<<<1, 1024, 0, stream>>>(bsum, boff, NB);
    scan_final_kernel<<<NB, BT, 0, stream>>>(cntAll, boff, rowptrAll, cursors, NC);
    const int nbscat = cdiv(E0, 4096);
    scatfill_kernel<<<nbscat + cdiv(E1 + N0, BT), BT, 0, stream>>>(
        src0, dst0, src1, dst1, dsrc, ddst, rowptrAll,
        cursors, pairbuf, cnt2, cntD2, col1, colD, nbscat, nbins0);
    binfill_kernel<<<nbins0, BT, 0, stream>>>(pairbuf, rowptrAll, col0, N0);

    // ---- layer 0 SAGE: y0s = X@W0s + b0 (bf16) ; y0n = X@W0n (fp8) ----
    dualmm_reg_kernel<<<G0, BT, 0, stream>>>(X, WT(0), WT(1), b0,
        nullptr, y0sb, nullptr, y0nf8, N0, nt0);
    // x0 = y0s + mean_nbr(y0n)  (bf16 out)
    csr_agg_big<1><<<cdiv(N0, 8), BT, 0, stream>>>(y0nf8, rowptrAll, 0, col0,
        y0sb, nullptr, x0b, nullptr, nullptr, nullptr, N0, 0);

    // ---- down pool: x1 = relu(mean_cluster(x0))  (bf16 plane) ----
    csr_agg_big<0><<<cdiv(N1, 8), BT, 0, stream>>>(x0b, rowptrAll + N0 + N1, E0 + E1,
        colD, nullptr, nullptr, x1bb, nullptr, nullptr, nullptr, N1, 1);

    // ---- layer 1 SAGE (bf16 A, fp32 outs) ----
    dualmm_regb_kernel<<<nt1, BT, 0, stream>>>(x1bb, WT(2), WT(3), b1,
        nullptr, nullptr, nullptr, y1s, nullptr, y1n, nullptr, N1, nt1);
    csr_agg2_kernel<<<cdiv(N1, 4), BT, 0, stream>>>(y1n, rowptrAll + N0, E0, col1,
        y1s, y1s, N1, 1);

    // ---- layer 2: small dualmm (fp32 A, fp32 outs), big bf16-A w/ up-scatter ----
    dualmm_reg_kernel<<<nt1, BT, 0, stream>>>(y1s, WT(4), WT(6), nullptr,
        C2, nullptr, D2, nullptr, N1, nt1);
    dualmm_regb_kernel<<<G0, BT, 0, stream>>>(x0b, WT(5), WT(7), nullptr,
        ddst, C2, D2, nullptr, y2sb, nullptr, y2nf8, N0, nt0);

    // ---- layer 2 combine + fused readout ----
    csr_agg_big<1><<<cdiv(N0, 8), BT, 0, stream>>>(y2nf8, rowptrAll, 0, col0,
        y2sb, b2, nullptr, Wm, bm, zbuf, N0, 1);

    // ---- softmax over nodes ----
    softmax_partial_kernel<<<64, BT, 0, stream>>>(zbuf, red, N0, 64);
    softmax_final_kernel<<<128, BT, 0, stream>>>(zbuf, red, out, N0, 64);
}